// Round 1
// baseline (30980.762 us; speedup 1.0000x reference)
//
#include <hip/hip_runtime.h>
#include <hip/hip_bf16.h>
#include <cstdint>

// ---------------------------------------------------------------------------
// CCT-with-binarized-conv3d forward, fp32 baseline.
// Pipeline:
//   conv1 (sign weights)        -> bit b1 (acc>0)            [B,64,9,224,224]
//   pack b1 channels -> u64     -> b1p                       [B,9,224,224]
//   conv2 via popcount          -> bit b2                    [B,32,3,224,224]
//   pack b2 channels -> u32     -> b2p                       [B,3,224,224]
//   conv3 via popcount          -> h3 = relu(count) fp32     [B,3,224,224]
//   tokenizer conv 7x7 s2 relu  -> tok                       [B,256,112,112]
//   maxpool 3x3 s2 + pos_emb    -> z                         [B,3136,256]
//   7x { LN, qkv GEMM, flash-attn, proj GEMM(+res), LN, fc1 GEMM(gelu),
//        fc2 GEMM(+res) }
//   LN, seq-pool softmax, head  -> out [4,101] fp32
// ---------------------------------------------------------------------------

#define SEQL 3136

// ---------------- prep kernels ----------------
__global__ __launch_bounds__(256) void k_prep_sign(const float* __restrict__ w,
                                                   float* __restrict__ sw, int n) {
    int i = blockIdx.x * 256 + threadIdx.x;
    if (i < n) {
        float v = w[i];
        sw[i] = (v > 0.f) ? 1.f : ((v < 0.f) ? -1.f : 0.f);
    }
}

__global__ __launch_bounds__(256) void k_prep_masks2(const float* __restrict__ w2,
                                                     uint64_t* __restrict__ wp,
                                                     uint64_t* __restrict__ wn) {
    int i = blockIdx.x * 256 + threadIdx.x;
    if (i >= 32 * 147) return;
    int oc = i / 147, r = i % 147;           // r = kd*49 + kh*7 + kw
    uint64_t p = 0, n = 0;
    for (int ic = 0; ic < 64; ic++) {
        float v = w2[(long)oc * 9408 + (long)ic * 147 + r];
        if (v > 0.f) p |= (1ull << ic);
        else if (v < 0.f) n |= (1ull << ic);
    }
    wp[i] = p; wn[i] = n;
}

__global__ __launch_bounds__(256) void k_prep_masks3(const float* __restrict__ w3,
                                                     uint32_t* __restrict__ wp,
                                                     uint32_t* __restrict__ wn) {
    int i = blockIdx.x * 256 + threadIdx.x;
    if (i >= 3 * 147) return;
    int oc = i / 147, r = i % 147;
    uint32_t p = 0, n = 0;
    for (int ic = 0; ic < 32; ic++) {
        float v = w3[(long)oc * 4704 + (long)ic * 147 + r];
        if (v > 0.f) p |= (1u << ic);
        else if (v < 0.f) n |= (1u << ic);
    }
    wp[i] = p; wn[i] = n;
}

// ---------------- conv1: fp32, ternary weights, emit sign bit ----------------
// out layout [b][oc(64)][od(9)][oh][ow] as uint8 (acc>0); 4 ow per thread.
__global__ __launch_bounds__(256) void k_conv1(const float* __restrict__ x,
                                               const float* __restrict__ sw1,
                                               uint8_t* __restrict__ b1) {
    int q = blockIdx.x * 256 + threadIdx.x;   // total 28,901,376
    int ow4 = q % 56; q /= 56;
    int oh = q % 224; q /= 224;
    int od = q % 9;   q /= 9;
    int oc = q % 64;  int b = q / 64;
    int ow0 = ow4 * 4;
    float a0 = 0.f, a1 = 0.f, a2 = 0.f, a3 = 0.f;
    for (int ic = 0; ic < 3; ic++) {
        for (int kd = 0; kd < 3; kd++) {
            int d = od * 3 - 1 + kd;
            if ((unsigned)d >= 27u) continue;
            const float* xp = x + ((long)(b * 3 + ic) * 27 + d) * 50176;
            const float* swb = sw1 + ((oc * 3 + ic) * 3 + kd) * 49;
            for (int kh = 0; kh < 7; kh++) {
                int h = oh - 3 + kh;
                if ((unsigned)h >= 224u) continue;
                const float* xr = xp + h * 224;
                float xv[10];
#pragma unroll
                for (int t = 0; t < 10; t++) {
                    int w = ow0 - 3 + t;
                    xv[t] = ((unsigned)w < 224u) ? xr[w] : 0.f;
                }
                const float* swp = swb + kh * 7;
#pragma unroll
                for (int kw = 0; kw < 7; kw++) {
                    float s = swp[kw];
                    a0 = fmaf(s, xv[kw],     a0);
                    a1 = fmaf(s, xv[kw + 1], a1);
                    a2 = fmaf(s, xv[kw + 2], a2);
                    a3 = fmaf(s, xv[kw + 3], a3);
                }
            }
        }
    }
    long ob = (((long)(b * 64 + oc) * 9 + od) * 224 + oh) * 224 + ow0;
    b1[ob + 0] = (a0 > 0.f); b1[ob + 1] = (a1 > 0.f);
    b1[ob + 2] = (a2 > 0.f); b1[ob + 3] = (a3 > 0.f);
}

// pack 64 channels -> u64 per (b,d,h,w)
__global__ __launch_bounds__(256) void k_pack64(const uint8_t* __restrict__ b1,
                                                uint64_t* __restrict__ p) {
    int gid = blockIdx.x * 256 + threadIdx.x;  // 1,806,336 = 4*9*224*224
    int w = gid % 224; int t = gid / 224;
    int h = t % 224; t /= 224;
    int d = t % 9;  int b = t / 9;
    long base = (((long)b * 576 + d) * 224 + h) * 224 + w;  // b*64*9 = b*576
    uint64_t bits = 0;
    for (int c = 0; c < 64; c++)
        if (b1[base + (long)c * 451584]) bits |= (1ull << c);
    p[gid] = bits;
}

// conv2 via popcount over packed channels
__global__ __launch_bounds__(256) void k_conv2(const uint64_t* __restrict__ bp1,
                                               const uint64_t* __restrict__ wp,
                                               const uint64_t* __restrict__ wn,
                                               uint8_t* __restrict__ b2) {
    int gid = blockIdx.x * 256 + threadIdx.x;  // 19,267,584
    int q = gid;
    int ow = q % 224; q /= 224;
    int oh = q % 224; q /= 224;
    int od = q % 3;   q /= 3;
    int oc = q % 32;  int b = q / 32;
    int acc = 0;
    for (int kd = 0; kd < 3; kd++) {
        int d = od * 3 - 1 + kd;
        if ((unsigned)d >= 9u) continue;
        for (int kh = 0; kh < 7; kh++) {
            int h = oh - 3 + kh;
            if ((unsigned)h >= 224u) continue;
            const uint64_t* bp = bp1 + ((long)(b * 9 + d) * 224 + h) * 224;
            const uint64_t* mp = wp + ((oc * 3 + kd) * 7 + kh) * 7;
            const uint64_t* mn = wn + ((oc * 3 + kd) * 7 + kh) * 7;
#pragma unroll
            for (int kw = 0; kw < 7; kw++) {
                int w = ow - 3 + kw;
                if ((unsigned)w < 224u) {
                    uint64_t bits = bp[w];
                    acc += __popcll(bits & mp[kw]) - __popcll(bits & mn[kw]);
                }
            }
        }
    }
    b2[gid] = (acc > 0);
}

__global__ __launch_bounds__(256) void k_pack32(const uint8_t* __restrict__ b2,
                                                uint32_t* __restrict__ p) {
    int gid = blockIdx.x * 256 + threadIdx.x;  // 602,112 = 4*3*224*224
    int w = gid % 224; int t = gid / 224;
    int h = t % 224; t /= 224;
    int d = t % 3;  int b = t / 3;
    long base = (((long)b * 96 + d) * 224 + h) * 224 + w;  // b*32*3 = b*96
    uint32_t bits = 0;
    for (int c = 0; c < 32; c++)
        if (b2[base + (long)c * 150528]) bits |= (1u << c);
    p[gid] = bits;
}

// conv3 via popcount -> fp32 relu count
__global__ __launch_bounds__(256) void k_conv3(const uint32_t* __restrict__ bp2,
                                               const uint32_t* __restrict__ wp,
                                               const uint32_t* __restrict__ wn,
                                               float* __restrict__ h3) {
    int gid = blockIdx.x * 256 + threadIdx.x;  // 602,112 = 4*3*224*224
    int q = gid;
    int ow = q % 224; q /= 224;
    int oh = q % 224; q /= 224;
    int oc = q % 3;   int b = q / 3;
    int acc = 0;
    for (int kd = 0; kd < 3; kd++) {
        int d = kd - 1;                 // od==0, stride 3, pad 1
        if ((unsigned)d >= 3u) continue;
        for (int kh = 0; kh < 7; kh++) {
            int h = oh - 3 + kh;
            if ((unsigned)h >= 224u) continue;
            const uint32_t* bp = bp2 + ((long)(b * 3 + d) * 224 + h) * 224;
            const uint32_t* mp = wp + ((oc * 3 + kd) * 7 + kh) * 7;
            const uint32_t* mn = wn + ((oc * 3 + kd) * 7 + kh) * 7;
#pragma unroll
            for (int kw = 0; kw < 7; kw++) {
                int w = ow - 3 + kw;
                if ((unsigned)w < 224u) {
                    uint32_t bits = bp[w];
                    acc += __popc(bits & mp[kw]) - __popc(bits & mn[kw]);
                }
            }
        }
    }
    h3[gid] = fmaxf((float)acc, 0.f);
}

// tokenizer conv 7x7 stride2 pad3, relu, no bias
__global__ __launch_bounds__(256) void k_tok(const float* __restrict__ h3,
                                             const float* __restrict__ wt,
                                             float* __restrict__ tok) {
    int gid = blockIdx.x * 256 + threadIdx.x;  // 12,845,056
    int q = gid;
    int ow = q % 112; q /= 112;
    int oh = q % 112; q /= 112;
    int oc = q % 256; int b = q / 256;
    float acc = 0.f;
    for (int ic = 0; ic < 3; ic++) {
        const float* xp = h3 + (long)(b * 3 + ic) * 50176;
        const float* wr0 = wt + (oc * 3 + ic) * 49;
        for (int kh = 0; kh < 7; kh++) {
            int h = oh * 2 - 3 + kh;
            if ((unsigned)h >= 224u) continue;
            const float* xr = xp + h * 224;
            const float* wr = wr0 + kh * 7;
#pragma unroll
            for (int kw = 0; kw < 7; kw++) {
                int w = ow * 2 - 3 + kw;
                if ((unsigned)w < 224u) acc = fmaf(wr[kw], xr[w], acc);
            }
        }
    }
    tok[gid] = fmaxf(acc, 0.f);
}

// maxpool 3x3 s2 p1 + pos_emb, write z[b][n][c]
__global__ __launch_bounds__(256) void k_pool_z(const float* __restrict__ tok,
                                                const float* __restrict__ pos,
                                                float* __restrict__ z) {
    int gid = blockIdx.x * 256 + threadIdx.x;  // 3,211,264
    int c = gid % 256;
    int n = (gid / 256) % SEQL;
    int b = gid / (256 * SEQL);
    int oh = n / 56, ow = n % 56;
    const float* tp = tok + (long)(b * 256 + c) * 12544;
    float m = -1e30f;
#pragma unroll
    for (int kh = 0; kh < 3; kh++) {
        int h = oh * 2 - 1 + kh;
        if ((unsigned)h >= 112u) continue;
#pragma unroll
        for (int kw = 0; kw < 3; kw++) {
            int w = ow * 2 - 1 + kw;
            if ((unsigned)w < 112u) m = fmaxf(m, tp[h * 112 + w]);
        }
    }
    z[gid] = m + pos[n * 256 + c];
}

// layernorm over 256 dims, wave per row (4 rows/block)
__global__ __launch_bounds__(256) void k_ln(const float* __restrict__ X,
                                            const float* __restrict__ g,
                                            const float* __restrict__ be,
                                            float* __restrict__ out) {
    int wid = threadIdx.x >> 6, lane = threadIdx.x & 63;
    int r = blockIdx.x * 4 + wid;  // < 12544
    const float* xr = X + (long)r * 256;
    float v0 = xr[lane], v1 = xr[lane + 64], v2 = xr[lane + 128], v3 = xr[lane + 192];
    float s = v0 + v1 + v2 + v3;
#pragma unroll
    for (int off = 1; off < 64; off <<= 1) s += __shfl_xor(s, off);
    float mean = s * (1.0f / 256.0f);
    float d0 = v0 - mean, d1 = v1 - mean, d2 = v2 - mean, d3 = v3 - mean;
    float sq = d0 * d0 + d1 * d1 + d2 * d2 + d3 * d3;
#pragma unroll
    for (int off = 1; off < 64; off <<= 1) sq += __shfl_xor(sq, off);
    float rs = rsqrtf(sq * (1.0f / 256.0f) + 1e-5f);
    float* orow = out + (long)r * 256;
    orow[lane]       = d0 * rs * g[lane]       + be[lane];
    orow[lane + 64]  = d1 * rs * g[lane + 64]  + be[lane + 64];
    orow[lane + 128] = d2 * rs * g[lane + 128] + be[lane + 128];
    orow[lane + 192] = d3 * rs * g[lane + 192] + be[lane + 192];
}

// C[M,N] = act(A[M,K] @ W[N,K]^T + bias) (+ C if resid). 64x64 tile, 4x4/thread.
__global__ __launch_bounds__(256) void k_gemm(const float* __restrict__ A,
                                              const float* __restrict__ W,
                                              const float* __restrict__ bias,
                                              float* __restrict__ C,
                                              int M, int N, int K,
                                              int dogelu, int resid) {
    __shared__ float As[64 * 33], Ws[64 * 33];
    int tid = threadIdx.x;
    int tx = tid & 15, ty = tid >> 4;
    int n0 = blockIdx.x * 64, m0 = blockIdx.y * 64;
    float c[4][4] = {};
    for (int k0 = 0; k0 < K; k0 += 32) {
        __syncthreads();
#pragma unroll
        for (int e = 0; e < 8; e++) {
            int idx = e * 256 + tid;
            int row = idx >> 5, col = idx & 31;
            As[row * 33 + col] = A[(long)(m0 + row) * K + k0 + col];
            Ws[row * 33 + col] = W[(long)(n0 + row) * K + k0 + col];
        }
        __syncthreads();
#pragma unroll
        for (int kk = 0; kk < 32; kk++) {
            float av[4], wv[4];
#pragma unroll
            for (int i = 0; i < 4; i++) av[i] = As[(ty * 4 + i) * 33 + kk];
#pragma unroll
            for (int j = 0; j < 4; j++) wv[j] = Ws[(tx * 4 + j) * 33 + kk];
#pragma unroll
            for (int i = 0; i < 4; i++)
#pragma unroll
                for (int j = 0; j < 4; j++)
                    c[i][j] = fmaf(av[i], wv[j], c[i][j]);
        }
    }
#pragma unroll
    for (int i = 0; i < 4; i++) {
        int mrow = m0 + ty * 4 + i;
        float* crow = C + (long)mrow * N + n0;
#pragma unroll
        for (int j = 0; j < 4; j++) {
            int n = tx * 4 + j;
            float v = c[i][j] + bias[n0 + n];
            if (dogelu) v = 0.5f * v * (1.0f + erff(v * 0.70710678118654752f));
            if (resid) v += crow[n];
            crow[n] = v;
        }
    }
}

// flash attention: 64-row Q tile per block, online softmax over 49 K tiles.
// qkv layout [b*SEQL + n][768] with q|k|v at +0/+256/+512, head h at +h*64.
__global__ __launch_bounds__(256) void k_flash(const float* __restrict__ qkv,
                                               float* __restrict__ o) {
    __shared__ float Qs[64 * 65], Ks[64 * 65], Vs[64 * 65];
    float* Ps = Ks;  // P tile reuses K tile (sync-guarded)
    int tid = threadIdx.x;
    int tx = tid & 15, ty = tid >> 4;
    int qt = blockIdx.x, h = blockIdx.y, b = blockIdx.z;
    long base = (long)b * SEQL * 768 + h * 64;
#pragma unroll
    for (int e = 0; e < 16; e++) {
        int idx = e * 256 + tid;
        int r = idx >> 6, d = idx & 63;
        Qs[r * 65 + d] = qkv[base + (long)(qt * 64 + r) * 768 + d] * 0.125f;
    }
    float m[4], l[4], acc[4][4];
#pragma unroll
    for (int i = 0; i < 4; i++) {
        m[i] = -1e30f; l[i] = 0.f;
#pragma unroll
        for (int j = 0; j < 4; j++) acc[i][j] = 0.f;
    }
    for (int kt = 0; kt < 49; kt++) {
        __syncthreads();  // prev GEMM2 done (and Q tile visible on iter 0)
#pragma unroll
        for (int e = 0; e < 16; e++) {
            int idx = e * 256 + tid;
            int r = idx >> 6, d = idx & 63;
            long rowb = base + (long)(kt * 64 + r) * 768;
            Ks[r * 65 + d] = qkv[rowb + 256 + d];
            Vs[r * 65 + d] = qkv[rowb + 512 + d];
        }
        __syncthreads();
        float s[4][4] = {};
        for (int kk = 0; kk < 64; kk++) {
            float qa[4], kb[4];
#pragma unroll
            for (int i = 0; i < 4; i++) qa[i] = Qs[(ty * 4 + i) * 65 + kk];
#pragma unroll
            for (int j = 0; j < 4; j++) kb[j] = Ks[(tx * 4 + j) * 65 + kk];
#pragma unroll
            for (int i = 0; i < 4; i++)
#pragma unroll
                for (int j = 0; j < 4; j++)
                    s[i][j] = fmaf(qa[i], kb[j], s[i][j]);
        }
        // online softmax (cross-lane over the 16 tx lanes of each row group)
        float alpha[4];
#pragma unroll
        for (int i = 0; i < 4; i++) {
            float rm = fmaxf(fmaxf(s[i][0], s[i][1]), fmaxf(s[i][2], s[i][3]));
#pragma unroll
            for (int off = 1; off < 16; off <<= 1) rm = fmaxf(rm, __shfl_xor(rm, off));
            float mn = fmaxf(m[i], rm);
            alpha[i] = expf(m[i] - mn);
            float ps = 0.f;
#pragma unroll
            for (int j = 0; j < 4; j++) { s[i][j] = expf(s[i][j] - mn); ps += s[i][j]; }
#pragma unroll
            for (int off = 1; off < 16; off <<= 1) ps += __shfl_xor(ps, off);
            l[i] = l[i] * alpha[i] + ps;
            m[i] = mn;
#pragma unroll
            for (int j = 0; j < 4; j++) acc[i][j] *= alpha[i];
        }
        __syncthreads();  // all lanes done reading Ks
#pragma unroll
        for (int i = 0; i < 4; i++)
#pragma unroll
            for (int j = 0; j < 4; j++)
                Ps[(ty * 4 + i) * 65 + tx * 4 + j] = s[i][j];
        __syncthreads();
        for (int jj = 0; jj < 64; jj++) {
            float pv[4], vv[4];
#pragma unroll
            for (int i = 0; i < 4; i++) pv[i] = Ps[(ty * 4 + i) * 65 + jj];
#pragma unroll
            for (int dj = 0; dj < 4; dj++) vv[dj] = Vs[jj * 65 + tx * 4 + dj];
#pragma unroll
            for (int i = 0; i < 4; i++)
#pragma unroll
                for (int dj = 0; dj < 4; dj++)
                    acc[i][dj] = fmaf(pv[i], vv[dj], acc[i][dj]);
        }
    }
    long obase = ((long)b * SEQL + qt * 64) * 256 + h * 64;
#pragma unroll
    for (int i = 0; i < 4; i++) {
        float inv = 1.0f / l[i];
#pragma unroll
        for (int dj = 0; dj < 4; dj++)
            o[obase + (long)(ty * 4 + i) * 256 + tx * 4 + dj] = acc[i][dj] * inv;
    }
}

// pooling logits: lg[r] = z[r,:]·pool_w + pool_b  (wave per row)
__global__ __launch_bounds__(256) void k_pool_logits(const float* __restrict__ zl,
                                                     const float* __restrict__ pw,
                                                     const float* __restrict__ pb,
                                                     float* __restrict__ lg) {
    int wid = threadIdx.x >> 6, lane = threadIdx.x & 63;
    int r = blockIdx.x * 4 + wid;
    const float* xr = zl + (long)r * 256;
    float a = xr[lane] * pw[lane] + xr[lane + 64] * pw[lane + 64]
            + xr[lane + 128] * pw[lane + 128] + xr[lane + 192] * pw[lane + 192];
#pragma unroll
    for (int off = 1; off < 64; off <<= 1) a += __shfl_xor(a, off);
    if (lane == 0) lg[r] = a + pb[0];
}

__global__ __launch_bounds__(256) void k_pool_softmax(float* __restrict__ lg) {
    __shared__ float red[256];
    int b = blockIdx.x, tid = threadIdx.x;
    float* p = lg + b * SEQL;
    float m = -1e30f;
    for (int i = tid; i < SEQL; i += 256) m = fmaxf(m, p[i]);
    red[tid] = m; __syncthreads();
    for (int s = 128; s > 0; s >>= 1) {
        if (tid < s) red[tid] = fmaxf(red[tid], red[tid + s]);
        __syncthreads();
    }
    float M = red[0]; __syncthreads();
    float sum = 0.f;
    for (int i = tid; i < SEQL; i += 256) sum += expf(p[i] - M);
    red[tid] = sum; __syncthreads();
    for (int s = 128; s > 0; s >>= 1) {
        if (tid < s) red[tid] += red[tid + s];
        __syncthreads();
    }
    float inv = 1.0f / red[0];
    for (int i = tid; i < SEQL; i += 256) p[i] = expf(p[i] - M) * inv;
}

__global__ __launch_bounds__(256) void k_pooled(const float* __restrict__ lg,
                                                const float* __restrict__ zl,
                                                float* __restrict__ pooled) {
    int b = blockIdx.x, d = threadIdx.x;
    const float* zb = zl + (long)b * SEQL * 256;
    const float* ab = lg + b * SEQL;
    float acc = 0.f;
    for (int n = 0; n < SEQL; n++) acc = fmaf(ab[n], zb[(long)n * 256 + d], acc);
    pooled[b * 256 + d] = acc;
}

__global__ __launch_bounds__(512) void k_head(const float* __restrict__ pooled,
                                              const float* __restrict__ hw,
                                              const float* __restrict__ hb,
                                              float* __restrict__ out) {
    int t = threadIdx.x;
    if (t >= 404) return;
    int b = t / 101, c = t % 101;
    float acc = hb[c];
    for (int d = 0; d < 256; d++)
        acc = fmaf(pooled[b * 256 + d], hw[c * 256 + d], acc);
    out[b * 101 + c] = acc;
}

// ---------------------------------------------------------------------------
extern "C" void kernel_launch(void* const* d_in, const int* in_sizes, int n_in,
                              void* d_out, int out_size, void* d_ws, size_t ws_size,
                              hipStream_t stream) {
    (void)in_sizes; (void)n_in; (void)out_size; (void)ws_size;
    const float* x     = (const float*)d_in[0];
    const float* w1    = (const float*)d_in[1];
    const float* w2    = (const float*)d_in[2];
    const float* w3    = (const float*)d_in[3];
    const float* tokw  = (const float*)d_in[4];
    const float* pos   = (const float*)d_in[5];
    const float* ln1s  = (const float*)d_in[6];
    const float* ln1b  = (const float*)d_in[7];
    const float* qkvw  = (const float*)d_in[8];
    const float* qkvb  = (const float*)d_in[9];
    const float* projw = (const float*)d_in[10];
    const float* projb = (const float*)d_in[11];
    const float* ln2s  = (const float*)d_in[12];
    const float* ln2b  = (const float*)d_in[13];
    const float* fc1w  = (const float*)d_in[14];
    const float* fc1b  = (const float*)d_in[15];
    const float* fc2w  = (const float*)d_in[16];
    const float* fc2b  = (const float*)d_in[17];
    const float* lnfs  = (const float*)d_in[18];
    const float* lnfb  = (const float*)d_in[19];
    const float* poolw = (const float*)d_in[20];
    const float* poolb = (const float*)d_in[21];
    const float* headw = (const float*)d_in[22];
    const float* headb = (const float*)d_in[23];
    float* out = (float*)d_out;
    char* ws = (char*)d_ws;

    // ---- workspace layout (phase-aliased; peak requirement ~154.4 MB) ----
    // Phase A (convs):
    uint8_t*  B1  = (uint8_t*)(ws + 0);                    // 115,605,504
    uint64_t* B1P = (uint64_t*)(ws + 115605504);           //  14,450,688
    uint8_t*  B2  = (uint8_t*)(ws + 130056192);            //  19,267,584
    uint32_t* B2P = (uint32_t*)(ws + 149323776);           //   2,408,448
    float*    SW1 = (float*)(ws + 151732224);              //     112,896
    uint64_t* WP2 = (uint64_t*)(ws + 151845120);           //      37,632
    uint64_t* WN2 = (uint64_t*)(ws + 151882752);           //      37,632
    uint32_t* WP3 = (uint32_t*)(ws + 151920384);           //       2,048
    uint32_t* WN3 = (uint32_t*)(ws + 151922432);           //       2,048
    float*    H3  = (float*)(ws + 151924480);              //   2,408,448 (ends 154,332,928)
    // Phase B/C (aliases conv region; all conv buffers dead by then):
    float*    TOK = (float*)(ws + 0);                      //  51,380,224
    float*    Z   = (float*)(ws + 51380224);               //  12,845,056
    float*    F   = (float*)(ws + 64225280);               //  12,845,056
    float*    G   = (float*)(ws + 77070336);               //  38,535,168
    float*    O   = (float*)(ws + 115605504);              //  12,845,056
    float*    MLP = (float*)(ws + 128450560);              //  25,690,112
    float*    LG  = (float*)(ws + 154140672);              //      50,176
    float*    PL  = (float*)(ws + 154190848);              //       4,096

    k_prep_sign<<<(28224 + 255) / 256, 256, 0, stream>>>(w1, SW1, 28224);
    k_prep_masks2<<<(4704 + 255) / 256, 256, 0, stream>>>(w2, WP2, WN2);
    k_prep_masks3<<<(441 + 255) / 256, 256, 0, stream>>>(w3, WP3, WN3);

    k_conv1<<<112896, 256, 0, stream>>>(x, SW1, B1);
    k_pack64<<<7056, 256, 0, stream>>>(B1, B1P);
    k_conv2<<<75264, 256, 0, stream>>>(B1P, WP2, WN2, B2);
    k_pack32<<<2352, 256, 0, stream>>>(B2, B2P);
    k_conv3<<<2352, 256, 0, stream>>>(B2P, WP3, WN3, H3);
    k_tok<<<50176, 256, 0, stream>>>(H3, tokw, TOK);
    k_pool_z<<<12544, 256, 0, stream>>>(TOK, pos, Z);

    for (int l = 0; l < 7; l++) {
        k_ln<<<3136, 256, 0, stream>>>(Z, ln1s + l * 256, ln1b + l * 256, F);
        k_gemm<<<dim3(12, 196), 256, 0, stream>>>(F, qkvw + (long)l * 196608,
                                                  qkvb + l * 768, G,
                                                  12544, 768, 256, 0, 0);
        k_flash<<<dim3(49, 4, 4), 256, 0, stream>>>(G, O);
        k_gemm<<<dim3(4, 196), 256, 0, stream>>>(O, projw + (long)l * 65536,
                                                 projb + l * 256, Z,
                                                 12544, 256, 256, 0, 1);
        k_ln<<<3136, 256, 0, stream>>>(Z, ln2s + l * 256, ln2b + l * 256, F);
        k_gemm<<<dim3(8, 196), 256, 0, stream>>>(F, fc1w + (long)l * 131072,
                                                 fc1b + l * 512, MLP,
                                                 12544, 512, 256, 1, 0);
        k_gemm<<<dim3(4, 196), 256, 0, stream>>>(MLP, fc2w + (long)l * 131072,
                                                 fc2b + l * 256, Z,
                                                 12544, 256, 512, 0, 1);
    }

    k_ln<<<3136, 256, 0, stream>>>(Z, lnfs, lnfb, F);
    k_pool_logits<<<3136, 256, 0, stream>>>(F, poolw, poolb, LG);
    k_pool_softmax<<<4, 256, 0, stream>>>(LG);
    k_pooled<<<4, 256, 0, stream>>>(LG, F, PL);
    k_head<<<1, 512, 0, stream>>>(PL, headw, headb, out);
}

// Round 2
// 11997.507 us; speedup vs baseline: 2.5823x; 2.5823x over previous
//
#include <hip/hip_runtime.h>
#include <hip/hip_bf16.h>
#include <cstdint>

#define SEQL 3136

typedef __attribute__((ext_vector_type(8))) short v8s;
typedef __attribute__((ext_vector_type(4))) float f32x4;

__device__ __forceinline__ uint16_t bf16u(float f) {
    uint32_t u = __float_as_uint(f);
    uint32_t r = u + 0x7fff + ((u >> 16) & 1);   // RNE
    return (uint16_t)(r >> 16);
}
__device__ __forceinline__ uint32_t pack2(float a, float b) {
    return (uint32_t)bf16u(a) | ((uint32_t)bf16u(b) << 16);
}

// ---------------- prep kernels ----------------
// w1 sign, transposed to [ic][kd][r(49)][oc(64)] for coalesced LDS staging
__global__ __launch_bounds__(256) void k_prep_w1t(const float* __restrict__ w1,
                                                  float* __restrict__ wt) {
    int i = blockIdx.x * 256 + threadIdx.x;   // 28224
    if (i >= 28224) return;
    int oc = i & 63; int t = i >> 6;
    int r = t % 49; int ickd = t / 49;
    int ic = ickd / 3, kd = ickd % 3;
    float v = w1[(((oc * 3 + ic) * 3 + kd) * 49) + r];
    wt[i] = (v > 0.f) ? 1.f : ((v < 0.f) ? -1.f : 0.f);
}

__global__ __launch_bounds__(256) void k_prep_masks2(const float* __restrict__ w2,
                                                     uint64_t* __restrict__ wp,
                                                     uint64_t* __restrict__ wn) {
    int i = blockIdx.x * 256 + threadIdx.x;
    if (i >= 32 * 147) return;
    int oc = i / 147, r = i % 147;
    uint64_t p = 0, n = 0;
    for (int ic = 0; ic < 64; ic++) {
        float v = w2[(long)oc * 9408 + (long)ic * 147 + r];
        if (v > 0.f) p |= (1ull << ic);
        else if (v < 0.f) n |= (1ull << ic);
    }
    wp[i] = p; wn[i] = n;
}

__global__ __launch_bounds__(256) void k_prep_masks3(const float* __restrict__ w3,
                                                     uint32_t* __restrict__ wp,
                                                     uint32_t* __restrict__ wn) {
    int i = blockIdx.x * 256 + threadIdx.x;
    if (i >= 3 * 147) return;
    int oc = i / 147, r = i % 147;
    uint32_t p = 0, n = 0;
    for (int ic = 0; ic < 32; ic++) {
        float v = w3[(long)oc * 4704 + (long)ic * 147 + r];
        if (v > 0.f) p |= (1u << ic);
        else if (v < 0.f) n |= (1u << ic);
    }
    wp[i] = p; wn[i] = n;
}

// ---------------- conv1: LDS-tiled, 4oc x 14ow register tile ----------------
// block = (oh, od, b); stages x patch [3ic][3kd][7kh][232] once, weights per (ic,kd).
__global__ __launch_bounds__(256) void k_conv1(const float* __restrict__ x,
                                               const float* __restrict__ wt,
                                               uint8_t* __restrict__ b1) {
    __shared__ float xs[14616];    // 3*3*7*232
    __shared__ float wsh[3136];    // 49*64
    int tid = threadIdx.x;
    int oh = blockIdx.x, od = blockIdx.y, b = blockIdx.z;
    for (int i = tid; i < 14616; i += 256) {
        int col = i % 232; int t = i / 232;
        int kh = t % 7; t /= 7;
        int kd = t % 3; int ic = t / 3;
        int d = od * 3 - 1 + kd;
        int hh = oh - 3 + kh;
        int ww = col - 3;
        float v = 0.f;
        if ((unsigned)d < 27u && (unsigned)hh < 224u && (unsigned)ww < 224u)
            v = x[((long)(b * 3 + ic) * 27 + d) * 50176 + hh * 224 + ww];
        xs[i] = v;
    }
    int tx = tid & 15, ty = tid >> 4;
    float acc[4][14];
#pragma unroll
    for (int j = 0; j < 4; j++)
#pragma unroll
        for (int o2 = 0; o2 < 14; o2++) acc[j][o2] = 0.f;

    for (int ickd = 0; ickd < 9; ickd++) {
        __syncthreads();   // iter 0: xs visible; later: prev wsh consumed
        const float* wsrc = wt + ickd * 49 * 64;
        for (int i = tid; i < 3136; i += 256) wsh[i] = wsrc[i];
        __syncthreads();
        const float* xb = xs + ickd * 7 * 232;
#pragma unroll
        for (int kh = 0; kh < 7; kh++) {
            const float* row = xb + kh * 232 + tx * 14;
            float xv[20];
#pragma unroll
            for (int t = 0; t < 20; t++) xv[t] = row[t];
            const float* wrow = wsh + kh * 7 * 64 + ty * 4;
#pragma unroll
            for (int kw = 0; kw < 7; kw++) {
                float w0 = wrow[kw * 64 + 0], w1v = wrow[kw * 64 + 1];
                float w2v = wrow[kw * 64 + 2], w3v = wrow[kw * 64 + 3];
#pragma unroll
                for (int o2 = 0; o2 < 14; o2++) {
                    float xvv = xv[o2 + kw];
                    acc[0][o2] = fmaf(w0, xvv, acc[0][o2]);
                    acc[1][o2] = fmaf(w1v, xvv, acc[1][o2]);
                    acc[2][o2] = fmaf(w2v, xvv, acc[2][o2]);
                    acc[3][o2] = fmaf(w3v, xvv, acc[3][o2]);
                }
            }
        }
    }
#pragma unroll
    for (int j = 0; j < 4; j++) {
        int oc = ty * 4 + j;
        long ob = (((long)(b * 64 + oc) * 9 + od) * 224 + oh) * 224 + tx * 14;
#pragma unroll
        for (int o2 = 0; o2 < 14; o2++) b1[ob + o2] = (acc[j][o2] > 0.f);
    }
}

// pack 64 channels -> u64 per (b,d,h,w)
__global__ __launch_bounds__(256) void k_pack64(const uint8_t* __restrict__ b1,
                                                uint64_t* __restrict__ p) {
    int gid = blockIdx.x * 256 + threadIdx.x;  // 1,806,336
    int w = gid % 224; int t = gid / 224;
    int h = t % 224; t /= 224;
    int d = t % 9;  int b = t / 9;
    long base = (((long)b * 576 + d) * 224 + h) * 224 + w;
    uint64_t bits = 0;
    for (int c = 0; c < 64; c++)
        if (b1[base + (long)c * 451584]) bits |= (1ull << c);
    p[gid] = bits;
}

__global__ __launch_bounds__(256) void k_conv2(const uint64_t* __restrict__ bp1,
                                               const uint64_t* __restrict__ wp,
                                               const uint64_t* __restrict__ wn,
                                               uint8_t* __restrict__ b2) {
    int gid = blockIdx.x * 256 + threadIdx.x;  // 19,267,584
    int q = gid;
    int ow = q % 224; q /= 224;
    int oh = q % 224; q /= 224;
    int od = q % 3;   q /= 3;
    int oc = q % 32;  int b = q / 32;
    int acc = 0;
    for (int kd = 0; kd < 3; kd++) {
        int d = od * 3 - 1 + kd;
        if ((unsigned)d >= 9u) continue;
        for (int kh = 0; kh < 7; kh++) {
            int h = oh - 3 + kh;
            if ((unsigned)h >= 224u) continue;
            const uint64_t* bp = bp1 + ((long)(b * 9 + d) * 224 + h) * 224;
            const uint64_t* mp = wp + ((oc * 3 + kd) * 7 + kh) * 7;
            const uint64_t* mn = wn + ((oc * 3 + kd) * 7 + kh) * 7;
#pragma unroll
            for (int kw = 0; kw < 7; kw++) {
                int w = ow - 3 + kw;
                if ((unsigned)w < 224u) {
                    uint64_t bits = bp[w];
                    acc += __popcll(bits & mp[kw]) - __popcll(bits & mn[kw]);
                }
            }
        }
    }
    b2[gid] = (acc > 0);
}

__global__ __launch_bounds__(256) void k_pack32(const uint8_t* __restrict__ b2,
                                                uint32_t* __restrict__ p) {
    int gid = blockIdx.x * 256 + threadIdx.x;  // 602,112
    int w = gid % 224; int t = gid / 224;
    int h = t % 224; t /= 224;
    int d = t % 3;  int b = t / 3;
    long base = (((long)b * 96 + d) * 224 + h) * 224 + w;
    uint32_t bits = 0;
    for (int c = 0; c < 32; c++)
        if (b2[base + (long)c * 150528]) bits |= (1u << c);
    p[gid] = bits;
}

__global__ __launch_bounds__(256) void k_conv3(const uint32_t* __restrict__ bp2,
                                               const uint32_t* __restrict__ wp,
                                               const uint32_t* __restrict__ wn,
                                               float* __restrict__ h3) {
    int gid = blockIdx.x * 256 + threadIdx.x;  // 602,112
    int q = gid;
    int ow = q % 224; q /= 224;
    int oh = q % 224; q /= 224;
    int oc = q % 3;   int b = q / 3;
    int acc = 0;
    for (int kd = 0; kd < 3; kd++) {
        int d = kd - 1;
        if ((unsigned)d >= 3u) continue;
        for (int kh = 0; kh < 7; kh++) {
            int h = oh - 3 + kh;
            if ((unsigned)h >= 224u) continue;
            const uint32_t* bp = bp2 + ((long)(b * 3 + d) * 224 + h) * 224;
            const uint32_t* mp = wp + ((oc * 3 + kd) * 7 + kh) * 7;
            const uint32_t* mn = wn + ((oc * 3 + kd) * 7 + kh) * 7;
#pragma unroll
            for (int kw = 0; kw < 7; kw++) {
                int w = ow - 3 + kw;
                if ((unsigned)w < 224u) {
                    uint32_t bits = bp[w];
                    acc += __popc(bits & mp[kw]) - __popc(bits & mn[kw]);
                }
            }
        }
    }
    h3[gid] = fmaxf((float)acc, 0.f);
}

__global__ __launch_bounds__(256) void k_tok(const float* __restrict__ h3,
                                             const float* __restrict__ wt,
                                             float* __restrict__ tok) {
    int gid = blockIdx.x * 256 + threadIdx.x;  // 12,845,056
    int q = gid;
    int ow = q % 112; q /= 112;
    int oh = q % 112; q /= 112;
    int oc = q % 256; int b = q / 256;
    float acc = 0.f;
    for (int ic = 0; ic < 3; ic++) {
        const float* xp = h3 + (long)(b * 3 + ic) * 50176;
        const float* wr0 = wt + (oc * 3 + ic) * 49;
        for (int kh = 0; kh < 7; kh++) {
            int h = oh * 2 - 3 + kh;
            if ((unsigned)h >= 224u) continue;
            const float* xr = xp + h * 224;
            const float* wr = wr0 + kh * 7;
#pragma unroll
            for (int kw = 0; kw < 7; kw++) {
                int w = ow * 2 - 3 + kw;
                if ((unsigned)w < 224u) acc = fmaf(wr[kw], xr[w], acc);
            }
        }
    }
    tok[gid] = fmaxf(acc, 0.f);
}

__global__ __launch_bounds__(256) void k_pool_z(const float* __restrict__ tok,
                                                const float* __restrict__ pos,
                                                float* __restrict__ z) {
    int gid = blockIdx.x * 256 + threadIdx.x;  // 3,211,264
    int c = gid % 256;
    int n = (gid / 256) % SEQL;
    int b = gid / (256 * SEQL);
    int oh = n / 56, ow = n % 56;
    const float* tp = tok + (long)(b * 256 + c) * 12544;
    float m = -1e30f;
#pragma unroll
    for (int kh = 0; kh < 3; kh++) {
        int h = oh * 2 - 1 + kh;
        if ((unsigned)h >= 112u) continue;
#pragma unroll
        for (int kw = 0; kw < 3; kw++) {
            int w = ow * 2 - 1 + kw;
            if ((unsigned)w < 112u) m = fmaxf(m, tp[h * 112 + w]);
        }
    }
    z[gid] = m + pos[n * 256 + c];
}

__global__ __launch_bounds__(256) void k_ln(const float* __restrict__ X,
                                            const float* __restrict__ g,
                                            const float* __restrict__ be,
                                            float* __restrict__ out) {
    int wid = threadIdx.x >> 6, lane = threadIdx.x & 63;
    int r = blockIdx.x * 4 + wid;
    const float* xr = X + (long)r * 256;
    float v0 = xr[lane], v1 = xr[lane + 64], v2 = xr[lane + 128], v3 = xr[lane + 192];
    float s = v0 + v1 + v2 + v3;
#pragma unroll
    for (int off = 1; off < 64; off <<= 1) s += __shfl_xor(s, off);
    float mean = s * (1.0f / 256.0f);
    float d0 = v0 - mean, d1 = v1 - mean, d2 = v2 - mean, d3 = v3 - mean;
    float sq = d0 * d0 + d1 * d1 + d2 * d2 + d3 * d3;
#pragma unroll
    for (int off = 1; off < 64; off <<= 1) sq += __shfl_xor(sq, off);
    float rs = rsqrtf(sq * (1.0f / 256.0f) + 1e-5f);
    float* orow = out + (long)r * 256;
    orow[lane]       = d0 * rs * g[lane]       + be[lane];
    orow[lane + 64]  = d1 * rs * g[lane + 64]  + be[lane + 64];
    orow[lane + 128] = d2 * rs * g[lane + 128] + be[lane + 128];
    orow[lane + 192] = d3 * rs * g[lane + 192] + be[lane + 192];
}

// fp32 GEMM: C[M,N] = act(A @ W^T + bias) (+C)
__global__ __launch_bounds__(256) void k_gemm(const float* __restrict__ A,
                                              const float* __restrict__ W,
                                              const float* __restrict__ bias,
                                              float* __restrict__ C,
                                              int M, int N, int K,
                                              int dogelu, int resid) {
    __shared__ float As[64 * 33], Ws[64 * 33];
    int tid = threadIdx.x;
    int tx = tid & 15, ty = tid >> 4;
    int n0 = blockIdx.x * 64, m0 = blockIdx.y * 64;
    float c[4][4] = {};
    for (int k0 = 0; k0 < K; k0 += 32) {
        __syncthreads();
#pragma unroll
        for (int e = 0; e < 8; e++) {
            int idx = e * 256 + tid;
            int row = idx >> 5, col = idx & 31;
            As[row * 33 + col] = A[(long)(m0 + row) * K + k0 + col];
            Ws[row * 33 + col] = W[(long)(n0 + row) * K + k0 + col];
        }
        __syncthreads();
#pragma unroll
        for (int kk = 0; kk < 32; kk++) {
            float av[4], wv[4];
#pragma unroll
            for (int i = 0; i < 4; i++) av[i] = As[(ty * 4 + i) * 33 + kk];
#pragma unroll
            for (int j = 0; j < 4; j++) wv[j] = Ws[(tx * 4 + j) * 33 + kk];
#pragma unroll
            for (int i = 0; i < 4; i++)
#pragma unroll
                for (int j = 0; j < 4; j++)
                    c[i][j] = fmaf(av[i], wv[j], c[i][j]);
        }
    }
#pragma unroll
    for (int i = 0; i < 4; i++) {
        int mrow = m0 + ty * 4 + i;
        float* crow = C + (long)mrow * N + n0;
#pragma unroll
        for (int j = 0; j < 4; j++) {
            int n = tx * 4 + j;
            float v = c[i][j] + bias[n0 + n];
            if (dogelu) v = 0.5f * v * (1.0f + erff(v * 0.70710678118654752f));
            if (resid) v += crow[n];
            crow[n] = v;
        }
    }
}

// ---------------- flash attention, bf16 MFMA 16x16x32 ----------------
// block: 256 thr = 4 waves; wave w owns Q rows [16w,16w+16) of a 64-row Q tile.
// LDS holds bf16 pairs packed in u32; row stride 36 u32 (72 bf16) for 2-way-max banks.
__global__ __launch_bounds__(256) void k_flash(const float* __restrict__ qkv,
                                               float* __restrict__ o) {
    __shared__ uint32_t Qs[64 * 36], Ks[64 * 36], Vt[64 * 36];
    __shared__ uint16_t Ps[64 * 72];
    int tid = threadIdx.x;
    int lane = tid & 63, wv = tid >> 6;
    int qt = blockIdx.x, h = blockIdx.y, b = blockIdx.z;
    long base = (long)b * SEQL * 768 + h * 64;
    // stage Q (scaled by 1/8), packed bf16 pairs
    for (int i = tid; i < 2048; i += 256) {
        int d2 = i & 31, r = i >> 5;
        const float* src = qkv + base + (long)(qt * 64 + r) * 768 + 2 * d2;
        Qs[r * 36 + d2] = pack2(src[0] * 0.125f, src[1] * 0.125f);
    }
    int g = lane >> 4, tl = lane & 15;
    int qr0 = wv * 16;
    __syncthreads();
    v8s aq[2];
#pragma unroll
    for (int ks = 0; ks < 2; ks++)
        aq[ks] = *(const v8s*)&Qs[(qr0 + tl) * 36 + ks * 16 + g * 4];

    float m_[4], l_[4];
    f32x4 ov[4];
#pragma unroll
    for (int r = 0; r < 4; r++) { m_[r] = -1e30f; l_[r] = 0.f; }
#pragma unroll
    for (int j = 0; j < 4; j++) ov[j] = (f32x4){0.f, 0.f, 0.f, 0.f};

    for (int kt = 0; kt < 49; kt++) {
        __syncthreads();   // prev iter's K/V reads complete
        for (int i = tid; i < 2048; i += 256) {
            int d2 = i & 31, r = i >> 5;
            const float* kp = qkv + base + (long)(kt * 64 + r) * 768 + 256 + 2 * d2;
            Ks[r * 36 + d2] = pack2(kp[0], kp[1]);
        }
        for (int i = tid; i < 2048; i += 256) {
            int d = i & 63, r2 = i >> 6;
            const float* vp = qkv + base + (long)(kt * 64 + 2 * r2) * 768 + 512 + d;
            Vt[d * 36 + r2] = pack2(vp[0], vp[768]);   // rows 2r2, 2r2+1
        }
        __syncthreads();
        // S = (Q/8) K^T   — wave computes 16x64 strip as 4 C-frags
        f32x4 s[4];
#pragma unroll
        for (int j = 0; j < 4; j++) s[j] = (f32x4){0.f, 0.f, 0.f, 0.f};
#pragma unroll
        for (int ks = 0; ks < 2; ks++) {
#pragma unroll
            for (int j = 0; j < 4; j++) {
                v8s bk = *(const v8s*)&Ks[(j * 16 + tl) * 36 + ks * 16 + g * 4];
                s[j] = __builtin_amdgcn_mfma_f32_16x16x32_bf16(aq[ks], bk, s[j], 0, 0, 0);
            }
        }
        // online softmax; lane handles rows qr0 + g*4 + r
        float alpha[4];
#pragma unroll
        for (int r = 0; r < 4; r++) {
            float mx = fmaxf(fmaxf(s[0][r], s[1][r]), fmaxf(s[2][r], s[3][r]));
#pragma unroll
            for (int off = 1; off < 16; off <<= 1) mx = fmaxf(mx, __shfl_xor(mx, off));
            float nm = fmaxf(m_[r], mx);
            alpha[r] = __expf(m_[r] - nm);
            float rs = 0.f;
#pragma unroll
            for (int j = 0; j < 4; j++) {
                float p = __expf(s[j][r] - nm);
                s[j][r] = p; rs += p;
            }
#pragma unroll
            for (int off = 1; off < 16; off <<= 1) rs += __shfl_xor(rs, off);
            l_[r] = l_[r] * alpha[r] + rs;
            m_[r] = nm;
        }
#pragma unroll
        for (int j = 0; j < 4; j++)
#pragma unroll
            for (int r = 0; r < 4; r++) ov[j][r] *= alpha[r];
        // P -> LDS (bf16, A-layout rows owned by this wave only)
#pragma unroll
        for (int j = 0; j < 4; j++)
#pragma unroll
            for (int r = 0; r < 4; r++)
                Ps[(qr0 + g * 4 + r) * 72 + j * 16 + tl] = bf16u(s[j][r]);
        // O += P V   (same-wave LDS RAW: DS pipe processes in order)
#pragma unroll
        for (int ks = 0; ks < 2; ks++) {
            v8s ap = *(const v8s*)&Ps[(qr0 + tl) * 72 + ks * 32 + g * 8];
#pragma unroll
            for (int jd = 0; jd < 4; jd++) {
                v8s bv = *(const v8s*)&Vt[(jd * 16 + tl) * 36 + ks * 16 + g * 4];
                ov[jd] = __builtin_amdgcn_mfma_f32_16x16x32_bf16(ap, bv, ov[jd], 0, 0, 0);
            }
        }
    }
    long ob = ((long)b * SEQL + qt * 64) * 256 + h * 64;
#pragma unroll
    for (int r = 0; r < 4; r++) {
        float inv = 1.0f / l_[r];
        int row = qr0 + g * 4 + r;
#pragma unroll
        for (int jd = 0; jd < 4; jd++)
            o[ob + (long)row * 256 + jd * 16 + tl] = ov[jd][r] * inv;
    }
}

__global__ __launch_bounds__(256) void k_pool_logits(const float* __restrict__ zl,
                                                     const float* __restrict__ pw,
                                                     const float* __restrict__ pb,
                                                     float* __restrict__ lg) {
    int wid = threadIdx.x >> 6, lane = threadIdx.x & 63;
    int r = blockIdx.x * 4 + wid;
    const float* xr = zl + (long)r * 256;
    float a = xr[lane] * pw[lane] + xr[lane + 64] * pw[lane + 64]
            + xr[lane + 128] * pw[lane + 128] + xr[lane + 192] * pw[lane + 192];
#pragma unroll
    for (int off = 1; off < 64; off <<= 1) a += __shfl_xor(a, off);
    if (lane == 0) lg[r] = a + pb[0];
}

__global__ __launch_bounds__(256) void k_pool_softmax(float* __restrict__ lg) {
    __shared__ float red[256];
    int b = blockIdx.x, tid = threadIdx.x;
    float* p = lg + b * SEQL;
    float m = -1e30f;
    for (int i = tid; i < SEQL; i += 256) m = fmaxf(m, p[i]);
    red[tid] = m; __syncthreads();
    for (int s = 128; s > 0; s >>= 1) {
        if (tid < s) red[tid] = fmaxf(red[tid], red[tid + s]);
        __syncthreads();
    }
    float M = red[0]; __syncthreads();
    float sum = 0.f;
    for (int i = tid; i < SEQL; i += 256) sum += expf(p[i] - M);
    red[tid] = sum; __syncthreads();
    for (int s = 128; s > 0; s >>= 1) {
        if (tid < s) red[tid] += red[tid + s];
        __syncthreads();
    }
    float inv = 1.0f / red[0];
    for (int i = tid; i < SEQL; i += 256) p[i] = expf(p[i] - M) * inv;
}

__global__ __launch_bounds__(256) void k_pooled(const float* __restrict__ lg,
                                                const float* __restrict__ zl,
                                                float* __restrict__ pooled) {
    int b = blockIdx.x, d = threadIdx.x;
    const float* zb = zl + (long)b * SEQL * 256;
    const float* ab = lg + b * SEQL;
    float acc = 0.f;
    for (int n = 0; n < SEQL; n++) acc = fmaf(ab[n], zb[(long)n * 256 + d], acc);
    pooled[b * 256 + d] = acc;
}

__global__ __launch_bounds__(512) void k_head(const float* __restrict__ pooled,
                                              const float* __restrict__ hw,
                                              const float* __restrict__ hb,
                                              float* __restrict__ out) {
    int t = threadIdx.x;
    if (t >= 404) return;
    int b = t / 101, c = t % 101;
    float acc = hb[c];
    for (int d = 0; d < 256; d++)
        acc = fmaf(pooled[b * 256 + d], hw[c * 256 + d], acc);
    out[b * 101 + c] = acc;
}

// ---------------------------------------------------------------------------
extern "C" void kernel_launch(void* const* d_in, const int* in_sizes, int n_in,
                              void* d_out, int out_size, void* d_ws, size_t ws_size,
                              hipStream_t stream) {
    (void)in_sizes; (void)n_in; (void)out_size; (void)ws_size;
    const float* x     = (const float*)d_in[0];
    const float* w1    = (const float*)d_in[1];
    const float* w2    = (const float*)d_in[2];
    const float* w3    = (const float*)d_in[3];
    const float* tokw  = (const float*)d_in[4];
    const float* pos   = (const float*)d_in[5];
    const float* ln1s  = (const float*)d_in[6];
    const float* ln1b  = (const float*)d_in[7];
    const float* qkvw  = (const float*)d_in[8];
    const float* qkvb  = (const float*)d_in[9];
    const float* projw = (const float*)d_in[10];
    const float* projb = (const float*)d_in[11];
    const float* ln2s  = (const float*)d_in[12];
    const float* ln2b  = (const float*)d_in[13];
    const float* fc1w  = (const float*)d_in[14];
    const float* fc1b  = (const float*)d_in[15];
    const float* fc2w  = (const float*)d_in[16];
    const float* fc2b  = (const float*)d_in[17];
    const float* lnfs  = (const float*)d_in[18];
    const float* lnfb  = (const float*)d_in[19];
    const float* poolw = (const float*)d_in[20];
    const float* poolb = (const float*)d_in[21];
    const float* headw = (const float*)d_in[22];
    const float* headb = (const float*)d_in[23];
    float* out = (float*)d_out;
    char* ws = (char*)d_ws;

    // ---- workspace layout (phase-aliased) ----
    uint8_t*  B1  = (uint8_t*)(ws + 0);                    // 115,605,504
    uint64_t* B1P = (uint64_t*)(ws + 115605504);           //  14,450,688
    uint8_t*  B2  = (uint8_t*)(ws + 130056192);            //  19,267,584
    uint32_t* B2P = (uint32_t*)(ws + 149323776);           //   2,408,448
    float*    W1T = (float*)(ws + 151732224);              //     112,896
    uint64_t* WP2 = (uint64_t*)(ws + 151845120);
    uint64_t* WN2 = (uint64_t*)(ws + 151882752);
    uint32_t* WP3 = (uint32_t*)(ws + 151920384);
    uint32_t* WN3 = (uint32_t*)(ws + 151922432);
    float*    H3  = (float*)(ws + 151924480);              //   2,408,448
    float*    TOK = (float*)(ws + 0);                      //  51,380,224
    float*    Z   = (float*)(ws + 51380224);
    float*    F   = (float*)(ws + 64225280);
    float*    G   = (float*)(ws + 77070336);               //  38,535,168
    float*    O   = (float*)(ws + 115605504);
    float*    MLP = (float*)(ws + 128450560);
    float*    LG  = (float*)(ws + 154140672);
    float*    PL  = (float*)(ws + 154190848);

    k_prep_w1t<<<(28224 + 255) / 256, 256, 0, stream>>>(w1, W1T);
    k_prep_masks2<<<(4704 + 255) / 256, 256, 0, stream>>>(w2, WP2, WN2);
    k_prep_masks3<<<(441 + 255) / 256, 256, 0, stream>>>(w3, WP3, WN3);

    k_conv1<<<dim3(224, 9, 4), 256, 0, stream>>>(x, W1T, B1);
    k_pack64<<<7056, 256, 0, stream>>>(B1, B1P);
    k_conv2<<<75264, 256, 0, stream>>>(B1P, WP2, WN2, B2);
    k_pack32<<<2352, 256, 0, stream>>>(B2, B2P);
    k_conv3<<<2352, 256, 0, stream>>>(B2P, WP3, WN3, H3);
    k_tok<<<50176, 256, 0, stream>>>(H3, tokw, TOK);
    k_pool_z<<<12544, 256, 0, stream>>>(TOK, pos, Z);

    for (int l = 0; l < 7; l++) {
        k_ln<<<3136, 256, 0, stream>>>(Z, ln1s + l * 256, ln1b + l * 256, F);
        k_gemm<<<dim3(12, 196), 256, 0, stream>>>(F, qkvw + (long)l * 196608,
                                                  qkvb + l * 768, G,
                                                  12544, 768, 256, 0, 0);
        k_flash<<<dim3(49, 4, 4), 256, 0, stream>>>(G, O);
        k_gemm<<<dim3(4, 196), 256, 0, stream>>>(O, projw + (long)l * 65536,
                                                 projb + l * 256, Z,
                                                 12544, 256, 256, 0, 1);
        k_ln<<<3136, 256, 0, stream>>>(Z, ln2s + l * 256, ln2b + l * 256, F);
        k_gemm<<<dim3(8, 196), 256, 0, stream>>>(F, fc1w + (long)l * 131072,
                                                 fc1b + l * 512, MLP,
                                                 12544, 512, 256, 1, 0);
        k_gemm<<<dim3(4, 196), 256, 0, stream>>>(MLP, fc2w + (long)l * 131072,
                                                 fc2b + l * 256, Z,
                                                 12544, 256, 512, 0, 1);
    }

    k_ln<<<3136, 256, 0, stream>>>(Z, lnfs, lnfb, F);
    k_pool_logits<<<3136, 256, 0, stream>>>(F, poolw, poolb, LG);
    k_pool_softmax<<<4, 256, 0, stream>>>(LG);
    k_pooled<<<4, 256, 0, stream>>>(LG, F, PL);
    k_head<<<1, 512, 0, stream>>>(PL, headw, headb, out);
}

// Round 3
// 6123.163 us; speedup vs baseline: 5.0596x; 1.9594x over previous
//
#include <hip/hip_runtime.h>
#include <hip/hip_bf16.h>
#include <cstdint>

#define SEQL 3136

typedef __attribute__((ext_vector_type(8))) short v8s;
typedef __attribute__((ext_vector_type(4))) float f32x4;

__device__ __forceinline__ uint16_t bf16u(float f) {
    uint32_t u = __float_as_uint(f);
    uint32_t r = u + 0x7fff + ((u >> 16) & 1);   // RNE
    return (uint16_t)(r >> 16);
}

// ---------------- prep kernels ----------------
// w1 sign, transposed to [ic][kd][r(49)][oc(64)]
__global__ __launch_bounds__(256) void k_prep_w1t(const float* __restrict__ w1,
                                                  float* __restrict__ wt) {
    int i = blockIdx.x * 256 + threadIdx.x;   // 28224
    if (i >= 28224) return;
    int oc = i & 63; int t = i >> 6;
    int r = t % 49; int ickd = t / 49;
    int ic = ickd / 3, kd = ickd % 3;
    float v = w1[(((oc * 3 + ic) * 3 + kd) * 49) + r];
    wt[i] = (v > 0.f) ? 1.f : ((v < 0.f) ? -1.f : 0.f);
}

__global__ __launch_bounds__(256) void k_prep_masks2(const float* __restrict__ w2,
                                                     uint64_t* __restrict__ wp,
                                                     uint64_t* __restrict__ wn) {
    int i = blockIdx.x * 256 + threadIdx.x;
    if (i >= 32 * 147) return;
    int oc = i / 147, r = i % 147;
    uint64_t p = 0, n = 0;
    for (int ic = 0; ic < 64; ic++) {
        float v = w2[(long)oc * 9408 + (long)ic * 147 + r];
        if (v > 0.f) p |= (1ull << ic);
        else if (v < 0.f) n |= (1ull << ic);
    }
    wp[i] = p; wn[i] = n;
}

__global__ __launch_bounds__(256) void k_prep_masks3(const float* __restrict__ w3,
                                                     uint32_t* __restrict__ wp,
                                                     uint32_t* __restrict__ wn) {
    int i = blockIdx.x * 256 + threadIdx.x;
    if (i >= 3 * 147) return;
    int oc = i / 147, r = i % 147;
    uint32_t p = 0, n = 0;
    for (int ic = 0; ic < 32; ic++) {
        float v = w3[(long)oc * 4704 + (long)ic * 147 + r];
        if (v > 0.f) p |= (1u << ic);
        else if (v < 0.f) n |= (1u << ic);
    }
    wp[i] = p; wn[i] = n;
}

__global__ __launch_bounds__(256) void k_cvt(const float* __restrict__ s,
                                             uint16_t* __restrict__ d, int n) {
    int i = blockIdx.x * 256 + threadIdx.x;
    if (i < n) d[i] = bf16u(s[i]);
}

// ---------------- conv1: LDS-tiled, outputs packed u64 bits ----------------
__global__ __launch_bounds__(256) void k_conv1(const float* __restrict__ x,
                                               const float* __restrict__ wt,
                                               uint64_t* __restrict__ b1p) {
    __shared__ float xs[14616];    // 3ic*3kd*7kh*232
    __shared__ float wsh[3136];    // 49*64
    __shared__ unsigned long long wordarr[224];
    int tid = threadIdx.x;
    int oh = blockIdx.x, od = blockIdx.y, b = blockIdx.z;
    for (int i = tid; i < 14616; i += 256) {
        int col = i % 232; int t = i / 232;
        int kh = t % 7; t /= 7;
        int kd = t % 3; int ic = t / 3;
        int d = od * 3 - 1 + kd;
        int hh = oh - 3 + kh;
        int ww = col - 3;
        float v = 0.f;
        if ((unsigned)d < 27u && (unsigned)hh < 224u && (unsigned)ww < 224u)
            v = x[((long)(b * 3 + ic) * 27 + d) * 50176 + hh * 224 + ww];
        xs[i] = v;
    }
    if (tid < 224) wordarr[tid] = 0ull;
    int tx = tid & 15, ty = tid >> 4;
    float acc[4][14];
#pragma unroll
    for (int j = 0; j < 4; j++)
#pragma unroll
        for (int o2 = 0; o2 < 14; o2++) acc[j][o2] = 0.f;

    for (int ickd = 0; ickd < 9; ickd++) {
        __syncthreads();
        const float* wsrc = wt + ickd * 49 * 64;
        for (int i = tid; i < 3136; i += 256) wsh[i] = wsrc[i];
        __syncthreads();
        const float* xb = xs + ickd * 7 * 232;
#pragma unroll
        for (int kh = 0; kh < 7; kh++) {
            const float* row = xb + kh * 232 + tx * 14;
            float xv[20];
#pragma unroll
            for (int t = 0; t < 20; t++) xv[t] = row[t];
            const float* wrow = wsh + kh * 7 * 64 + ty * 4;
#pragma unroll
            for (int kw = 0; kw < 7; kw++) {
                float w0 = wrow[kw * 64 + 0], w1v = wrow[kw * 64 + 1];
                float w2v = wrow[kw * 64 + 2], w3v = wrow[kw * 64 + 3];
#pragma unroll
                for (int o2 = 0; o2 < 14; o2++) {
                    float xvv = xv[o2 + kw];
                    acc[0][o2] = fmaf(w0, xvv, acc[0][o2]);
                    acc[1][o2] = fmaf(w1v, xvv, acc[1][o2]);
                    acc[2][o2] = fmaf(w2v, xvv, acc[2][o2]);
                    acc[3][o2] = fmaf(w3v, xvv, acc[3][o2]);
                }
            }
        }
    }
    int ow0 = tx * 14;
#pragma unroll
    for (int o2 = 0; o2 < 14; o2++) {
        unsigned long long nib =
            (unsigned long long)((acc[0][o2] > 0.f) | ((acc[1][o2] > 0.f) << 1) |
                                 ((acc[2][o2] > 0.f) << 2) | ((acc[3][o2] > 0.f) << 3));
        if (nib) atomicOr(&wordarr[ow0 + o2], nib << (ty * 4));
    }
    __syncthreads();
    if (tid < 224)
        b1p[(((long)b * 9 + od) * 224 + oh) * 224 + tid] = wordarr[tid];
}

// ---------------- conv2: LDS patch + popcount, packed u32 out ----------------
__global__ __launch_bounds__(256) void k_conv2(const uint64_t* __restrict__ bp1,
                                               const uint64_t* __restrict__ wp,
                                               const uint64_t* __restrict__ wn,
                                               uint32_t* __restrict__ b2p) {
    __shared__ uint64_t xs[21 * 232];   // 39,144 B
    __shared__ uint32_t obits[224];
    int tid = threadIdx.x;
    int oh = blockIdx.x, od = blockIdx.y, b = blockIdx.z;
    for (int i = tid; i < 21 * 232; i += 256) {
        int col = i % 232; int t = i / 232;
        int kh = t % 7; int kd = t / 7;
        int d = od * 3 - 1 + kd;
        int h = oh - 3 + kh;
        int w = col - 3;
        uint64_t v = 0;
        if ((unsigned)d < 9u && (unsigned)h < 224u && (unsigned)w < 224u)
            v = bp1[(((long)b * 9 + d) * 224 + h) * 224 + w];
        xs[i] = v;
    }
    if (tid < 224) obits[tid] = 0;
    __syncthreads();
    int tx = tid & 15, ty = tid >> 4;
    int ow0 = tx * 14, oc0 = ty * 2;
    int acc0[14], acc1[14];
#pragma unroll
    for (int o2 = 0; o2 < 14; o2++) { acc0[o2] = 0; acc1[o2] = 0; }
    for (int kd = 0; kd < 3; kd++) {
#pragma unroll
        for (int kh = 0; kh < 7; kh++) {
            const uint64_t* row = &xs[(kd * 7 + kh) * 232 + ow0];
            uint64_t xv[20];
#pragma unroll
            for (int t = 0; t < 20; t++) xv[t] = row[t];
            int rbase = kd * 49 + kh * 7;
#pragma unroll
            for (int kw = 0; kw < 7; kw++) {
                uint64_t p0 = wp[oc0 * 147 + rbase + kw];
                uint64_t n0 = wn[oc0 * 147 + rbase + kw];
                uint64_t p1 = wp[(oc0 + 1) * 147 + rbase + kw];
                uint64_t n1 = wn[(oc0 + 1) * 147 + rbase + kw];
#pragma unroll
                for (int o2 = 0; o2 < 14; o2++) {
                    uint64_t bits = xv[o2 + kw];
                    acc0[o2] += __popcll(bits & p0) - __popcll(bits & n0);
                    acc1[o2] += __popcll(bits & p1) - __popcll(bits & n1);
                }
            }
        }
    }
#pragma unroll
    for (int o2 = 0; o2 < 14; o2++) {
        uint32_t v = (uint32_t)((acc0[o2] > 0) | ((acc1[o2] > 0) << 1));
        if (v) atomicOr(&obits[ow0 + o2], v << oc0);
    }
    __syncthreads();
    if (tid < 224)
        b2p[(((long)b * 3 + od) * 224 + oh) * 224 + tid] = obits[tid];
}

// conv3 via popcount -> fp32 relu count
__global__ __launch_bounds__(256) void k_conv3(const uint32_t* __restrict__ bp2,
                                               const uint32_t* __restrict__ wp,
                                               const uint32_t* __restrict__ wn,
                                               float* __restrict__ h3) {
    int gid = blockIdx.x * 256 + threadIdx.x;  // 602,112
    int q = gid;
    int ow = q % 224; q /= 224;
    int oh = q % 224; q /= 224;
    int oc = q % 3;   int b = q / 3;
    int acc = 0;
    for (int kd = 0; kd < 3; kd++) {
        int d = kd - 1;
        if ((unsigned)d >= 3u) continue;
        for (int kh = 0; kh < 7; kh++) {
            int h = oh - 3 + kh;
            if ((unsigned)h >= 224u) continue;
            const uint32_t* bp = bp2 + ((long)(b * 3 + d) * 224 + h) * 224;
            const uint32_t* mp = wp + ((oc * 3 + kd) * 7 + kh) * 7;
            const uint32_t* mn = wn + ((oc * 3 + kd) * 7 + kh) * 7;
#pragma unroll
            for (int kw = 0; kw < 7; kw++) {
                int w = ow - 3 + kw;
                if ((unsigned)w < 224u) {
                    uint32_t bits = bp[w];
                    acc += __popc(bits & mp[kw]) - __popc(bits & mn[kw]);
                }
            }
        }
    }
    h3[gid] = fmaxf((float)acc, 0.f);
}

// ---------------- tokenizer conv, LDS-tiled; thread = oc ----------------
__global__ __launch_bounds__(256) void k_tok(const float* __restrict__ h3,
                                             const float* __restrict__ wt,
                                             float* __restrict__ tok) {
    __shared__ float xs[3 * 7 * 232];   // 19,488 B
    int tid = threadIdx.x;
    int oh = blockIdx.x, b = blockIdx.y;
    for (int i = tid; i < 3 * 7 * 232; i += 256) {
        int col = i % 232; int t = i / 232;
        int kh = t % 7; int ic = t / 7;
        int ih = oh * 2 - 3 + kh;
        int iw = col - 3;
        float v = 0.f;
        if ((unsigned)ih < 224u && (unsigned)iw < 224u)
            v = h3[((long)(b * 3 + ic) * 50176) + ih * 224 + iw];
        xs[i] = v;
    }
    __syncthreads();
    int oc = tid;
    float* orow = tok + ((long)(b * 256 + oc) * 112 + oh) * 112;
    for (int chunk = 0; chunk < 4; chunk++) {
        int ow0 = chunk * 28;
        float acc[28];
#pragma unroll
        for (int o2 = 0; o2 < 28; o2++) acc[o2] = 0.f;
        for (int ic = 0; ic < 3; ic++) {
#pragma unroll
            for (int kh = 0; kh < 7; kh++) {
                const float* row = &xs[(ic * 7 + kh) * 232 + ow0 * 2];
                float xv[61];
#pragma unroll
                for (int t = 0; t < 61; t++) xv[t] = row[t];
                const float* wr = wt + (oc * 3 + ic) * 49 + kh * 7;
                float w[7];
#pragma unroll
                for (int kw = 0; kw < 7; kw++) w[kw] = wr[kw];
#pragma unroll
                for (int kw = 0; kw < 7; kw++)
#pragma unroll
                    for (int o2 = 0; o2 < 28; o2++)
                        acc[o2] = fmaf(w[kw], xv[2 * o2 + kw], acc[o2]);
            }
        }
#pragma unroll
        for (int o2 = 0; o2 < 28; o2++) orow[ow0 + o2] = fmaxf(acc[o2], 0.f);
    }
}

// maxpool 3x3 s2 p1 + pos_emb, write z[b][n][c] fp32
__global__ __launch_bounds__(256) void k_pool_z(const float* __restrict__ tok,
                                                const float* __restrict__ pos,
                                                float* __restrict__ z) {
    int gid = blockIdx.x * 256 + threadIdx.x;  // 3,211,264
    int c = gid % 256;
    int n = (gid / 256) % SEQL;
    int b = gid / (256 * SEQL);
    int oh = n / 56, ow = n % 56;
    const float* tp = tok + (long)(b * 256 + c) * 12544;
    float m = -1e30f;
#pragma unroll
    for (int kh = 0; kh < 3; kh++) {
        int h = oh * 2 - 1 + kh;
        if ((unsigned)h >= 112u) continue;
#pragma unroll
        for (int kw = 0; kw < 3; kw++) {
            int w = ow * 2 - 1 + kw;
            if ((unsigned)w < 112u) m = fmaxf(m, tp[h * 112 + w]);
        }
    }
    z[gid] = m + pos[n * 256 + c];
}

// layernorm over 256; out bf16 (obf=1) or fp32
__global__ __launch_bounds__(256) void k_ln(const float* __restrict__ X,
                                            const float* __restrict__ g,
                                            const float* __restrict__ be,
                                            void* __restrict__ outp, int obf) {
    int wid = threadIdx.x >> 6, lane = threadIdx.x & 63;
    int r = blockIdx.x * 4 + wid;
    const float* xr = X + (long)r * 256;
    float v0 = xr[lane], v1 = xr[lane + 64], v2 = xr[lane + 128], v3 = xr[lane + 192];
    float s = v0 + v1 + v2 + v3;
#pragma unroll
    for (int off = 1; off < 64; off <<= 1) s += __shfl_xor(s, off);
    float mean = s * (1.0f / 256.0f);
    float d0 = v0 - mean, d1 = v1 - mean, d2 = v2 - mean, d3 = v3 - mean;
    float sq = d0 * d0 + d1 * d1 + d2 * d2 + d3 * d3;
#pragma unroll
    for (int off = 1; off < 64; off <<= 1) sq += __shfl_xor(sq, off);
    float rs = rsqrtf(sq * (1.0f / 256.0f) + 1e-5f);
    float o0 = d0 * rs * g[lane]       + be[lane];
    float o1 = d1 * rs * g[lane + 64]  + be[lane + 64];
    float o2 = d2 * rs * g[lane + 128] + be[lane + 128];
    float o3 = d3 * rs * g[lane + 192] + be[lane + 192];
    if (obf) {
        uint16_t* orow = (uint16_t*)outp + (long)r * 256;
        orow[lane] = bf16u(o0); orow[lane + 64] = bf16u(o1);
        orow[lane + 128] = bf16u(o2); orow[lane + 192] = bf16u(o3);
    } else {
        float* orow = (float*)outp + (long)r * 256;
        orow[lane] = o0; orow[lane + 64] = o1;
        orow[lane + 128] = o2; orow[lane + 192] = o3;
    }
}

// ---------------- bf16 MFMA GEMM: 128x128 tile, 4 waves ----------------
// C = op(A[M,K] @ W[N,K]^T + bias); resid: C fp32 +=; else C bf16 store (opt gelu)
__global__ __launch_bounds__(256) void k_gemm(const uint16_t* __restrict__ A,
                                              const uint16_t* __restrict__ W,
                                              const float* __restrict__ bias,
                                              void* __restrict__ C,
                                              int M, int N, int K,
                                              int dogelu, int resid) {
    __shared__ uint16_t As[128 * 40], Bs[128 * 40];
    int tid = threadIdx.x;
    int lane = tid & 63, wave = tid >> 6;
    int wm = wave >> 1, wn = wave & 1;
    int m0 = blockIdx.y * 128, n0 = blockIdx.x * 128;
    f32x4 acc[4][4];
#pragma unroll
    for (int i = 0; i < 4; i++)
#pragma unroll
        for (int j = 0; j < 4; j++) acc[i][j] = (f32x4){0.f, 0.f, 0.f, 0.f};
    int rl = lane & 15, kq = (lane >> 4) * 8;
    for (int k0 = 0; k0 < K; k0 += 32) {
        __syncthreads();
#pragma unroll
        for (int c = 0; c < 2; c++) {
            int idx = c * 256 + tid;
            int row = idx >> 2, k8 = (idx & 3) * 8;
            *(uint4*)&As[row * 40 + k8] = *(const uint4*)&A[(long)(m0 + row) * K + k0 + k8];
            *(uint4*)&Bs[row * 40 + k8] = *(const uint4*)&W[(long)(n0 + row) * K + k0 + k8];
        }
        __syncthreads();
        v8s a[4], bb[4];
#pragma unroll
        for (int i = 0; i < 4; i++) a[i] = *(const v8s*)&As[(wm * 64 + i * 16 + rl) * 40 + kq];
#pragma unroll
        for (int j = 0; j < 4; j++) bb[j] = *(const v8s*)&Bs[(wn * 64 + j * 16 + rl) * 40 + kq];
#pragma unroll
        for (int i = 0; i < 4; i++)
#pragma unroll
            for (int j = 0; j < 4; j++)
                acc[i][j] = __builtin_amdgcn_mfma_f32_16x16x32_bf16(a[i], bb[j], acc[i][j], 0, 0, 0);
    }
    int rq = (lane >> 4) * 4;
#pragma unroll
    for (int i = 0; i < 4; i++) {
#pragma unroll
        for (int j = 0; j < 4; j++) {
            int col = n0 + wn * 64 + j * 16 + rl;
            float bval = bias[col];
#pragma unroll
            for (int r = 0; r < 4; r++) {
                int row = m0 + wm * 64 + i * 16 + rq + r;
                float v = acc[i][j][r] + bval;
                if (dogelu) v = 0.5f * v * (1.0f + erff(v * 0.70710678118654752f));
                if (resid) ((float*)C)[(long)row * N + col] += v;
                else ((uint16_t*)C)[(long)row * N + col] = bf16u(v);
            }
        }
    }
}

// ---------------- flash attention, bf16 in (G), bf16 out (O) ----------------
__global__ __launch_bounds__(256) void k_flash(const uint16_t* __restrict__ G,
                                               uint16_t* __restrict__ o) {
    __shared__ uint32_t Qs[64 * 36], Ks[64 * 36], Vt[64 * 36];
    __shared__ uint16_t Ps[64 * 72];
    int tid = threadIdx.x;
    int lane = tid & 63, wv = tid >> 6;
    int qt = blockIdx.x, h = blockIdx.y, b = blockIdx.z;
    long base = (long)b * SEQL * 768 + h * 64;
    for (int i = tid; i < 2048; i += 256) {
        int d2 = i & 31, r = i >> 5;
        Qs[r * 36 + d2] = *(const uint32_t*)&G[base + (long)(qt * 64 + r) * 768 + 2 * d2];
    }
    int g = lane >> 4, tl = lane & 15;
    int qr0 = wv * 16;
    __syncthreads();
    v8s aq[2];
#pragma unroll
    for (int ks = 0; ks < 2; ks++)
        aq[ks] = *(const v8s*)&Qs[(qr0 + tl) * 36 + ks * 16 + g * 4];

    float m_[4], l_[4];
    f32x4 ov[4];
#pragma unroll
    for (int r = 0; r < 4; r++) { m_[r] = -1e30f; l_[r] = 0.f; }
#pragma unroll
    for (int j = 0; j < 4; j++) ov[j] = (f32x4){0.f, 0.f, 0.f, 0.f};

    for (int kt = 0; kt < 49; kt++) {
        __syncthreads();
        for (int i = tid; i < 2048; i += 256) {
            int d2 = i & 31, r = i >> 5;
            Ks[r * 36 + d2] = *(const uint32_t*)&G[base + (long)(kt * 64 + r) * 768 + 256 + 2 * d2];
        }
        for (int i = tid; i < 2048; i += 256) {
            int d = i & 63, r2 = i >> 6;
            uint32_t lo = G[base + (long)(kt * 64 + 2 * r2) * 768 + 512 + d];
            uint32_t hi = G[base + (long)(kt * 64 + 2 * r2 + 1) * 768 + 512 + d];
            Vt[d * 36 + r2] = lo | (hi << 16);
        }
        __syncthreads();
        f32x4 s[4];
#pragma unroll
        for (int j = 0; j < 4; j++) s[j] = (f32x4){0.f, 0.f, 0.f, 0.f};
#pragma unroll
        for (int ks = 0; ks < 2; ks++) {
#pragma unroll
            for (int j = 0; j < 4; j++) {
                v8s bk = *(const v8s*)&Ks[(j * 16 + tl) * 36 + ks * 16 + g * 4];
                s[j] = __builtin_amdgcn_mfma_f32_16x16x32_bf16(aq[ks], bk, s[j], 0, 0, 0);
            }
        }
        float alpha[4];
#pragma unroll
        for (int r = 0; r < 4; r++) {
            float s0 = s[0][r] * 0.125f, s1 = s[1][r] * 0.125f;
            float s2 = s[2][r] * 0.125f, s3 = s[3][r] * 0.125f;
            s[0][r] = s0; s[1][r] = s1; s[2][r] = s2; s[3][r] = s3;
            float mx = fmaxf(fmaxf(s0, s1), fmaxf(s2, s3));
#pragma unroll
            for (int off = 1; off < 16; off <<= 1) mx = fmaxf(mx, __shfl_xor(mx, off));
            float nm = fmaxf(m_[r], mx);
            alpha[r] = __expf(m_[r] - nm);
            float rs = 0.f;
#pragma unroll
            for (int j = 0; j < 4; j++) {
                float p = __expf(s[j][r] - nm);
                s[j][r] = p; rs += p;
            }
#pragma unroll
            for (int off = 1; off < 16; off <<= 1) rs += __shfl_xor(rs, off);
            l_[r] = l_[r] * alpha[r] + rs;
            m_[r] = nm;
        }
#pragma unroll
        for (int j = 0; j < 4; j++)
#pragma unroll
            for (int r = 0; r < 4; r++) ov[j][r] *= alpha[r];
#pragma unroll
        for (int j = 0; j < 4; j++)
#pragma unroll
            for (int r = 0; r < 4; r++)
                Ps[(qr0 + g * 4 + r) * 72 + j * 16 + tl] = bf16u(s[j][r]);
#pragma unroll
        for (int ks = 0; ks < 2; ks++) {
            v8s ap = *(const v8s*)&Ps[(qr0 + tl) * 72 + ks * 32 + g * 8];
#pragma unroll
            for (int jd = 0; jd < 4; jd++) {
                v8s bv = *(const v8s*)&Vt[(jd * 16 + tl) * 36 + ks * 16 + g * 4];
                ov[jd] = __builtin_amdgcn_mfma_f32_16x16x32_bf16(ap, bv, ov[jd], 0, 0, 0);
            }
        }
    }
    long ob = ((long)b * SEQL + qt * 64) * 256 + h * 64;
#pragma unroll
    for (int r = 0; r < 4; r++) {
        float inv = 1.0f / l_[r];
        int row = qr0 + g * 4 + r;
#pragma unroll
        for (int jd = 0; jd < 4; jd++)
            o[ob + (long)row * 256 + jd * 16 + tl] = bf16u(ov[jd][r] * inv);
    }
}

__global__ __launch_bounds__(256) void k_pool_logits(const float* __restrict__ zl,
                                                     const float* __restrict__ pw,
                                                     const float* __restrict__ pb,
                                                     float* __restrict__ lg) {
    int wid = threadIdx.x >> 6, lane = threadIdx.x & 63;
    int r = blockIdx.x * 4 + wid;
    const float* xr = zl + (long)r * 256;
    float a = xr[lane] * pw[lane] + xr[lane + 64] * pw[lane + 64]
            + xr[lane + 128] * pw[lane + 128] + xr[lane + 192] * pw[lane + 192];
#pragma unroll
    for (int off = 1; off < 64; off <<= 1) a += __shfl_xor(a, off);
    if (lane == 0) lg[r] = a + pb[0];
}

__global__ __launch_bounds__(256) void k_pool_softmax(float* __restrict__ lg) {
    __shared__ float red[256];
    int b = blockIdx.x, tid = threadIdx.x;
    float* p = lg + b * SEQL;
    float m = -1e30f;
    for (int i = tid; i < SEQL; i += 256) m = fmaxf(m, p[i]);
    red[tid] = m; __syncthreads();
    for (int s = 128; s > 0; s >>= 1) {
        if (tid < s) red[tid] = fmaxf(red[tid], red[tid + s]);
        __syncthreads();
    }
    float M = red[0]; __syncthreads();
    float sum = 0.f;
    for (int i = tid; i < SEQL; i += 256) sum += expf(p[i] - M);
    red[tid] = sum; __syncthreads();
    for (int s = 128; s > 0; s >>= 1) {
        if (tid < s) red[tid] += red[tid + s];
        __syncthreads();
    }
    float inv = 1.0f / red[0];
    for (int i = tid; i < SEQL; i += 256) p[i] = expf(p[i] - M) * inv;
}

__global__ __launch_bounds__(256) void k_pooled(const float* __restrict__ lg,
                                                const float* __restrict__ zl,
                                                float* __restrict__ pooled) {
    int b = blockIdx.x, d = threadIdx.x;
    const float* zb = zl + (long)b * SEQL * 256;
    const float* ab = lg + b * SEQL;
    float acc = 0.f;
    for (int n = 0; n < SEQL; n++) acc = fmaf(ab[n], zb[(long)n * 256 + d], acc);
    pooled[b * 256 + d] = acc;
}

__global__ __launch_bounds__(512) void k_head(const float* __restrict__ pooled,
                                              const float* __restrict__ hw,
                                              const float* __restrict__ hb,
                                              float* __restrict__ out) {
    int t = threadIdx.x;
    if (t >= 404) return;
    int b = t / 101, c = t % 101;
    float acc = hb[c];
    for (int d = 0; d < 256; d++)
        acc = fmaf(pooled[b * 256 + d], hw[c * 256 + d], acc);
    out[b * 101 + c] = acc;
}

// ---------------------------------------------------------------------------
extern "C" void kernel_launch(void* const* d_in, const int* in_sizes, int n_in,
                              void* d_out, int out_size, void* d_ws, size_t ws_size,
                              hipStream_t stream) {
    (void)in_sizes; (void)n_in; (void)out_size; (void)ws_size;
    const float* x     = (const float*)d_in[0];
    const float* w1    = (const float*)d_in[1];
    const float* w2    = (const float*)d_in[2];
    const float* w3    = (const float*)d_in[3];
    const float* tokw  = (const float*)d_in[4];
    const float* pos   = (const float*)d_in[5];
    const float* ln1s  = (const float*)d_in[6];
    const float* ln1b  = (const float*)d_in[7];
    const float* qkvw  = (const float*)d_in[8];
    const float* qkvb  = (const float*)d_in[9];
    const float* projw = (const float*)d_in[10];
    const float* projb = (const float*)d_in[11];
    const float* ln2s  = (const float*)d_in[12];
    const float* ln2b  = (const float*)d_in[13];
    const float* fc1w  = (const float*)d_in[14];
    const float* fc1b  = (const float*)d_in[15];
    const float* fc2w  = (const float*)d_in[16];
    const float* fc2b  = (const float*)d_in[17];
    const float* lnfs  = (const float*)d_in[18];
    const float* lnfb  = (const float*)d_in[19];
    const float* poolw = (const float*)d_in[20];
    const float* poolb = (const float*)d_in[21];
    const float* headw = (const float*)d_in[22];
    const float* headb = (const float*)d_in[23];
    float* out = (float*)d_out;
    char* ws = (char*)d_ws;

    // ---- workspace layout ----
    uint64_t* B1P = (uint64_t*)(ws + 0);                  // 14,450,688
    uint32_t* B2P = (uint32_t*)(ws + 14450688);           //  2,408,448
    float*    H3  = (float*)(ws + 16859136);              //  2,408,448
    float*    W1T = (float*)(ws + 19267584);              //    112,896
    uint64_t* WP2 = (uint64_t*)(ws + 19380480);
    uint64_t* WN2 = (uint64_t*)(ws + 19418112);
    uint32_t* WP3 = (uint32_t*)(ws + 19455744);
    uint32_t* WN3 = (uint32_t*)(ws + 19457792);
    uint16_t* WQb = (uint16_t*)(ws + 19460096);           //  2,752,512
    uint16_t* WPb = (uint16_t*)(ws + 22212608);           //    917,504
    uint16_t* W1b = (uint16_t*)(ws + 23130112);           //  1,835,008
    uint16_t* W2b = (uint16_t*)(ws + 24965120);           //  1,835,008
    float*    TOK = (float*)(ws + 26800128);              // 51,380,224
    float*    Ffin= (float*)(ws + 26800128);              // aliases TOK (dead)
    float*    Z   = (float*)(ws + 78180352);              // 12,845,056
    uint16_t* Fbf = (uint16_t*)(ws + 91025408);           //  6,422,528
    uint16_t* Gbf = (uint16_t*)(ws + 97447936);           // 19,267,584
    uint16_t* Obf = (uint16_t*)(ws + 116715520);          //  6,422,528
    uint16_t* MLPb= (uint16_t*)(ws + 123138048);          // 12,845,056
    float*    LG  = (float*)(ws + 135983104);             //     50,176
    float*    PL  = (float*)(ws + 136033280);             //      4,096

    k_prep_w1t<<<111, 256, 0, stream>>>(w1, W1T);
    k_prep_masks2<<<19, 256, 0, stream>>>(w2, WP2, WN2);
    k_prep_masks3<<<2, 256, 0, stream>>>(w3, WP3, WN3);
    k_cvt<<<5376, 256, 0, stream>>>(qkvw, WQb, 1376256);
    k_cvt<<<1792, 256, 0, stream>>>(projw, WPb, 458752);
    k_cvt<<<3584, 256, 0, stream>>>(fc1w, W1b, 917504);
    k_cvt<<<3584, 256, 0, stream>>>(fc2w, W2b, 917504);

    k_conv1<<<dim3(224, 9, 4), 256, 0, stream>>>(x, W1T, B1P);
    k_conv2<<<dim3(224, 3, 4), 256, 0, stream>>>(B1P, WP2, WN2, B2P);
    k_conv3<<<2352, 256, 0, stream>>>(B2P, WP3, WN3, H3);
    k_tok<<<dim3(112, 4), 256, 0, stream>>>(H3, tokw, TOK);
    k_pool_z<<<12544, 256, 0, stream>>>(TOK, pos, Z);

    for (int l = 0; l < 7; l++) {
        k_ln<<<3136, 256, 0, stream>>>(Z, ln1s + l * 256, ln1b + l * 256, Fbf, 1);
        k_gemm<<<dim3(6, 98), 256, 0, stream>>>(Fbf, WQb + (long)l * 196608,
                                                qkvb + l * 768, Gbf,
                                                12544, 768, 256, 0, 0);
        k_flash<<<dim3(49, 4, 4), 256, 0, stream>>>(Gbf, Obf);
        k_gemm<<<dim3(2, 98), 256, 0, stream>>>(Obf, WPb + (long)l * 65536,
                                                projb + l * 256, Z,
                                                12544, 256, 256, 0, 1);
        k_ln<<<3136, 256, 0, stream>>>(Z, ln2s + l * 256, ln2b + l * 256, Fbf, 1);
        k_gemm<<<dim3(4, 98), 256, 0, stream>>>(Fbf, W1b + (long)l * 131072,
                                                fc1b + l * 512, MLPb,
                                                12544, 512, 256, 1, 0);
        k_gemm<<<dim3(2, 98), 256, 0, stream>>>(MLPb, W2b + (long)l * 131072,
                                                fc2b + l * 256, Z,
                                                12544, 256, 512, 0, 1);
    }

    k_ln<<<3136, 256, 0, stream>>>(Z, lnfs, lnfb, Ffin, 0);
    k_pool_logits<<<3136, 256, 0, stream>>>(Ffin, poolw, poolb, LG);
    k_pool_softmax<<<4, 256, 0, stream>>>(LG);
    k_pooled<<<4, 256, 0, stream>>>(LG, Ffin, PL);
    k_head<<<1, 512, 0, stream>>>(PL, headw, headb, out);
}

// Round 4
// 5997.959 us; speedup vs baseline: 5.1652x; 1.0209x over previous
//
#include <hip/hip_runtime.h>
#include <hip/hip_bf16.h>
#include <cstdint>

#define SEQL 3136

typedef __attribute__((ext_vector_type(8))) short v8s;
typedef __attribute__((ext_vector_type(4))) float f32x4;

__device__ __forceinline__ uint16_t bf16u(float f) {
    uint32_t u = __float_as_uint(f);
    uint32_t r = u + 0x7fff + ((u >> 16) & 1);   // RNE
    return (uint16_t)(r >> 16);
}

// ---------------- merged prep: w1 sign-transpose + conv2/conv3 masks ----------------
__global__ __launch_bounds__(256) void k_prep(const float* __restrict__ w1,
                                              const float* __restrict__ w2,
                                              const float* __restrict__ w3,
                                              float* __restrict__ w1t,
                                              uint64_t* __restrict__ wp2,
                                              uint64_t* __restrict__ wn2,
                                              uint32_t* __restrict__ wp3,
                                              uint32_t* __restrict__ wn3) {
    int gid = blockIdx.x * 256 + threadIdx.x;
    if (gid < 28224) {
        int oc = gid & 63; int t = gid >> 6;
        int r = t % 49; int ickd = t / 49;
        int ic = ickd / 3, kd = ickd % 3;
        float v = w1[(((oc * 3 + ic) * 3 + kd) * 49) + r];
        w1t[gid] = (v > 0.f) ? 1.f : ((v < 0.f) ? -1.f : 0.f);
    } else if (gid < 28224 + 4704) {
        int i = gid - 28224;
        int oc = i / 147, r = i % 147;
        uint64_t p = 0, n = 0;
        for (int ic = 0; ic < 64; ic++) {
            float v = w2[(long)oc * 9408 + (long)ic * 147 + r];
            if (v > 0.f) p |= (1ull << ic);
            else if (v < 0.f) n |= (1ull << ic);
        }
        wp2[i] = p; wn2[i] = n;
    } else if (gid < 28224 + 4704 + 441) {
        int i = gid - 28224 - 4704;
        int oc = i / 147, r = i % 147;
        uint32_t p = 0, n = 0;
        for (int ic = 0; ic < 32; ic++) {
            float v = w3[(long)oc * 4704 + (long)ic * 147 + r];
            if (v > 0.f) p |= (1u << ic);
            else if (v < 0.f) n |= (1u << ic);
        }
        wp3[i] = p; wn3[i] = n;
    }
}

// merged fp32->bf16 weight conversion (qkv | proj | fc1 | fc2)
__global__ __launch_bounds__(256) void k_cvtall(const float* __restrict__ qw,
                                                const float* __restrict__ pw,
                                                const float* __restrict__ f1,
                                                const float* __restrict__ f2,
                                                uint16_t* __restrict__ dq,
                                                uint16_t* __restrict__ dp,
                                                uint16_t* __restrict__ d1,
                                                uint16_t* __restrict__ d2) {
    int i = blockIdx.x * 256 + threadIdx.x;   // total 3,670,016
    if (i < 1376256) dq[i] = bf16u(qw[i]);
    else if (i < 1835008) dp[i - 1376256] = bf16u(pw[i - 1376256]);
    else if (i < 2752512) d1[i - 1835008] = bf16u(f1[i - 1835008]);
    else if (i < 3670016) d2[i - 2752512] = bf16u(f2[i - 2752512]);
}

// ---------------- conv1: double-buffered per-(ic,kd) staging, packed u64 out ----------------
__global__ __launch_bounds__(256) void k_conv1(const float* __restrict__ x,
                                               const float* __restrict__ wt,
                                               uint64_t* __restrict__ b1p) {
    __shared__ float xp[2][1640];      // 7kh x 232 per phase (+pad)
    __shared__ float wsh[2][3136];     // 49 x 64 per phase
    __shared__ unsigned long long wordarr[224];
    int tid = threadIdx.x;
    int oh = blockIdx.x, od = blockIdx.y, b = blockIdx.z;
    if (tid < 224) wordarr[tid] = 0ull;

    auto stage = [&](int p, int s) {
        int ic = p / 3, kd = p % 3;
        int d = od * 3 - 1 + kd;
        const float* xsrc = x + ((long)(b * 3 + ic) * 27 + d) * 50176;
        bool dok = ((unsigned)d < 27u);
        for (int i = tid; i < 1624; i += 256) {
            int col = i % 232, kh = i / 232;
            int hh = oh - 3 + kh, ww = col - 3;
            float v = 0.f;
            if (dok && (unsigned)hh < 224u && (unsigned)ww < 224u)
                v = xsrc[hh * 224 + ww];
            xp[s][i] = v;
        }
        const float* wsrc = wt + p * 3136;
        for (int i = tid; i < 3136; i += 256) wsh[s][i] = wsrc[i];
    };

    stage(0, 0);
    int tx = tid & 15, ty = tid >> 4;
    float acc[4][14];
#pragma unroll
    for (int j = 0; j < 4; j++)
#pragma unroll
        for (int o2 = 0; o2 < 14; o2++) acc[j][o2] = 0.f;
    __syncthreads();

    for (int p = 0; p < 9; p++) {
        int cur = p & 1;
        if (p < 8) stage(p + 1, (p + 1) & 1);
        const float* xb = xp[cur];
        const float* wb = wsh[cur];
#pragma unroll
        for (int kh = 0; kh < 7; kh++) {
            const float* row = xb + kh * 232 + tx * 14;
            float xv[20];
#pragma unroll
            for (int t = 0; t < 20; t++) xv[t] = row[t];
            const float* wrow = wb + kh * 7 * 64 + ty * 4;
#pragma unroll
            for (int kw = 0; kw < 7; kw++) {
                float w0 = wrow[kw * 64 + 0], w1v = wrow[kw * 64 + 1];
                float w2v = wrow[kw * 64 + 2], w3v = wrow[kw * 64 + 3];
#pragma unroll
                for (int o2 = 0; o2 < 14; o2++) {
                    float xvv = xv[o2 + kw];
                    acc[0][o2] = fmaf(w0, xvv, acc[0][o2]);
                    acc[1][o2] = fmaf(w1v, xvv, acc[1][o2]);
                    acc[2][o2] = fmaf(w2v, xvv, acc[2][o2]);
                    acc[3][o2] = fmaf(w3v, xvv, acc[3][o2]);
                }
            }
        }
        __syncthreads();
    }
    int ow0 = tx * 14;
#pragma unroll
    for (int o2 = 0; o2 < 14; o2++) {
        unsigned long long nib =
            (unsigned long long)((acc[0][o2] > 0.f) | ((acc[1][o2] > 0.f) << 1) |
                                 ((acc[2][o2] > 0.f) << 2) | ((acc[3][o2] > 0.f) << 3));
        if (nib) atomicOr(&wordarr[ow0 + o2], nib << (ty * 4));
    }
    __syncthreads();
    if (tid < 224)
        b1p[(((long)b * 9 + od) * 224 + oh) * 224 + tid] = wordarr[tid];
}

// ---------------- conv2: LDS patch + popcount, packed u32 out ----------------
__global__ __launch_bounds__(256) void k_conv2(const uint64_t* __restrict__ bp1,
                                               const uint64_t* __restrict__ wp,
                                               const uint64_t* __restrict__ wn,
                                               uint32_t* __restrict__ b2p) {
    __shared__ uint64_t xs[21 * 232];
    __shared__ uint32_t obits[224];
    int tid = threadIdx.x;
    int oh = blockIdx.x, od = blockIdx.y, b = blockIdx.z;
    for (int i = tid; i < 21 * 232; i += 256) {
        int col = i % 232; int t = i / 232;
        int kh = t % 7; int kd = t / 7;
        int d = od * 3 - 1 + kd;
        int h = oh - 3 + kh;
        int w = col - 3;
        uint64_t v = 0;
        if ((unsigned)d < 9u && (unsigned)h < 224u && (unsigned)w < 224u)
            v = bp1[(((long)b * 9 + d) * 224 + h) * 224 + w];
        xs[i] = v;
    }
    if (tid < 224) obits[tid] = 0;
    __syncthreads();
    int tx = tid & 15, ty = tid >> 4;
    int ow0 = tx * 14, oc0 = ty * 2;
    int acc0[14], acc1[14];
#pragma unroll
    for (int o2 = 0; o2 < 14; o2++) { acc0[o2] = 0; acc1[o2] = 0; }
    for (int kd = 0; kd < 3; kd++) {
#pragma unroll
        for (int kh = 0; kh < 7; kh++) {
            const uint64_t* row = &xs[(kd * 7 + kh) * 232 + ow0];
            uint64_t xv[20];
#pragma unroll
            for (int t = 0; t < 20; t++) xv[t] = row[t];
            int rbase = kd * 49 + kh * 7;
#pragma unroll
            for (int kw = 0; kw < 7; kw++) {
                uint64_t p0 = wp[oc0 * 147 + rbase + kw];
                uint64_t n0 = wn[oc0 * 147 + rbase + kw];
                uint64_t p1 = wp[(oc0 + 1) * 147 + rbase + kw];
                uint64_t n1 = wn[(oc0 + 1) * 147 + rbase + kw];
#pragma unroll
                for (int o2 = 0; o2 < 14; o2++) {
                    uint64_t bits = xv[o2 + kw];
                    acc0[o2] += __popcll(bits & p0) - __popcll(bits & n0);
                    acc1[o2] += __popcll(bits & p1) - __popcll(bits & n1);
                }
            }
        }
    }
#pragma unroll
    for (int o2 = 0; o2 < 14; o2++) {
        uint32_t v = (uint32_t)((acc0[o2] > 0) | ((acc1[o2] > 0) << 1));
        if (v) atomicOr(&obits[ow0 + o2], v << oc0);
    }
    __syncthreads();
    if (tid < 224)
        b2p[(((long)b * 3 + od) * 224 + oh) * 224 + tid] = obits[tid];
}

// conv3 via popcount -> fp32 relu count
__global__ __launch_bounds__(256) void k_conv3(const uint32_t* __restrict__ bp2,
                                               const uint32_t* __restrict__ wp,
                                               const uint32_t* __restrict__ wn,
                                               float* __restrict__ h3) {
    int gid = blockIdx.x * 256 + threadIdx.x;  // 602,112
    int q = gid;
    int ow = q % 224; q /= 224;
    int oh = q % 224; q /= 224;
    int oc = q % 3;   int b = q / 3;
    int acc = 0;
    for (int kd = 0; kd < 3; kd++) {
        int d = kd - 1;
        if ((unsigned)d >= 3u) continue;
        for (int kh = 0; kh < 7; kh++) {
            int h = oh - 3 + kh;
            if ((unsigned)h >= 224u) continue;
            const uint32_t* bp = bp2 + ((long)(b * 3 + d) * 224 + h) * 224;
            const uint32_t* mp = wp + ((oc * 3 + kd) * 7 + kh) * 7;
            const uint32_t* mn = wn + ((oc * 3 + kd) * 7 + kh) * 7;
#pragma unroll
            for (int kw = 0; kw < 7; kw++) {
                int w = ow - 3 + kw;
                if ((unsigned)w < 224u) {
                    uint32_t bits = bp[w];
                    acc += __popc(bits & mp[kw]) - __popc(bits & mn[kw]);
                }
            }
        }
    }
    h3[gid] = fmaxf((float)acc, 0.f);
}

// ---------------- tokenizer conv; tok layout [b][h][w][c] (c-contiguous) ----------------
__global__ __launch_bounds__(256) void k_tok(const float* __restrict__ h3,
                                             const float* __restrict__ wt,
                                             float* __restrict__ tok) {
    __shared__ float xs[3 * 7 * 232];
    int tid = threadIdx.x;
    int oh = blockIdx.x, b = blockIdx.y;
    for (int i = tid; i < 3 * 7 * 232; i += 256) {
        int col = i % 232; int t = i / 232;
        int kh = t % 7; int ic = t / 7;
        int ih = oh * 2 - 3 + kh;
        int iw = col - 3;
        float v = 0.f;
        if ((unsigned)ih < 224u && (unsigned)iw < 224u)
            v = h3[((long)(b * 3 + ic) * 50176) + ih * 224 + iw];
        xs[i] = v;
    }
    __syncthreads();
    int oc = tid;
    float* obase = tok + ((long)(b * 112 + oh) * 112) * 256 + oc;
    for (int chunk = 0; chunk < 4; chunk++) {
        int ow0 = chunk * 28;
        float acc[28];
#pragma unroll
        for (int o2 = 0; o2 < 28; o2++) acc[o2] = 0.f;
        for (int ic = 0; ic < 3; ic++) {
#pragma unroll
            for (int kh = 0; kh < 7; kh++) {
                const float* row = &xs[(ic * 7 + kh) * 232 + ow0 * 2];
                float xv[61];
#pragma unroll
                for (int t = 0; t < 61; t++) xv[t] = row[t];
                const float* wr = wt + (oc * 3 + ic) * 49 + kh * 7;
                float w[7];
#pragma unroll
                for (int kw = 0; kw < 7; kw++) w[kw] = wr[kw];
#pragma unroll
                for (int kw = 0; kw < 7; kw++)
#pragma unroll
                    for (int o2 = 0; o2 < 28; o2++)
                        acc[o2] = fmaf(w[kw], xv[2 * o2 + kw], acc[o2]);
            }
        }
#pragma unroll
        for (int o2 = 0; o2 < 28; o2++)
            obase[(long)(ow0 + o2) * 256] = fmaxf(acc[o2], 0.f);
    }
}

// maxpool 3x3 s2 p1 + pos_emb; tok is [b][h][w][c] -> fully coalesced
__global__ __launch_bounds__(256) void k_pool_z(const float* __restrict__ tok,
                                                const float* __restrict__ pos,
                                                float* __restrict__ z) {
    int gid = blockIdx.x * 256 + threadIdx.x;  // 3,211,264
    int c = gid & 255;
    int n = (gid >> 8) % SEQL;
    int b = gid / (256 * SEQL);
    int oh = n / 56, ow = n % 56;
    const float* tp = tok + ((long)b * 112 * 112) * 256 + c;
    float m = -1e30f;
#pragma unroll
    for (int kh = 0; kh < 3; kh++) {
        int h = oh * 2 - 1 + kh;
        if ((unsigned)h >= 112u) continue;
#pragma unroll
        for (int kw = 0; kw < 3; kw++) {
            int w = ow * 2 - 1 + kw;
            if ((unsigned)w < 112u) m = fmaxf(m, tp[(long)(h * 112 + w) * 256]);
        }
    }
    z[gid] = m + pos[n * 256 + c];
}

// layernorm over 256; out bf16 (obf=1) or fp32
__global__ __launch_bounds__(256) void k_ln(const float* __restrict__ X,
                                            const float* __restrict__ g,
                                            const float* __restrict__ be,
                                            void* __restrict__ outp, int obf) {
    int wid = threadIdx.x >> 6, lane = threadIdx.x & 63;
    int r = blockIdx.x * 4 + wid;
    const float* xr = X + (long)r * 256;
    float v0 = xr[lane], v1 = xr[lane + 64], v2 = xr[lane + 128], v3 = xr[lane + 192];
    float s = v0 + v1 + v2 + v3;
#pragma unroll
    for (int off = 1; off < 64; off <<= 1) s += __shfl_xor(s, off);
    float mean = s * (1.0f / 256.0f);
    float d0 = v0 - mean, d1 = v1 - mean, d2 = v2 - mean, d3 = v3 - mean;
    float sq = d0 * d0 + d1 * d1 + d2 * d2 + d3 * d3;
#pragma unroll
    for (int off = 1; off < 64; off <<= 1) sq += __shfl_xor(sq, off);
    float rs = rsqrtf(sq * (1.0f / 256.0f) + 1e-5f);
    float o0 = d0 * rs * g[lane]       + be[lane];
    float o1 = d1 * rs * g[lane + 64]  + be[lane + 64];
    float o2 = d2 * rs * g[lane + 128] + be[lane + 128];
    float o3 = d3 * rs * g[lane + 192] + be[lane + 192];
    if (obf) {
        uint16_t* orow = (uint16_t*)outp + (long)r * 256;
        orow[lane] = bf16u(o0); orow[lane + 64] = bf16u(o1);
        orow[lane + 128] = bf16u(o2); orow[lane + 192] = bf16u(o3);
    } else {
        float* orow = (float*)outp + (long)r * 256;
        orow[lane] = o0; orow[lane + 64] = o1;
        orow[lane + 128] = o2; orow[lane + 192] = o3;
    }
}

// ---------------- bf16 MFMA GEMM: 128x128 tile, 4 waves ----------------
__global__ __launch_bounds__(256) void k_gemm(const uint16_t* __restrict__ A,
                                              const uint16_t* __restrict__ W,
                                              const float* __restrict__ bias,
                                              void* __restrict__ C,
                                              int M, int N, int K,
                                              int dogelu, int resid) {
    __shared__ uint16_t As[128 * 40], Bs[128 * 40];
    int tid = threadIdx.x;
    int lane = tid & 63, wave = tid >> 6;
    int wm = wave >> 1, wn = wave & 1;
    int m0 = blockIdx.y * 128, n0 = blockIdx.x * 128;
    f32x4 acc[4][4];
#pragma unroll
    for (int i = 0; i < 4; i++)
#pragma unroll
        for (int j = 0; j < 4; j++) acc[i][j] = (f32x4){0.f, 0.f, 0.f, 0.f};
    int rl = lane & 15, kq = (lane >> 4) * 8;
    for (int k0 = 0; k0 < K; k0 += 32) {
        __syncthreads();
#pragma unroll
        for (int c = 0; c < 2; c++) {
            int idx = c * 256 + tid;
            int row = idx >> 2, k8 = (idx & 3) * 8;
            *(uint4*)&As[row * 40 + k8] = *(const uint4*)&A[(long)(m0 + row) * K + k0 + k8];
            *(uint4*)&Bs[row * 40 + k8] = *(const uint4*)&W[(long)(n0 + row) * K + k0 + k8];
        }
        __syncthreads();
        v8s a[4], bb[4];
#pragma unroll
        for (int i = 0; i < 4; i++) a[i] = *(const v8s*)&As[(wm * 64 + i * 16 + rl) * 40 + kq];
#pragma unroll
        for (int j = 0; j < 4; j++) bb[j] = *(const v8s*)&Bs[(wn * 64 + j * 16 + rl) * 40 + kq];
#pragma unroll
        for (int i = 0; i < 4; i++)
#pragma unroll
            for (int j = 0; j < 4; j++)
                acc[i][j] = __builtin_amdgcn_mfma_f32_16x16x32_bf16(a[i], bb[j], acc[i][j], 0, 0, 0);
    }
    int rq = (lane >> 4) * 4;
#pragma unroll
    for (int i = 0; i < 4; i++) {
#pragma unroll
        for (int j = 0; j < 4; j++) {
            int col = n0 + wn * 64 + j * 16 + rl;
            float bval = bias[col];
#pragma unroll
            for (int r = 0; r < 4; r++) {
                int row = m0 + wm * 64 + i * 16 + rq + r;
                float v = acc[i][j][r] + bval;
                if (dogelu) v = 0.5f * v * (1.0f + erff(v * 0.70710678118654752f));
                if (resid) ((float*)C)[(long)row * N + col] += v;
                else ((uint16_t*)C)[(long)row * N + col] = bf16u(v);
            }
        }
    }
}

// ---------------- flash attention, bf16 MFMA ----------------
__device__ __forceinline__ v8s ldV35(const uint32_t* Vt, int row, int w0) {
    union { v8s v; uint32_t u[4]; } t;
    const uint32_t* p = Vt + row * 35 + w0;
    t.u[0] = p[0]; t.u[1] = p[1]; t.u[2] = p[2]; t.u[3] = p[3];
    return t.v;
}

__global__ __launch_bounds__(256) void k_flash(const uint16_t* __restrict__ G,
                                               uint16_t* __restrict__ o) {
    __shared__ uint32_t Qs[64 * 36], Ks[64 * 36], Vt[64 * 35];
    __shared__ uint16_t Ps[64 * 72];
    int tid = threadIdx.x;
    int lane = tid & 63, wv = tid >> 6;
    int qt = blockIdx.x, h = blockIdx.y, b = blockIdx.z;
    long base = (long)b * SEQL * 768 + h * 64;
    for (int i = tid; i < 2048; i += 256) {
        int d2 = i & 31, r = i >> 5;
        Qs[r * 36 + d2] = *(const uint32_t*)&G[base + (long)(qt * 64 + r) * 768 + 2 * d2];
    }
    int g = lane >> 4, tl = lane & 15;
    int qr0 = wv * 16;
    __syncthreads();
    v8s aq[2];
#pragma unroll
    for (int ks = 0; ks < 2; ks++)
        aq[ks] = *(const v8s*)&Qs[(qr0 + tl) * 36 + ks * 16 + g * 4];

    float m_[4], l_[4];
    f32x4 ov[4];
#pragma unroll
    for (int r = 0; r < 4; r++) { m_[r] = -1e30f; l_[r] = 0.f; }
#pragma unroll
    for (int j = 0; j < 4; j++) ov[j] = (f32x4){0.f, 0.f, 0.f, 0.f};

    for (int kt = 0; kt < 49; kt++) {
        __syncthreads();
        for (int i = tid; i < 2048; i += 256) {
            int d2 = i & 31, r = i >> 5;
            Ks[r * 36 + d2] = *(const uint32_t*)&G[base + (long)(kt * 64 + r) * 768 + 256 + 2 * d2];
        }
        for (int i = tid; i < 2048; i += 256) {
            int d = i & 63, r2 = i >> 6;
            uint32_t lo = G[base + (long)(kt * 64 + 2 * r2) * 768 + 512 + d];
            uint32_t hi = G[base + (long)(kt * 64 + 2 * r2 + 1) * 768 + 512 + d];
            Vt[d * 35 + r2] = lo | (hi << 16);
        }
        __syncthreads();
        f32x4 s[4];
#pragma unroll
        for (int j = 0; j < 4; j++) s[j] = (f32x4){0.f, 0.f, 0.f, 0.f};
#pragma unroll
        for (int ks = 0; ks < 2; ks++) {
#pragma unroll
            for (int j = 0; j < 4; j++) {
                v8s bk = *(const v8s*)&Ks[(j * 16 + tl) * 36 + ks * 16 + g * 4];
                s[j] = __builtin_amdgcn_mfma_f32_16x16x32_bf16(aq[ks], bk, s[j], 0, 0, 0);
            }
        }
        float alpha[4];
#pragma unroll
        for (int r = 0; r < 4; r++) {
            float s0 = s[0][r] * 0.125f, s1 = s[1][r] * 0.125f;
            float s2 = s[2][r] * 0.125f, s3 = s[3][r] * 0.125f;
            s[0][r] = s0; s[1][r] = s1; s[2][r] = s2; s[3][r] = s3;
            float mx = fmaxf(fmaxf(s0, s1), fmaxf(s2, s3));
#pragma unroll
            for (int off = 1; off < 16; off <<= 1) mx = fmaxf(mx, __shfl_xor(mx, off));
            float nm = fmaxf(m_[r], mx);
            alpha[r] = __expf(m_[r] - nm);
            float rs = 0.f;
#pragma unroll
            for (int j = 0; j < 4; j++) {
                float p = __expf(s[j][r] - nm);
                s[j][r] = p; rs += p;
            }
#pragma unroll
            for (int off = 1; off < 16; off <<= 1) rs += __shfl_xor(rs, off);
            l_[r] = l_[r] * alpha[r] + rs;
            m_[r] = nm;
        }
#pragma unroll
        for (int j = 0; j < 4; j++)
#pragma unroll
            for (int r = 0; r < 4; r++) ov[j][r] *= alpha[r];
#pragma unroll
        for (int j = 0; j < 4; j++)
#pragma unroll
            for (int r = 0; r < 4; r++)
                Ps[(qr0 + g * 4 + r) * 72 + j * 16 + tl] = bf16u(s[j][r]);
#pragma unroll
        for (int ks = 0; ks < 2; ks++) {
            v8s ap = *(const v8s*)&Ps[(qr0 + tl) * 72 + ks * 32 + g * 8];
#pragma unroll
            for (int jd = 0; jd < 4; jd++) {
                v8s bv = ldV35(Vt, jd * 16 + tl, ks * 16 + g * 4);
                ov[jd] = __builtin_amdgcn_mfma_f32_16x16x32_bf16(ap, bv, ov[jd], 0, 0, 0);
            }
        }
    }
    long ob = ((long)b * SEQL + qt * 64) * 256 + h * 64;
#pragma unroll
    for (int r = 0; r < 4; r++) {
        float inv = 1.0f / l_[r];
        int row = qr0 + g * 4 + r;
#pragma unroll
        for (int jd = 0; jd < 4; jd++)
            o[ob + (long)row * 256 + jd * 16 + tl] = bf16u(ov[jd][r] * inv);
    }
}

// ---------------- fused tail: pool logits + softmax + pooled + head ----------------
__global__ __launch_bounds__(256) void k_tail(const float* __restrict__ F,
                                              const float* __restrict__ pw,
                                              const float* __restrict__ pb,
                                              const float* __restrict__ hw,
                                              const float* __restrict__ hb,
                                              float* __restrict__ out) {
    __shared__ float lg[SEQL];
    __shared__ float red[256];
    __shared__ float pooled[256];
    int b = blockIdx.x, tid = threadIdx.x;
    int wv = tid >> 6, lane = tid & 63;
    const float* Fb = F + (long)b * SEQL * 256;
    for (int r = wv; r < SEQL; r += 4) {
        const float* xr = Fb + (long)r * 256;
        float a = xr[lane] * pw[lane] + xr[lane + 64] * pw[lane + 64]
                + xr[lane + 128] * pw[lane + 128] + xr[lane + 192] * pw[lane + 192];
#pragma unroll
        for (int off = 1; off < 64; off <<= 1) a += __shfl_xor(a, off);
        if (lane == 0) lg[r] = a + pb[0];
    }
    __syncthreads();
    float m = -1e30f;
    for (int i = tid; i < SEQL; i += 256) m = fmaxf(m, lg[i]);
    red[tid] = m; __syncthreads();
    for (int s = 128; s > 0; s >>= 1) {
        if (tid < s) red[tid] = fmaxf(red[tid], red[tid + s]);
        __syncthreads();
    }
    float M = red[0]; __syncthreads();
    float sum = 0.f;
    for (int i = tid; i < SEQL; i += 256) sum += expf(lg[i] - M);
    red[tid] = sum; __syncthreads();
    for (int s = 128; s > 0; s >>= 1) {
        if (tid < s) red[tid] += red[tid + s];
        __syncthreads();
    }
    float inv = 1.0f / red[0];
    __syncthreads();
    for (int i = tid; i < SEQL; i += 256) lg[i] = expf(lg[i] - M) * inv;
    __syncthreads();
    float acc = 0.f;
    for (int n = 0; n < SEQL; n++) acc = fmaf(lg[n], Fb[(long)n * 256 + tid], acc);
    pooled[tid] = acc;
    __syncthreads();
    if (tid < 101) {
        float a = hb[tid];
        for (int d = 0; d < 256; d++) a = fmaf(pooled[d], hw[tid * 256 + d], a);
        out[b * 101 + tid] = a;
    }
}

// ---------------------------------------------------------------------------
extern "C" void kernel_launch(void* const* d_in, const int* in_sizes, int n_in,
                              void* d_out, int out_size, void* d_ws, size_t ws_size,
                              hipStream_t stream) {
    (void)in_sizes; (void)n_in; (void)out_size; (void)ws_size;
    const float* x     = (const float*)d_in[0];
    const float* w1    = (const float*)d_in[1];
    const float* w2    = (const float*)d_in[2];
    const float* w3    = (const float*)d_in[3];
    const float* tokw  = (const float*)d_in[4];
    const float* pos   = (const float*)d_in[5];
    const float* ln1s  = (const float*)d_in[6];
    const float* ln1b  = (const float*)d_in[7];
    const float* qkvw  = (const float*)d_in[8];
    const float* qkvb  = (const float*)d_in[9];
    const float* projw = (const float*)d_in[10];
    const float* projb = (const float*)d_in[11];
    const float* ln2s  = (const float*)d_in[12];
    const float* ln2b  = (const float*)d_in[13];
    const float* fc1w  = (const float*)d_in[14];
    const float* fc1b  = (const float*)d_in[15];
    const float* fc2w  = (const float*)d_in[16];
    const float* fc2b  = (const float*)d_in[17];
    const float* lnfs  = (const float*)d_in[18];
    const float* lnfb  = (const float*)d_in[19];
    const float* poolw = (const float*)d_in[20];
    const float* poolb = (const float*)d_in[21];
    const float* headw = (const float*)d_in[22];
    const float* headb = (const float*)d_in[23];
    float* out = (float*)d_out;
    char* ws = (char*)d_ws;

    uint64_t* B1P = (uint64_t*)(ws + 0);                  // 14,450,688
    uint32_t* B2P = (uint32_t*)(ws + 14450688);           //  2,408,448
    float*    H3  = (float*)(ws + 16859136);              //  2,408,448
    float*    W1T = (float*)(ws + 19267584);              //    112,896
    uint64_t* WP2 = (uint64_t*)(ws + 19380480);
    uint64_t* WN2 = (uint64_t*)(ws + 19418112);
    uint32_t* WP3 = (uint32_t*)(ws + 19455744);
    uint32_t* WN3 = (uint32_t*)(ws + 19457792);
    uint16_t* WQb = (uint16_t*)(ws + 19460096);           //  2,752,512
    uint16_t* WPb = (uint16_t*)(ws + 22212608);           //    917,504
    uint16_t* W1b = (uint16_t*)(ws + 23130112);           //  1,835,008
    uint16_t* W2b = (uint16_t*)(ws + 24965120);           //  1,835,008
    float*    TOK = (float*)(ws + 26800128);              // 51,380,224 [b][h][w][c]
    float*    Ffin= (float*)(ws + 26800128);              // aliases TOK (dead by then)
    float*    Z   = (float*)(ws + 78180352);              // 12,845,056
    uint16_t* Fbf = (uint16_t*)(ws + 91025408);           //  6,422,528
    uint16_t* Gbf = (uint16_t*)(ws + 97447936);           // 19,267,584
    uint16_t* Obf = (uint16_t*)(ws + 116715520);          //  6,422,528
    uint16_t* MLPb= (uint16_t*)(ws + 123138048);          // 12,845,056

    k_prep<<<131, 256, 0, stream>>>(w1, w2, w3, W1T, WP2, WN2, WP3, WN3);
    k_cvtall<<<14336, 256, 0, stream>>>(qkvw, projw, fc1w, fc2w, WQb, WPb, W1b, W2b);

    k_conv1<<<dim3(224, 9, 4), 256, 0, stream>>>(x, W1T, B1P);
    k_conv2<<<dim3(224, 3, 4), 256, 0, stream>>>(B1P, WP2, WN2, B2P);
    k_conv3<<<2352, 256, 0, stream>>>(B2P, WP3, WN3, H3);
    k_tok<<<dim3(112, 4), 256, 0, stream>>>(H3, tokw, TOK);
    k_pool_z<<<12544, 256, 0, stream>>>(TOK, pos, Z);

    for (int l = 0; l < 7; l++) {
        k_ln<<<3136, 256, 0, stream>>>(Z, ln1s + l * 256, ln1b + l * 256, Fbf, 1);
        k_gemm<<<dim3(6, 98), 256, 0, stream>>>(Fbf, WQb + (long)l * 196608,
                                                qkvb + l * 768, Gbf,
                                                12544, 768, 256, 0, 0);
        k_flash<<<dim3(49, 4, 4), 256, 0, stream>>>(Gbf, Obf);
        k_gemm<<<dim3(2, 98), 256, 0, stream>>>(Obf, WPb + (long)l * 65536,
                                                projb + l * 256, Z,
                                                12544, 256, 256, 0, 1);
        k_ln<<<3136, 256, 0, stream>>>(Z, ln2s + l * 256, ln2b + l * 256, Fbf, 1);
        k_gemm<<<dim3(4, 98), 256, 0, stream>>>(Fbf, W1b + (long)l * 131072,
                                                fc1b + l * 512, MLPb,
                                                12544, 512, 256, 1, 0);
        k_gemm<<<dim3(2, 98), 256, 0, stream>>>(MLPb, W2b + (long)l * 131072,
                                                fc2b + l * 256, Z,
                                                12544, 256, 512, 0, 1);
    }

    k_ln<<<3136, 256, 0, stream>>>(Z, lnfs, lnfb, Ffin, 0);
    k_tail<<<4, 256, 0, stream>>>(Ffin, poolw, poolb, headw, headb, out);
}

// Round 5
// 5929.830 us; speedup vs baseline: 5.2246x; 1.0115x over previous
//
#include <hip/hip_runtime.h>
#include <hip/hip_bf16.h>
#include <cstdint>

#define SEQL 3136

typedef __attribute__((ext_vector_type(8))) short v8s;
typedef __attribute__((ext_vector_type(4))) float f32x4;

__device__ __forceinline__ uint16_t bf16u(float f) {
    uint32_t u = __float_as_uint(f);
    uint32_t r = u + 0x7fff + ((u >> 16) & 1);   // RNE
    return (uint16_t)(r >> 16);
}

// ---------------- merged prep: w1 sign-transpose + conv2/conv3 masks ----------------
__global__ __launch_bounds__(256) void k_prep(const float* __restrict__ w1,
                                              const float* __restrict__ w2,
                                              const float* __restrict__ w3,
                                              float* __restrict__ w1t,
                                              uint64_t* __restrict__ wp2,
                                              uint64_t* __restrict__ wn2,
                                              uint32_t* __restrict__ wp3,
                                              uint32_t* __restrict__ wn3) {
    int gid = blockIdx.x * 256 + threadIdx.x;
    if (gid < 28224) {
        int oc = gid & 63; int t = gid >> 6;
        int r = t % 49; int ickd = t / 49;
        int ic = ickd / 3, kd = ickd % 3;
        float v = w1[(((oc * 3 + ic) * 3 + kd) * 49) + r];
        w1t[gid] = (v > 0.f) ? 1.f : ((v < 0.f) ? -1.f : 0.f);
    } else if (gid < 28224 + 4704) {
        int i = gid - 28224;
        int oc = i / 147, r = i % 147;
        uint64_t p = 0, n = 0;
        for (int ic = 0; ic < 64; ic++) {
            float v = w2[(long)oc * 9408 + (long)ic * 147 + r];
            if (v > 0.f) p |= (1ull << ic);
            else if (v < 0.f) n |= (1ull << ic);
        }
        wp2[i] = p; wn2[i] = n;
    } else if (gid < 28224 + 4704 + 441) {
        int i = gid - 28224 - 4704;
        int oc = i / 147, r = i % 147;
        uint32_t p = 0, n = 0;
        for (int ic = 0; ic < 32; ic++) {
            float v = w3[(long)oc * 4704 + (long)ic * 147 + r];
            if (v > 0.f) p |= (1u << ic);
            else if (v < 0.f) n |= (1u << ic);
        }
        wp3[i] = p; wn3[i] = n;
    }
}

// merged fp32->bf16 weight conversion (qkv | proj | fc1 | fc2)
__global__ __launch_bounds__(256) void k_cvtall(const float* __restrict__ qw,
                                                const float* __restrict__ pw,
                                                const float* __restrict__ f1,
                                                const float* __restrict__ f2,
                                                uint16_t* __restrict__ dq,
                                                uint16_t* __restrict__ dp,
                                                uint16_t* __restrict__ d1,
                                                uint16_t* __restrict__ d2) {
    int i = blockIdx.x * 256 + threadIdx.x;   // total 3,670,016
    if (i < 1376256) dq[i] = bf16u(qw[i]);
    else if (i < 1835008) dp[i - 1376256] = bf16u(pw[i - 1376256]);
    else if (i < 2752512) d1[i - 1835008] = bf16u(f1[i - 1835008]);
    else if (i < 3670016) d2[i - 2752512] = bf16u(f2[i - 2752512]);
}

// ---------------- conv1: 2-oh blocking, double-buffered staging, packed u64 out ----------------
__global__ __launch_bounds__(256) void k_conv1(const float* __restrict__ x,
                                               const float* __restrict__ wt,
                                               uint64_t* __restrict__ b1p) {
    __shared__ float xp[2][1860];      // 8 rows x 232 per phase
    __shared__ float wsh[2][3136];     // 49 x 64 per phase
    __shared__ unsigned long long wordarr[2][224];
    int tid = threadIdx.x;
    int oh0 = blockIdx.x * 2, od = blockIdx.y, b = blockIdx.z;
    if (tid < 224) { wordarr[0][tid] = 0ull; wordarr[1][tid] = 0ull; }

    auto stage = [&](int p, int s) {
        int ic = p / 3, kd = p % 3;
        int d = od * 3 - 1 + kd;
        const float* xsrc = x + ((long)(b * 3 + ic) * 27 + d) * 50176;
        bool dok = ((unsigned)d < 27u);
        for (int i = tid; i < 1856; i += 256) {
            int col = i % 232, kh = i / 232;      // kh 0..7
            int hh = oh0 - 3 + kh, ww = col - 3;
            float v = 0.f;
            if (dok && (unsigned)hh < 224u && (unsigned)ww < 224u)
                v = xsrc[hh * 224 + ww];
            xp[s][i] = v;
        }
        const float* wsrc = wt + p * 3136;
        for (int i = tid; i < 3136; i += 256) wsh[s][i] = wsrc[i];
    };

    stage(0, 0);
    int tx = tid & 15, ty = tid >> 4;
    float acc[2][4][14];
#pragma unroll
    for (int oi = 0; oi < 2; oi++)
#pragma unroll
        for (int j = 0; j < 4; j++)
#pragma unroll
            for (int o2 = 0; o2 < 14; o2++) acc[oi][j][o2] = 0.f;
    __syncthreads();

    for (int p = 0; p < 9; p++) {
        int cur = p & 1;
        if (p < 8) stage(p + 1, cur ^ 1);
        const float* wb = wsh[cur];
#pragma unroll
        for (int oi = 0; oi < 2; oi++) {
#pragma unroll
            for (int kh = 0; kh < 7; kh++) {
                const float* row = xp[cur] + (kh + oi) * 232 + tx * 14;
                float xv[20];
#pragma unroll
                for (int t = 0; t < 20; t++) xv[t] = row[t];
                const float* wrow = wb + kh * 448 + ty * 4;
#pragma unroll
                for (int kw = 0; kw < 7; kw++) {
                    float w0 = wrow[kw * 64 + 0], w1v = wrow[kw * 64 + 1];
                    float w2v = wrow[kw * 64 + 2], w3v = wrow[kw * 64 + 3];
#pragma unroll
                    for (int o2 = 0; o2 < 14; o2++) {
                        float xvv = xv[o2 + kw];
                        acc[oi][0][o2] = fmaf(w0, xvv, acc[oi][0][o2]);
                        acc[oi][1][o2] = fmaf(w1v, xvv, acc[oi][1][o2]);
                        acc[oi][2][o2] = fmaf(w2v, xvv, acc[oi][2][o2]);
                        acc[oi][3][o2] = fmaf(w3v, xvv, acc[oi][3][o2]);
                    }
                }
            }
        }
        __syncthreads();
    }
    int ow0 = tx * 14;
#pragma unroll
    for (int oi = 0; oi < 2; oi++)
#pragma unroll
        for (int o2 = 0; o2 < 14; o2++) {
            unsigned long long nib =
                (unsigned long long)((acc[oi][0][o2] > 0.f) | ((acc[oi][1][o2] > 0.f) << 1) |
                                     ((acc[oi][2][o2] > 0.f) << 2) | ((acc[oi][3][o2] > 0.f) << 3));
            if (nib) atomicOr(&wordarr[oi][ow0 + o2], nib << (ty * 4));
        }
    __syncthreads();
    if (tid < 224) {
        long base = (((long)b * 9 + od) * 224 + oh0) * 224 + tid;
        b1p[base] = wordarr[0][tid];
        b1p[base + 224] = wordarr[1][tid];
    }
}

// ---------------- conv2: 2-oh blocking, LDS patch + popcount, packed u32 out ----------------
__global__ __launch_bounds__(256) void k_conv2(const uint64_t* __restrict__ bp1,
                                               const uint64_t* __restrict__ wp,
                                               const uint64_t* __restrict__ wn,
                                               uint32_t* __restrict__ b2p) {
    __shared__ uint64_t xs[24 * 232];   // 44,544 B
    __shared__ uint32_t obits[2][224];
    int tid = threadIdx.x;
    int oh0 = blockIdx.x * 2, od = blockIdx.y, b = blockIdx.z;
    for (int i = tid; i < 24 * 232; i += 256) {
        int col = i % 232; int t = i / 232;
        int kh = t & 7; int kd = t >> 3;     // kh 0..7
        int d = od * 3 - 1 + kd;
        int h = oh0 - 3 + kh;
        int w = col - 3;
        uint64_t v = 0;
        if ((unsigned)d < 9u && (unsigned)h < 224u && (unsigned)w < 224u)
            v = bp1[(((long)b * 9 + d) * 224 + h) * 224 + w];
        xs[i] = v;
    }
    if (tid < 224) { obits[0][tid] = 0; obits[1][tid] = 0; }
    __syncthreads();
    int tx = tid & 15, ty = tid >> 4;
    int ow0 = tx * 14, oc0 = ty * 2;
#pragma unroll
    for (int oi = 0; oi < 2; oi++) {
        int acc0[14], acc1[14];
#pragma unroll
        for (int o2 = 0; o2 < 14; o2++) { acc0[o2] = 0; acc1[o2] = 0; }
        for (int kd = 0; kd < 3; kd++) {
#pragma unroll
            for (int kh = 0; kh < 7; kh++) {
                const uint64_t* row = &xs[(kd * 8 + kh + oi) * 232 + ow0];
                uint64_t xv[20];
#pragma unroll
                for (int t = 0; t < 20; t++) xv[t] = row[t];
                int rbase = kd * 49 + kh * 7;
#pragma unroll
                for (int kw = 0; kw < 7; kw++) {
                    uint64_t p0 = wp[oc0 * 147 + rbase + kw];
                    uint64_t n0 = wn[oc0 * 147 + rbase + kw];
                    uint64_t p1 = wp[(oc0 + 1) * 147 + rbase + kw];
                    uint64_t n1 = wn[(oc0 + 1) * 147 + rbase + kw];
#pragma unroll
                    for (int o2 = 0; o2 < 14; o2++) {
                        uint64_t bits = xv[o2 + kw];
                        acc0[o2] += __popcll(bits & p0) - __popcll(bits & n0);
                        acc1[o2] += __popcll(bits & p1) - __popcll(bits & n1);
                    }
                }
            }
        }
#pragma unroll
        for (int o2 = 0; o2 < 14; o2++) {
            uint32_t v = (uint32_t)((acc0[o2] > 0) | ((acc1[o2] > 0) << 1));
            if (v) atomicOr(&obits[oi][ow0 + o2], v << oc0);
        }
    }
    __syncthreads();
    if (tid < 224) {
        long base = (((long)b * 3 + od) * 224 + oh0) * 224 + tid;
        b2p[base] = obits[0][tid];
        b2p[base + 224] = obits[1][tid];
    }
}

// conv3 via popcount -> fp32 relu count
__global__ __launch_bounds__(256) void k_conv3(const uint32_t* __restrict__ bp2,
                                               const uint32_t* __restrict__ wp,
                                               const uint32_t* __restrict__ wn,
                                               float* __restrict__ h3) {
    int gid = blockIdx.x * 256 + threadIdx.x;  // 602,112
    int q = gid;
    int ow = q % 224; q /= 224;
    int oh = q % 224; q /= 224;
    int oc = q % 3;   int b = q / 3;
    int acc = 0;
    for (int kd = 0; kd < 3; kd++) {
        int d = kd - 1;
        if ((unsigned)d >= 3u) continue;
        for (int kh = 0; kh < 7; kh++) {
            int h = oh - 3 + kh;
            if ((unsigned)h >= 224u) continue;
            const uint32_t* bp = bp2 + ((long)(b * 3 + d) * 224 + h) * 224;
            const uint32_t* mp = wp + ((oc * 3 + kd) * 7 + kh) * 7;
            const uint32_t* mn = wn + ((oc * 3 + kd) * 7 + kh) * 7;
#pragma unroll
            for (int kw = 0; kw < 7; kw++) {
                int w = ow - 3 + kw;
                if ((unsigned)w < 224u) {
                    uint32_t bits = bp[w];
                    acc += __popc(bits & mp[kw]) - __popc(bits & mn[kw]);
                }
            }
        }
    }
    h3[gid] = fmaxf((float)acc, 0.f);
}

// ---------------- tokenizer conv; tok layout [b][h][w][c] ----------------
__global__ __launch_bounds__(256) void k_tok(const float* __restrict__ h3,
                                             const float* __restrict__ wt,
                                             float* __restrict__ tok) {
    __shared__ float xs[3 * 7 * 232];
    int tid = threadIdx.x;
    int oh = blockIdx.x, b = blockIdx.y;
    for (int i = tid; i < 3 * 7 * 232; i += 256) {
        int col = i % 232; int t = i / 232;
        int kh = t % 7; int ic = t / 7;
        int ih = oh * 2 - 3 + kh;
        int iw = col - 3;
        float v = 0.f;
        if ((unsigned)ih < 224u && (unsigned)iw < 224u)
            v = h3[((long)(b * 3 + ic) * 50176) + ih * 224 + iw];
        xs[i] = v;
    }
    __syncthreads();
    int oc = tid;
    float* obase = tok + ((long)(b * 112 + oh) * 112) * 256 + oc;
    for (int chunk = 0; chunk < 4; chunk++) {
        int ow0 = chunk * 28;
        float acc[28];
#pragma unroll
        for (int o2 = 0; o2 < 28; o2++) acc[o2] = 0.f;
        for (int ic = 0; ic < 3; ic++) {
#pragma unroll
            for (int kh = 0; kh < 7; kh++) {
                const float* row = &xs[(ic * 7 + kh) * 232 + ow0 * 2];
                float xv[61];
#pragma unroll
                for (int t = 0; t < 61; t++) xv[t] = row[t];
                const float* wr = wt + (oc * 3 + ic) * 49 + kh * 7;
                float w[7];
#pragma unroll
                for (int kw = 0; kw < 7; kw++) w[kw] = wr[kw];
#pragma unroll
                for (int kw = 0; kw < 7; kw++)
#pragma unroll
                    for (int o2 = 0; o2 < 28; o2++)
                        acc[o2] = fmaf(w[kw], xv[2 * o2 + kw], acc[o2]);
            }
        }
#pragma unroll
        for (int o2 = 0; o2 < 28; o2++)
            obase[(long)(ow0 + o2) * 256] = fmaxf(acc[o2], 0.f);
    }
}

// maxpool 3x3 s2 p1 + pos_emb; tok is [b][h][w][c]
__global__ __launch_bounds__(256) void k_pool_z(const float* __restrict__ tok,
                                                const float* __restrict__ pos,
                                                float* __restrict__ z) {
    int gid = blockIdx.x * 256 + threadIdx.x;  // 3,211,264
    int c = gid & 255;
    int n = (gid >> 8) % SEQL;
    int b = gid / (256 * SEQL);
    int oh = n / 56, ow = n % 56;
    const float* tp = tok + ((long)b * 112 * 112) * 256 + c;
    float m = -1e30f;
#pragma unroll
    for (int kh = 0; kh < 3; kh++) {
        int h = oh * 2 - 1 + kh;
        if ((unsigned)h >= 112u) continue;
#pragma unroll
        for (int kw = 0; kw < 3; kw++) {
            int w = ow * 2 - 1 + kw;
            if ((unsigned)w < 112u) m = fmaxf(m, tp[(long)(h * 112 + w) * 256]);
        }
    }
    z[gid] = m + pos[n * 256 + c];
}

// layernorm over 256; out bf16 (obf=1) or fp32
__global__ __launch_bounds__(256) void k_ln(const float* __restrict__ X,
                                            const float* __restrict__ g,
                                            const float* __restrict__ be,
                                            void* __restrict__ outp, int obf) {
    int wid = threadIdx.x >> 6, lane = threadIdx.x & 63;
    int r = blockIdx.x * 4 + wid;
    const float* xr = X + (long)r * 256;
    float v0 = xr[lane], v1 = xr[lane + 64], v2 = xr[lane + 128], v3 = xr[lane + 192];
    float s = v0 + v1 + v2 + v3;
#pragma unroll
    for (int off = 1; off < 64; off <<= 1) s += __shfl_xor(s, off);
    float mean = s * (1.0f / 256.0f);
    float d0 = v0 - mean, d1 = v1 - mean, d2 = v2 - mean, d3 = v3 - mean;
    float sq = d0 * d0 + d1 * d1 + d2 * d2 + d3 * d3;
#pragma unroll
    for (int off = 1; off < 64; off <<= 1) sq += __shfl_xor(sq, off);
    float rs = rsqrtf(sq * (1.0f / 256.0f) + 1e-5f);
    float o0 = d0 * rs * g[lane]       + be[lane];
    float o1 = d1 * rs * g[lane + 64]  + be[lane + 64];
    float o2 = d2 * rs * g[lane + 128] + be[lane + 128];
    float o3 = d3 * rs * g[lane + 192] + be[lane + 192];
    if (obf) {
        uint16_t* orow = (uint16_t*)outp + (long)r * 256;
        orow[lane] = bf16u(o0); orow[lane + 64] = bf16u(o1);
        orow[lane + 128] = bf16u(o2); orow[lane + 192] = bf16u(o3);
    } else {
        float* orow = (float*)outp + (long)r * 256;
        orow[lane] = o0; orow[lane + 64] = o1;
        orow[lane + 128] = o2; orow[lane + 192] = o3;
    }
}

// ---------------- bf16 MFMA GEMM: 128x128 tile, 4 waves ----------------
__global__ __launch_bounds__(256) void k_gemm(const uint16_t* __restrict__ A,
                                              const uint16_t* __restrict__ W,
                                              const float* __restrict__ bias,
                                              void* __restrict__ C,
                                              int M, int N, int K,
                                              int dogelu, int resid) {
    __shared__ uint16_t As[128 * 40], Bs[128 * 40];
    int tid = threadIdx.x;
    int lane = tid & 63, wave = tid >> 6;
    int wm = wave >> 1, wn = wave & 1;
    int m0 = blockIdx.y * 128, n0 = blockIdx.x * 128;
    f32x4 acc[4][4];
#pragma unroll
    for (int i = 0; i < 4; i++)
#pragma unroll
        for (int j = 0; j < 4; j++) acc[i][j] = (f32x4){0.f, 0.f, 0.f, 0.f};
    int rl = lane & 15, kq = (lane >> 4) * 8;
    for (int k0 = 0; k0 < K; k0 += 32) {
        __syncthreads();
#pragma unroll
        for (int c = 0; c < 2; c++) {
            int idx = c * 256 + tid;
            int row = idx >> 2, k8 = (idx & 3) * 8;
            *(uint4*)&As[row * 40 + k8] = *(const uint4*)&A[(long)(m0 + row) * K + k0 + k8];
            *(uint4*)&Bs[row * 40 + k8] = *(const uint4*)&W[(long)(n0 + row) * K + k0 + k8];
        }
        __syncthreads();
        v8s a[4], bb[4];
#pragma unroll
        for (int i = 0; i < 4; i++) a[i] = *(const v8s*)&As[(wm * 64 + i * 16 + rl) * 40 + kq];
#pragma unroll
        for (int j = 0; j < 4; j++) bb[j] = *(const v8s*)&Bs[(wn * 64 + j * 16 + rl) * 40 + kq];
#pragma unroll
        for (int i = 0; i < 4; i++)
#pragma unroll
            for (int j = 0; j < 4; j++)
                acc[i][j] = __builtin_amdgcn_mfma_f32_16x16x32_bf16(a[i], bb[j], acc[i][j], 0, 0, 0);
    }
    int rq = (lane >> 4) * 4;
#pragma unroll
    for (int i = 0; i < 4; i++) {
#pragma unroll
        for (int j = 0; j < 4; j++) {
            int col = n0 + wn * 64 + j * 16 + rl;
            float bval = bias[col];
#pragma unroll
            for (int r = 0; r < 4; r++) {
                int row = m0 + wm * 64 + i * 16 + rq + r;
                float v = acc[i][j][r] + bval;
                if (dogelu) v = 0.5f * v * (1.0f + erff(v * 0.70710678118654752f));
                if (resid) ((float*)C)[(long)row * N + col] += v;
                else ((uint16_t*)C)[(long)row * N + col] = bf16u(v);
            }
        }
    }
}

// ---------------- V transpose: G's V block -> VT[b][h][64][3136] ----------------
__global__ __launch_bounds__(256) void k_vt(const uint16_t* __restrict__ G,
                                            uint16_t* __restrict__ VT) {
    __shared__ uint16_t T[64 * 66];
    int tid = threadIdx.x;
    int kt = blockIdx.x, h = blockIdx.y, b = blockIdx.z;
    long gbase = (long)b * SEQL * 768 + h * 64 + 512;
#pragma unroll
    for (int it = 0; it < 8; it++) {
        int idx = it * 256 + tid;
        int d2 = idx & 31, r = idx >> 5;
        uint32_t v = *(const uint32_t*)&G[gbase + (long)(kt * 64 + r) * 768 + 2 * d2];
        *(uint32_t*)&T[r * 66 + 2 * d2] = v;
    }
    __syncthreads();
    long obase = ((long)(b * 4 + h) * 64) * SEQL + kt * 64;
#pragma unroll
    for (int it = 0; it < 8; it++) {
        int idx = it * 256 + tid;
        int rw = idx & 31, d = idx >> 5;
        uint32_t lo = T[(2 * rw) * 66 + d];
        uint32_t hi = T[(2 * rw + 1) * 66 + d];
        *(uint32_t*)&VT[obase + (long)d * SEQL + 2 * rw] = lo | (hi << 16);
    }
}

// ---------------- flash attention, bf16 MFMA, pre-transposed V ----------------
__global__ __launch_bounds__(256) void k_flash(const uint16_t* __restrict__ G,
                                               const uint16_t* __restrict__ VT,
                                               uint16_t* __restrict__ o) {
    __shared__ uint32_t Qs[64 * 36], Ks[64 * 36], Vt[64 * 36];
    __shared__ uint16_t Ps[64 * 72];
    int tid = threadIdx.x;
    int lane = tid & 63, wv = tid >> 6;
    int qt = blockIdx.x, h = blockIdx.y, b = blockIdx.z;
    long base = (long)b * SEQL * 768 + h * 64;
    long vtbase = ((long)(b * 4 + h) * 64) * SEQL;
    for (int i = tid; i < 2048; i += 256) {
        int d2 = i & 31, r = i >> 5;
        Qs[r * 36 + d2] = *(const uint32_t*)&G[base + (long)(qt * 64 + r) * 768 + 2 * d2];
    }
    int g = lane >> 4, tl = lane & 15;
    int qr0 = wv * 16;
    __syncthreads();
    v8s aq[2];
#pragma unroll
    for (int ks = 0; ks < 2; ks++)
        aq[ks] = *(const v8s*)&Qs[(qr0 + tl) * 36 + ks * 16 + g * 4];

    float m_[4], l_[4];
    f32x4 ov[4];
#pragma unroll
    for (int r = 0; r < 4; r++) { m_[r] = -1e30f; l_[r] = 0.f; }
#pragma unroll
    for (int j = 0; j < 4; j++) ov[j] = (f32x4){0.f, 0.f, 0.f, 0.f};

    for (int kt = 0; kt < 49; kt++) {
        __syncthreads();
        for (int i = tid; i < 2048; i += 256) {
            int d2 = i & 31, r = i >> 5;
            Ks[r * 36 + d2] = *(const uint32_t*)&G[base + (long)(kt * 64 + r) * 768 + 256 + 2 * d2];
        }
        for (int i = tid; i < 2048; i += 256) {
            int rw = i & 31, d = i >> 5;
            Vt[d * 36 + rw] = *(const uint32_t*)&VT[vtbase + (long)d * SEQL + kt * 64 + 2 * rw];
        }
        __syncthreads();
        f32x4 s[4];
#pragma unroll
        for (int j = 0; j < 4; j++) s[j] = (f32x4){0.f, 0.f, 0.f, 0.f};
#pragma unroll
        for (int ks = 0; ks < 2; ks++) {
#pragma unroll
            for (int j = 0; j < 4; j++) {
                v8s bk = *(const v8s*)&Ks[(j * 16 + tl) * 36 + ks * 16 + g * 4];
                s[j] = __builtin_amdgcn_mfma_f32_16x16x32_bf16(aq[ks], bk, s[j], 0, 0, 0);
            }
        }
        float alpha[4];
#pragma unroll
        for (int r = 0; r < 4; r++) {
            float s0 = s[0][r] * 0.125f, s1 = s[1][r] * 0.125f;
            float s2 = s[2][r] * 0.125f, s3 = s[3][r] * 0.125f;
            s[0][r] = s0; s[1][r] = s1; s[2][r] = s2; s[3][r] = s3;
            float mx = fmaxf(fmaxf(s0, s1), fmaxf(s2, s3));
#pragma unroll
            for (int off = 1; off < 16; off <<= 1) mx = fmaxf(mx, __shfl_xor(mx, off));
            float nm = fmaxf(m_[r], mx);
            alpha[r] = __expf(m_[r] - nm);
            float rs = 0.f;
#pragma unroll
            for (int j = 0; j < 4; j++) {
                float p = __expf(s[j][r] - nm);
                s[j][r] = p; rs += p;
            }
#pragma unroll
            for (int off = 1; off < 16; off <<= 1) rs += __shfl_xor(rs, off);
            l_[r] = l_[r] * alpha[r] + rs;
            m_[r] = nm;
        }
#pragma unroll
        for (int j = 0; j < 4; j++)
#pragma unroll
            for (int r = 0; r < 4; r++) ov[j][r] *= alpha[r];
#pragma unroll
        for (int j = 0; j < 4; j++)
#pragma unroll
            for (int r = 0; r < 4; r++)
                Ps[(qr0 + g * 4 + r) * 72 + j * 16 + tl] = bf16u(s[j][r]);
#pragma unroll
        for (int ks = 0; ks < 2; ks++) {
            v8s ap = *(const v8s*)&Ps[(qr0 + tl) * 72 + ks * 32 + g * 8];
#pragma unroll
            for (int jd = 0; jd < 4; jd++) {
                v8s bv = *(const v8s*)&Vt[(jd * 16 + tl) * 36 + ks * 16 + g * 4];
                ov[jd] = __builtin_amdgcn_mfma_f32_16x16x32_bf16(ap, bv, ov[jd], 0, 0, 0);
            }
        }
    }
    long ob = ((long)b * SEQL + qt * 64) * 256 + h * 64;
#pragma unroll
    for (int r = 0; r < 4; r++) {
        float inv = 1.0f / l_[r];
        int row = qr0 + g * 4 + r;
#pragma unroll
        for (int jd = 0; jd < 4; jd++)
            o[ob + (long)row * 256 + jd * 16 + tl] = bf16u(ov[jd][r] * inv);
    }
}

// ---------------- fused tail ----------------
__global__ __launch_bounds__(256) void k_tail(const float* __restrict__ F,
                                              const float* __restrict__ pw,
                                              const float* __restrict__ pb,
                                              const float* __restrict__ hw,
                                              const float* __restrict__ hb,
                                              float* __restrict__ out) {
    __shared__ float lg[SEQL];
    __shared__ float red[256];
    __shared__ float pooled[256];
    int b = blockIdx.x, tid = threadIdx.x;
    int wv = tid >> 6, lane = tid & 63;
    const float* Fb = F + (long)b * SEQL * 256;
    for (int r = wv; r < SEQL; r += 4) {
        const float* xr = Fb + (long)r * 256;
        float a = xr[lane] * pw[lane] + xr[lane + 64] * pw[lane + 64]
                + xr[lane + 128] * pw[lane + 128] + xr[lane + 192] * pw[lane + 192];
#pragma unroll
        for (int off = 1; off < 64; off <<= 1) a += __shfl_xor(a, off);
        if (lane == 0) lg[r] = a + pb[0];
    }
    __syncthreads();
    float m = -1e30f;
    for (int i = tid; i < SEQL; i += 256) m = fmaxf(m, lg[i]);
    red[tid] = m; __syncthreads();
    for (int s = 128; s > 0; s >>= 1) {
        if (tid < s) red[tid] = fmaxf(red[tid], red[tid + s]);
        __syncthreads();
    }
    float M = red[0]; __syncthreads();
    float sum = 0.f;
    for (int i = tid; i < SEQL; i += 256) sum += expf(lg[i] - M);
    red[tid] = sum; __syncthreads();
    for (int s = 128; s > 0; s >>= 1) {
        if (tid < s) red[tid] += red[tid + s];
        __syncthreads();
    }
    float inv = 1.0f / red[0];
    __syncthreads();
    for (int i = tid; i < SEQL; i += 256) lg[i] = expf(lg[i] - M) * inv;
    __syncthreads();
    float acc = 0.f;
    for (int n = 0; n < SEQL; n++) acc = fmaf(lg[n], Fb[(long)n * 256 + tid], acc);
    pooled[tid] = acc;
    __syncthreads();
    if (tid < 101) {
        float a = hb[tid];
        for (int d = 0; d < 256; d++) a = fmaf(pooled[d], hw[tid * 256 + d], a);
        out[b * 101 + tid] = a;
    }
}

// ---------------------------------------------------------------------------
extern "C" void kernel_launch(void* const* d_in, const int* in_sizes, int n_in,
                              void* d_out, int out_size, void* d_ws, size_t ws_size,
                              hipStream_t stream) {
    (void)in_sizes; (void)n_in; (void)out_size; (void)ws_size;
    const float* x     = (const float*)d_in[0];
    const float* w1    = (const float*)d_in[1];
    const float* w2    = (const float*)d_in[2];
    const float* w3    = (const float*)d_in[3];
    const float* tokw  = (const float*)d_in[4];
    const float* pos   = (const float*)d_in[5];
    const float* ln1s  = (const float*)d_in[6];
    const float* ln1b  = (const float*)d_in[7];
    const float* qkvw  = (const float*)d_in[8];
    const float* qkvb  = (const float*)d_in[9];
    const float* projw = (const float*)d_in[10];
    const float* projb = (const float*)d_in[11];
    const float* ln2s  = (const float*)d_in[12];
    const float* ln2b  = (const float*)d_in[13];
    const float* fc1w  = (const float*)d_in[14];
    const float* fc1b  = (const float*)d_in[15];
    const float* fc2w  = (const float*)d_in[16];
    const float* fc2b  = (const float*)d_in[17];
    const float* lnfs  = (const float*)d_in[18];
    const float* lnfb  = (const float*)d_in[19];
    const float* poolw = (const float*)d_in[20];
    const float* poolb = (const float*)d_in[21];
    const float* headw = (const float*)d_in[22];
    const float* headb = (const float*)d_in[23];
    float* out = (float*)d_out;
    char* ws = (char*)d_ws;

    uint64_t* B1P = (uint64_t*)(ws + 0);                  // 14,450,688
    uint32_t* B2P = (uint32_t*)(ws + 14450688);           //  2,408,448
    float*    H3  = (float*)(ws + 16859136);              //  2,408,448
    float*    W1T = (float*)(ws + 19267584);              //    112,896
    uint64_t* WP2 = (uint64_t*)(ws + 19380480);
    uint64_t* WN2 = (uint64_t*)(ws + 19418112);
    uint32_t* WP3 = (uint32_t*)(ws + 19455744);
    uint32_t* WN3 = (uint32_t*)(ws + 19457792);
    uint16_t* WQb = (uint16_t*)(ws + 19460096);           //  2,752,512
    uint16_t* WPb = (uint16_t*)(ws + 22212608);           //    917,504
    uint16_t* W1b = (uint16_t*)(ws + 23130112);           //  1,835,008
    uint16_t* W2b = (uint16_t*)(ws + 24965120);           //  1,835,008
    float*    TOK = (float*)(ws + 26800128);              // 51,380,224 [b][h][w][c]
    float*    Ffin= (float*)(ws + 26800128);              // aliases TOK (dead by then)
    float*    Z   = (float*)(ws + 78180352);              // 12,845,056
    uint16_t* Fbf = (uint16_t*)(ws + 91025408);           //  6,422,528
    uint16_t* Gbf = (uint16_t*)(ws + 97447936);           // 19,267,584
    uint16_t* Obf = (uint16_t*)(ws + 116715520);          //  6,422,528
    uint16_t* MLPb= (uint16_t*)(ws + 123138048);          // 12,845,056
    uint16_t* VT  = (uint16_t*)(ws + 135983104);          //  6,422,528

    k_prep<<<131, 256, 0, stream>>>(w1, w2, w3, W1T, WP2, WN2, WP3, WN3);
    k_cvtall<<<14336, 256, 0, stream>>>(qkvw, projw, fc1w, fc2w, WQb, WPb, W1b, W2b);

    k_conv1<<<dim3(112, 9, 4), 256, 0, stream>>>(x, W1T, B1P);
    k_conv2<<<dim3(112, 3, 4), 256, 0, stream>>>(B1P, WP2, WN2, B2P);
    k_conv3<<<2352, 256, 0, stream>>>(B2P, WP3, WN3, H3);
    k_tok<<<dim3(112, 4), 256, 0, stream>>>(H3, tokw, TOK);
    k_pool_z<<<12544, 256, 0, stream>>>(TOK, pos, Z);

    for (int l = 0; l < 7; l++) {
        k_ln<<<3136, 256, 0, stream>>>(Z, ln1s + l * 256, ln1b + l * 256, Fbf, 1);
        k_gemm<<<dim3(6, 98), 256, 0, stream>>>(Fbf, WQb + (long)l * 196608,
                                                qkvb + l * 768, Gbf,
                                                12544, 768, 256, 0, 0);
        k_vt<<<dim3(49, 4, 4), 256, 0, stream>>>(Gbf, VT);
        k_flash<<<dim3(49, 4, 4), 256, 0, stream>>>(Gbf, VT, Obf);
        k_gemm<<<dim3(2, 98), 256, 0, stream>>>(Obf, WPb + (long)l * 65536,
                                                projb + l * 256, Z,
                                                12544, 256, 256, 0, 1);
        k_ln<<<3136, 256, 0, stream>>>(Z, ln2s + l * 256, ln2b + l * 256, Fbf, 1);
        k_gemm<<<dim3(4, 98), 256, 0, stream>>>(Fbf, W1b + (long)l * 131072,
                                                fc1b + l * 512, MLPb,
                                                12544, 512, 256, 1, 0);
        k_gemm<<<dim3(2, 98), 256, 0, stream>>>(MLPb, W2b + (long)l * 131072,
                                                fc2b + l * 256, Z,
                                                12544, 256, 512, 0, 1);
    }

    k_ln<<<3136, 256, 0, stream>>>(Z, lnfs, lnfb, Ffin, 0);
    k_tail<<<4, 256, 0, stream>>>(Ffin, poolw, poolb, headw, headb, out);
}

// Round 6
// 5309.249 us; speedup vs baseline: 5.8352x; 1.1169x over previous
//
#include <hip/hip_runtime.h>
#include <hip/hip_bf16.h>
#include <cstdint>

#define SEQL 3136

typedef __attribute__((ext_vector_type(8))) short v8s;
typedef __attribute__((ext_vector_type(4))) float f32x4;

__device__ __forceinline__ uint16_t bf16u(float f) {
    uint32_t u = __float_as_uint(f);
    uint32_t r = u + 0x7fff + ((u >> 16) & 1);   // RNE
    return (uint16_t)(r >> 16);
}
__device__ __forceinline__ float bf2f(uint16_t b) {
    uint32_t u = ((uint32_t)b) << 16;
    return __uint_as_float(u);
}

// ---------------- merged prep: bf16 weight cvt + conv1 bf16 sign-W + conv2/3 masks ----
__global__ __launch_bounds__(256) void k_prep(const float* __restrict__ qw,
                                              const float* __restrict__ pw,
                                              const float* __restrict__ f1,
                                              const float* __restrict__ f2,
                                              const float* __restrict__ w1,
                                              const float* __restrict__ w2,
                                              const float* __restrict__ w3,
                                              uint16_t* __restrict__ dq,
                                              uint16_t* __restrict__ dp,
                                              uint16_t* __restrict__ d1,
                                              uint16_t* __restrict__ d2,
                                              uint16_t* __restrict__ w1b,
                                              uint64_t* __restrict__ wp2,
                                              uint64_t* __restrict__ wn2,
                                              uint32_t* __restrict__ wp3,
                                              uint32_t* __restrict__ wn3) {
    int gid = blockIdx.x * 256 + threadIdx.x;
    if (gid < 1376256) { dq[gid] = bf16u(qw[gid]); return; }
    if (gid < 1835008) { int i = gid - 1376256; dp[i] = bf16u(pw[i]); return; }
    if (gid < 2752512) { int i = gid - 1835008; d1[i] = bf16u(f1[i]); return; }
    if (gid < 3670016) { int i = gid - 2752512; d2[i] = bf16u(f2[i]); return; }
    if (gid < 3698688) {
        // conv1 sign weights as bf16: W1B[kw][oc][c=(ic*3+kd)*7+kh], c=63 -> 0
        int i = gid - 3670016;
        int c = i & 63, oc = (i >> 6) & 63, kw = i >> 12;
        uint16_t v = 0;
        if (c < 63) {
            int ic = c / 21, rem = c % 21, kd = rem / 7, kh = rem % 7;
            float w = w1[((((oc * 3 + ic) * 3 + kd) * 7 + kh) * 7) + kw];
            v = (w > 0.f) ? 0x3F80 : ((w < 0.f) ? 0xBF80 : 0);
        }
        w1b[i] = v;
        return;
    }
    if (gid < 3703392) {
        int i = gid - 3698688;
        int oc = i / 147, r = i % 147;
        uint64_t p = 0, n = 0;
        for (int ic = 0; ic < 64; ic++) {
            float v = w2[(long)oc * 9408 + (long)ic * 147 + r];
            if (v > 0.f) p |= (1ull << ic);
            else if (v < 0.f) n |= (1ull << ic);
        }
        wp2[i] = p; wn2[i] = n;
        return;
    }
    if (gid < 3703833) {
        int i = gid - 3703392;
        int oc = i / 147, r = i % 147;
        uint32_t p = 0, n = 0;
        for (int ic = 0; ic < 32; ic++) {
            float v = w3[(long)oc * 4704 + (long)ic * 147 + r];
            if (v > 0.f) p |= (1u << ic);
            else if (v < 0.f) n |= (1u << ic);
        }
        wp3[i] = p; wn3[i] = n;
    }
}

// ---------------- conv1: MFMA implicit GEMM, 3-way bf16 split, packed u64 out --------
// block = (oh, od, b). M=224 ow (14 tiles), N=64 oc (4 tiles), K = 7kw x 64c.
__global__ __launch_bounds__(256) void k_conv1m(const float* __restrict__ x,
                                                const uint16_t* __restrict__ w1b,
                                                uint64_t* __restrict__ b1p) {
    __shared__ __align__(16) uint16_t Xt[232 * 72];   // [col][c] one split at a time
    __shared__ __align__(16) uint16_t Wb[64 * 72];    // [oc][c] for current kw
    __shared__ uint16_t obits16[224 * 4];
    int tid = threadIdx.x;
    int oh = blockIdx.x, od = blockIdx.y, b = blockIdx.z;
    int lane = tid & 63, wv = tid >> 6;
    int wm = wv >> 1, wn = wv & 1;
    int tl = lane & 15, g = lane >> 4;

    f32x4 acc[7][2];
#pragma unroll
    for (int mt = 0; mt < 7; mt++) {
        acc[mt][0] = (f32x4){0.f, 0.f, 0.f, 0.f};
        acc[mt][1] = (f32x4){0.f, 0.f, 0.f, 0.f};
    }

    for (int s = 0; s < 3; s++) {
        __syncthreads();   // prior reads of Xt done
        // stage Xt split s: 7424 u32 (col 0..231, c-pair 0..31)
        for (int it = 0; it < 29; it++) {
            int idx = it * 256 + tid;
            int col = idx % 232, cp = idx / 232;
            int c0 = cp * 2;
            uint32_t w = 0;
#pragma unroll
            for (int half = 0; half < 2; half++) {
                int c = c0 + half;
                float v = 0.f;
                if (c < 63) {
                    int ic = c / 21, rem = c % 21, kd = rem / 7, kh = rem % 7;
                    int d = od * 3 - 1 + kd;
                    int ih = oh - 3 + kh;
                    int iw = col - 3;
                    if ((unsigned)d < 27u && (unsigned)ih < 224u && (unsigned)iw < 224u)
                        v = x[((long)(b * 3 + ic) * 27 + d) * 50176 + ih * 224 + iw];
                }
                uint16_t hi = bf16u(v);
                uint16_t outp = hi;
                if (s > 0) {
                    float r1 = v - bf2f(hi);
                    uint16_t lo = bf16u(r1);
                    outp = lo;
                    if (s == 2) outp = bf16u(r1 - bf2f(lo));
                }
                w |= ((uint32_t)outp) << (16 * half);
            }
            *(uint32_t*)&Xt[col * 72 + c0] = w;
        }
        for (int kw = 0; kw < 7; kw++) {
            __syncthreads();   // prev Wb reads done (and Xt visible on kw==0)
            // stage Wb[kw]: 2048 u32
            for (int it = 0; it < 8; it++) {
                int idx = it * 256 + tid;
                int c2 = idx & 31, oc = idx >> 5;
                *(uint32_t*)&Wb[oc * 72 + c2 * 2] =
                    ((const uint32_t*)w1b)[kw * 2048 + oc * 32 + c2];
            }
            __syncthreads();
#pragma unroll
            for (int ks = 0; ks < 2; ks++) {
                v8s b0 = *(const v8s*)&Wb[(wn * 32 + tl) * 72 + ks * 32 + g * 8];
                v8s b1 = *(const v8s*)&Wb[(wn * 32 + 16 + tl) * 72 + ks * 32 + g * 8];
#pragma unroll
                for (int mt = 0; mt < 7; mt++) {
                    int colb = (wm * 7 + mt) * 16 + tl + kw;   // Xt index = xcol+3
                    v8s a = *(const v8s*)&Xt[colb * 72 + ks * 32 + g * 8];
                    acc[mt][0] = __builtin_amdgcn_mfma_f32_16x16x32_bf16(a, b0, acc[mt][0], 0, 0, 0);
                    acc[mt][1] = __builtin_amdgcn_mfma_f32_16x16x32_bf16(a, b1, acc[mt][1], 0, 0, 0);
                }
            }
        }
    }
    // epilogue: ballot -> 16-bit oc pieces
#pragma unroll
    for (int mt = 0; mt < 7; mt++)
#pragma unroll
        for (int nt = 0; nt < 2; nt++)
#pragma unroll
            for (int r = 0; r < 4; r++) {
                unsigned long long mask = __ballot(acc[mt][nt][r] > 0.f);
                if (tl == 0) {
                    int ow = (wm * 7 + mt) * 16 + g * 4 + r;
                    obits16[ow * 4 + wn * 2 + nt] = (uint16_t)(mask >> (g * 16));
                }
            }
    __syncthreads();
    if (tid < 224) {
        uint64_t w = (uint64_t)obits16[tid * 4]
                   | ((uint64_t)obits16[tid * 4 + 1] << 16)
                   | ((uint64_t)obits16[tid * 4 + 2] << 32)
                   | ((uint64_t)obits16[tid * 4 + 3] << 48);
        b1p[(((long)b * 9 + od) * 224 + oh) * 224 + tid] = w;
    }
}

// ---------------- conv2: 2-oh blocking, LDS patch + popcount, packed u32 out ---------
__global__ __launch_bounds__(256) void k_conv2(const uint64_t* __restrict__ bp1,
                                               const uint64_t* __restrict__ wp,
                                               const uint64_t* __restrict__ wn,
                                               uint32_t* __restrict__ b2p) {
    __shared__ uint64_t xs[24 * 232];
    __shared__ uint32_t obits[2][224];
    int tid = threadIdx.x;
    int oh0 = blockIdx.x * 2, od = blockIdx.y, b = blockIdx.z;
    for (int i = tid; i < 24 * 232; i += 256) {
        int col = i % 232; int t = i / 232;
        int kh = t & 7; int kd = t >> 3;
        int d = od * 3 - 1 + kd;
        int h = oh0 - 3 + kh;
        int w = col - 3;
        uint64_t v = 0;
        if ((unsigned)d < 9u && (unsigned)h < 224u && (unsigned)w < 224u)
            v = bp1[(((long)b * 9 + d) * 224 + h) * 224 + w];
        xs[i] = v;
    }
    if (tid < 224) { obits[0][tid] = 0; obits[1][tid] = 0; }
    __syncthreads();
    int tx = tid & 15, ty = tid >> 4;
    int ow0 = tx * 14, oc0 = ty * 2;
#pragma unroll
    for (int oi = 0; oi < 2; oi++) {
        int acc0[14], acc1[14];
#pragma unroll
        for (int o2 = 0; o2 < 14; o2++) { acc0[o2] = 0; acc1[o2] = 0; }
        for (int kd = 0; kd < 3; kd++) {
#pragma unroll
            for (int kh = 0; kh < 7; kh++) {
                const uint64_t* row = &xs[(kd * 8 + kh + oi) * 232 + ow0];
                uint64_t xv[20];
#pragma unroll
                for (int t = 0; t < 20; t++) xv[t] = row[t];
                int rbase = kd * 49 + kh * 7;
#pragma unroll
                for (int kw = 0; kw < 7; kw++) {
                    uint64_t p0 = wp[oc0 * 147 + rbase + kw];
                    uint64_t n0 = wn[oc0 * 147 + rbase + kw];
                    uint64_t p1 = wp[(oc0 + 1) * 147 + rbase + kw];
                    uint64_t n1 = wn[(oc0 + 1) * 147 + rbase + kw];
#pragma unroll
                    for (int o2 = 0; o2 < 14; o2++) {
                        uint64_t bits = xv[o2 + kw];
                        acc0[o2] += __popcll(bits & p0) - __popcll(bits & n0);
                        acc1[o2] += __popcll(bits & p1) - __popcll(bits & n1);
                    }
                }
            }
        }
#pragma unroll
        for (int o2 = 0; o2 < 14; o2++) {
            uint32_t v = (uint32_t)((acc0[o2] > 0) | ((acc1[o2] > 0) << 1));
            if (v) atomicOr(&obits[oi][ow0 + o2], v << oc0);
        }
    }
    __syncthreads();
    if (tid < 224) {
        long base = (((long)b * 3 + od) * 224 + oh0) * 224 + tid;
        b2p[base] = obits[0][tid];
        b2p[base + 224] = obits[1][tid];
    }
}

// conv3 via popcount -> fp32 relu count
__global__ __launch_bounds__(256) void k_conv3(const uint32_t* __restrict__ bp2,
                                               const uint32_t* __restrict__ wp,
                                               const uint32_t* __restrict__ wn,
                                               float* __restrict__ h3) {
    int gid = blockIdx.x * 256 + threadIdx.x;  // 602,112
    int q = gid;
    int ow = q % 224; q /= 224;
    int oh = q % 224; q /= 224;
    int oc = q % 3;   int b = q / 3;
    int acc = 0;
    for (int kd = 0; kd < 3; kd++) {
        int d = kd - 1;
        if ((unsigned)d >= 3u) continue;
        for (int kh = 0; kh < 7; kh++) {
            int h = oh - 3 + kh;
            if ((unsigned)h >= 224u) continue;
            const uint32_t* bp = bp2 + ((long)(b * 3 + d) * 224 + h) * 224;
            const uint32_t* mp = wp + ((oc * 3 + kd) * 7 + kh) * 7;
            const uint32_t* mn = wn + ((oc * 3 + kd) * 7 + kh) * 7;
#pragma unroll
            for (int kw = 0; kw < 7; kw++) {
                int w = ow - 3 + kw;
                if ((unsigned)w < 224u) {
                    uint32_t bits = bp[w];
                    acc += __popc(bits & mp[kw]) - __popc(bits & mn[kw]);
                }
            }
        }
    }
    h3[gid] = fmaxf((float)acc, 0.f);
}

// ---------------- tokenizer conv; tok layout [b][h][w][c] ----------------
__global__ __launch_bounds__(256) void k_tok(const float* __restrict__ h3,
                                             const float* __restrict__ wt,
                                             float* __restrict__ tok) {
    __shared__ float xs[3 * 7 * 232];
    int tid = threadIdx.x;
    int oh = blockIdx.x, b = blockIdx.y;
    for (int i = tid; i < 3 * 7 * 232; i += 256) {
        int col = i % 232; int t = i / 232;
        int kh = t % 7; int ic = t / 7;
        int ih = oh * 2 - 3 + kh;
        int iw = col - 3;
        float v = 0.f;
        if ((unsigned)ih < 224u && (unsigned)iw < 224u)
            v = h3[((long)(b * 3 + ic) * 50176) + ih * 224 + iw];
        xs[i] = v;
    }
    __syncthreads();
    int oc = tid;
    float* obase = tok + ((long)(b * 112 + oh) * 112) * 256 + oc;
    for (int chunk = 0; chunk < 4; chunk++) {
        int ow0 = chunk * 28;
        float acc[28];
#pragma unroll
        for (int o2 = 0; o2 < 28; o2++) acc[o2] = 0.f;
        for (int ic = 0; ic < 3; ic++) {
#pragma unroll
            for (int kh = 0; kh < 7; kh++) {
                const float* row = &xs[(ic * 7 + kh) * 232 + ow0 * 2];
                float xv[61];
#pragma unroll
                for (int t = 0; t < 61; t++) xv[t] = row[t];
                const float* wr = wt + (oc * 3 + ic) * 49 + kh * 7;
                float w[7];
#pragma unroll
                for (int kw = 0; kw < 7; kw++) w[kw] = wr[kw];
#pragma unroll
                for (int kw = 0; kw < 7; kw++)
#pragma unroll
                    for (int o2 = 0; o2 < 28; o2++)
                        acc[o2] = fmaf(w[kw], xv[2 * o2 + kw], acc[o2]);
            }
        }
#pragma unroll
        for (int o2 = 0; o2 < 28; o2++)
            obase[(long)(ow0 + o2) * 256] = fmaxf(acc[o2], 0.f);
    }
}

// maxpool 3x3 s2 p1 + pos_emb
__global__ __launch_bounds__(256) void k_pool_z(const float* __restrict__ tok,
                                                const float* __restrict__ pos,
                                                float* __restrict__ z) {
    int gid = blockIdx.x * 256 + threadIdx.x;
    int c = gid & 255;
    int n = (gid >> 8) % SEQL;
    int b = gid / (256 * SEQL);
    int oh = n / 56, ow = n % 56;
    const float* tp = tok + ((long)b * 112 * 112) * 256 + c;
    float m = -1e30f;
#pragma unroll
    for (int kh = 0; kh < 3; kh++) {
        int h = oh * 2 - 1 + kh;
        if ((unsigned)h >= 112u) continue;
#pragma unroll
        for (int kw = 0; kw < 3; kw++) {
            int w = ow * 2 - 1 + kw;
            if ((unsigned)w < 112u) m = fmaxf(m, tp[(long)(h * 112 + w) * 256]);
        }
    }
    z[gid] = m + pos[n * 256 + c];
}

// ---------------- GEMM with fused layernorm on A (A = LN(Z) rows) ----------------
// C_bf16 = act(LN(Z) @ W^T + bias); optional fused V-transpose into VT (qkv only).
__global__ __launch_bounds__(256) void k_gemm_ln(const float* __restrict__ Z,
                                                 const uint16_t* __restrict__ W,
                                                 const float* __restrict__ lns,
                                                 const float* __restrict__ lnb,
                                                 const float* __restrict__ bias,
                                                 uint16_t* __restrict__ C,
                                                 uint16_t* __restrict__ VT,
                                                 int N, int dogelu, int dovt) {
    __shared__ uint16_t As[128 * 40], Bs[128 * 40];
    __shared__ float mu[128], rsd[128];
    int tid = threadIdx.x;
    int lane = tid & 63, wave = tid >> 6;
    int wm = wave >> 1, wn = wave & 1;
    int m0 = blockIdx.y * 128, n0 = blockIdx.x * 128;
    // row stats: 2 threads per row
    {
        int row = tid >> 1, hf = tid & 1;
        const float* zr = Z + (long)(m0 + row) * 256 + hf * 128;
        float s = 0.f, sq = 0.f;
        for (int i = 0; i < 128; i++) { float v = zr[i]; s += v; sq += v * v; }
        s += __shfl_xor(s, 1); sq += __shfl_xor(sq, 1);
        if (hf == 0) {
            float m = s * (1.0f / 256.0f);
            mu[row] = m;
            rsd[row] = rsqrtf(sq * (1.0f / 256.0f) - m * m + 1e-5f);
        }
    }
    f32x4 acc[4][4];
#pragma unroll
    for (int i = 0; i < 4; i++)
#pragma unroll
        for (int j = 0; j < 4; j++) acc[i][j] = (f32x4){0.f, 0.f, 0.f, 0.f};
    int rl = lane & 15, kq = (lane >> 4) * 8;
    for (int k0 = 0; k0 < 256; k0 += 32) {
        __syncthreads();
        // stage A normalized: 128x32
#pragma unroll
        for (int c2 = 0; c2 < 16; c2++) {
            int idx = c2 * 256 + tid;
            int col = idx & 31, row = idx >> 5;
            float v = Z[(long)(m0 + row) * 256 + k0 + col];
            v = (v - mu[row]) * rsd[row] * lns[k0 + col] + lnb[k0 + col];
            As[row * 40 + col] = bf16u(v);
        }
#pragma unroll
        for (int c = 0; c < 2; c++) {
            int idx = c * 256 + tid;
            int row = idx >> 2, k8 = (idx & 3) * 8;
            *(uint4*)&Bs[row * 40 + k8] = *(const uint4*)&W[(long)(n0 + row) * 256 + k0 + k8];
        }
        __syncthreads();
        v8s a[4], bb[4];
#pragma unroll
        for (int i = 0; i < 4; i++) a[i] = *(const v8s*)&As[(wm * 64 + i * 16 + rl) * 40 + kq];
#pragma unroll
        for (int j = 0; j < 4; j++) bb[j] = *(const v8s*)&Bs[(wn * 64 + j * 16 + rl) * 40 + kq];
#pragma unroll
        for (int i = 0; i < 4; i++)
#pragma unroll
            for (int j = 0; j < 4; j++)
                acc[i][j] = __builtin_amdgcn_mfma_f32_16x16x32_bf16(a[i], bb[j], acc[i][j], 0, 0, 0);
    }
    int rq = (lane >> 4) * 4;
    bool vt = (dovt != 0) && (n0 >= 512);
#pragma unroll
    for (int i = 0; i < 4; i++) {
#pragma unroll
        for (int j = 0; j < 4; j++) {
            int col = n0 + wn * 64 + j * 16 + rl;
            float bval = bias[col];
#pragma unroll
            for (int r = 0; r < 4; r++) {
                int row = m0 + wm * 64 + i * 16 + rq + r;
                float v = acc[i][j][r] + bval;
                if (dogelu) v = 0.5f * v * (1.0f + erff(v * 0.70710678118654752f));
                if (vt) {
                    int hv = col - 512;
                    int h = hv >> 6, d = hv & 63;
                    int bb2 = row / SEQL, nn = row - bb2 * SEQL;
                    VT[((long)(bb2 * 4 + h) * 64 + d) * SEQL + nn] = bf16u(v);
                } else {
                    C[(long)row * N + col] = bf16u(v);
                }
            }
        }
    }
}

// ---------------- plain bf16 GEMM (A bf16), resid fp32 += ----------------
__global__ __launch_bounds__(256) void k_gemm(const uint16_t* __restrict__ A,
                                              const uint16_t* __restrict__ W,
                                              const float* __restrict__ bias,
                                              float* __restrict__ C,
                                              int M, int N, int K) {
    __shared__ uint16_t As[128 * 40], Bs[128 * 40];
    int tid = threadIdx.x;
    int lane = tid & 63, wave = tid >> 6;
    int wm = wave >> 1, wn = wave & 1;
    int m0 = blockIdx.y * 128, n0 = blockIdx.x * 128;
    f32x4 acc[4][4];
#pragma unroll
    for (int i = 0; i < 4; i++)
#pragma unroll
        for (int j = 0; j < 4; j++) acc[i][j] = (f32x4){0.f, 0.f, 0.f, 0.f};
    int rl = lane & 15, kq = (lane >> 4) * 8;
    for (int k0 = 0; k0 < K; k0 += 32) {
        __syncthreads();
#pragma unroll
        for (int c = 0; c < 2; c++) {
            int idx = c * 256 + tid;
            int row = idx >> 2, k8 = (idx & 3) * 8;
            *(uint4*)&As[row * 40 + k8] = *(const uint4*)&A[(long)(m0 + row) * K + k0 + k8];
            *(uint4*)&Bs[row * 40 + k8] = *(const uint4*)&W[(long)(n0 + row) * K + k0 + k8];
        }
        __syncthreads();
        v8s a[4], bb[4];
#pragma unroll
        for (int i = 0; i < 4; i++) a[i] = *(const v8s*)&As[(wm * 64 + i * 16 + rl) * 40 + kq];
#pragma unroll
        for (int j = 0; j < 4; j++) bb[j] = *(const v8s*)&Bs[(wn * 64 + j * 16 + rl) * 40 + kq];
#pragma unroll
        for (int i = 0; i < 4; i++)
#pragma unroll
            for (int j = 0; j < 4; j++)
                acc[i][j] = __builtin_amdgcn_mfma_f32_16x16x32_bf16(a[i], bb[j], acc[i][j], 0, 0, 0);
    }
    int rq = (lane >> 4) * 4;
#pragma unroll
    for (int i = 0; i < 4; i++) {
#pragma unroll
        for (int j = 0; j < 4; j++) {
            int col = n0 + wn * 64 + j * 16 + rl;
            float bval = bias[col];
#pragma unroll
            for (int r = 0; r < 4; r++) {
                int row = m0 + wm * 64 + i * 16 + rq + r;
                C[(long)row * N + col] += acc[i][j][r] + bval;
            }
        }
    }
}

// ---------------- flash attention, bf16 MFMA, pre-transposed V, b128 staging -------
__global__ __launch_bounds__(256) void k_flash(const uint16_t* __restrict__ G,
                                               const uint16_t* __restrict__ VT,
                                               uint16_t* __restrict__ o) {
    __shared__ __align__(16) uint32_t Qs[64 * 36], Ks[64 * 36], Vt[64 * 36];
    __shared__ __align__(16) uint16_t Ps[64 * 72];
    int tid = threadIdx.x;
    int lane = tid & 63, wv = tid >> 6;
    int qt = blockIdx.x, h = blockIdx.y, b = blockIdx.z;
    long base = (long)b * SEQL * 768 + h * 64;
    long vtbase = ((long)(b * 4 + h) * 64) * SEQL;
#pragma unroll
    for (int it = 0; it < 2; it++) {
        int idx = it * 256 + tid;
        int q8 = idx & 7, r = idx >> 3;
        *(uint4*)&Qs[r * 36 + q8 * 4] = *(const uint4*)&G[base + (long)(qt * 64 + r) * 768 + q8 * 8];
    }
    int g = lane >> 4, tl = lane & 15;
    int qr0 = wv * 16;
    __syncthreads();
    v8s aq[2];
#pragma unroll
    for (int ks = 0; ks < 2; ks++)
        aq[ks] = *(const v8s*)&Qs[(qr0 + tl) * 36 + ks * 16 + g * 4];

    float m_[4], l_[4];
    f32x4 ov[4];
#pragma unroll
    for (int r = 0; r < 4; r++) { m_[r] = -1e30f; l_[r] = 0.f; }
#pragma unroll
    for (int j = 0; j < 4; j++) ov[j] = (f32x4){0.f, 0.f, 0.f, 0.f};

    for (int kt = 0; kt < 49; kt++) {
        __syncthreads();
#pragma unroll
        for (int it = 0; it < 2; it++) {
            int idx = it * 256 + tid;
            int q8 = idx & 7, r = idx >> 3;
            *(uint4*)&Ks[r * 36 + q8 * 4] =
                *(const uint4*)&G[base + (long)(kt * 64 + r) * 768 + 256 + q8 * 8];
        }
#pragma unroll
        for (int it = 0; it < 2; it++) {
            int idx = it * 256 + tid;
            int r8 = idx & 7, d = idx >> 3;
            *(uint4*)&Vt[d * 36 + r8 * 4] =
                *(const uint4*)&VT[vtbase + (long)d * SEQL + kt * 64 + r8 * 8];
        }
        __syncthreads();
        f32x4 s[4];
#pragma unroll
        for (int j = 0; j < 4; j++) s[j] = (f32x4){0.f, 0.f, 0.f, 0.f};
#pragma unroll
        for (int ks = 0; ks < 2; ks++) {
#pragma unroll
            for (int j = 0; j < 4; j++) {
                v8s bk = *(const v8s*)&Ks[(j * 16 + tl) * 36 + ks * 16 + g * 4];
                s[j] = __builtin_amdgcn_mfma_f32_16x16x32_bf16(aq[ks], bk, s[j], 0, 0, 0);
            }
        }
        float alpha[4];
#pragma unroll
        for (int r = 0; r < 4; r++) {
            float s0 = s[0][r] * 0.125f, s1 = s[1][r] * 0.125f;
            float s2 = s[2][r] * 0.125f, s3 = s[3][r] * 0.125f;
            s[0][r] = s0; s[1][r] = s1; s[2][r] = s2; s[3][r] = s3;
            float mx = fmaxf(fmaxf(s0, s1), fmaxf(s2, s3));
#pragma unroll
            for (int off = 1; off < 16; off <<= 1) mx = fmaxf(mx, __shfl_xor(mx, off));
            float nm = fmaxf(m_[r], mx);
            alpha[r] = __expf(m_[r] - nm);
            float rs = 0.f;
#pragma unroll
            for (int j = 0; j < 4; j++) {
                float p = __expf(s[j][r] - nm);
                s[j][r] = p; rs += p;
            }
#pragma unroll
            for (int off = 1; off < 16; off <<= 1) rs += __shfl_xor(rs, off);
            l_[r] = l_[r] * alpha[r] + rs;
            m_[r] = nm;
        }
#pragma unroll
        for (int j = 0; j < 4; j++)
#pragma unroll
            for (int r = 0; r < 4; r++) ov[j][r] *= alpha[r];
#pragma unroll
        for (int j = 0; j < 4; j++)
#pragma unroll
            for (int r = 0; r < 4; r++)
                Ps[(qr0 + g * 4 + r) * 72 + j * 16 + tl] = bf16u(s[j][r]);
#pragma unroll
        for (int ks = 0; ks < 2; ks++) {
            v8s ap = *(const v8s*)&Ps[(qr0 + tl) * 72 + ks * 32 + g * 8];
#pragma unroll
            for (int jd = 0; jd < 4; jd++) {
                v8s bv = *(const v8s*)&Vt[(jd * 16 + tl) * 36 + ks * 16 + g * 4];
                ov[jd] = __builtin_amdgcn_mfma_f32_16x16x32_bf16(ap, bv, ov[jd], 0, 0, 0);
            }
        }
    }
    long ob = ((long)b * SEQL + qt * 64) * 256 + h * 64;
#pragma unroll
    for (int r = 0; r < 4; r++) {
        float inv = 1.0f / l_[r];
        int row = qr0 + g * 4 + r;
#pragma unroll
        for (int jd = 0; jd < 4; jd++)
            o[ob + (long)row * 256 + jd * 16 + tl] = bf16u(ov[jd][r] * inv);
    }
}

// ---------------- fused tail: final LN + pool logits + softmax + pooled + head -----
__global__ __launch_bounds__(256) void k_tail(const float* __restrict__ Z,
                                              const float* __restrict__ g,
                                              const float* __restrict__ be,
                                              const float* __restrict__ pw,
                                              const float* __restrict__ pb,
                                              const float* __restrict__ hw,
                                              const float* __restrict__ hb,
                                              float* __restrict__ out) {
    __shared__ float lg[SEQL];
    __shared__ float muA[SEQL];
    __shared__ float rsA[SEQL];
    __shared__ float red[256];
    __shared__ float pooled[256];
    __shared__ float sBsh;
    int b = blockIdx.x, tid = threadIdx.x;
    int wv = tid >> 6, lane = tid & 63;
    const float* Zb = Z + (long)b * SEQL * 256;
    for (int r = wv; r < SEQL; r += 4) {
        const float* xr = Zb + (long)r * 256;
        float v0 = xr[lane], v1 = xr[lane + 64], v2 = xr[lane + 128], v3 = xr[lane + 192];
        float s = v0 + v1 + v2 + v3;
#pragma unroll
        for (int off = 1; off < 64; off <<= 1) s += __shfl_xor(s, off);
        float mean = s * (1.0f / 256.0f);
        float d0 = v0 - mean, d1 = v1 - mean, d2 = v2 - mean, d3 = v3 - mean;
        float sq = d0 * d0 + d1 * d1 + d2 * d2 + d3 * d3;
#pragma unroll
        for (int off = 1; off < 64; off <<= 1) sq += __shfl_xor(sq, off);
        float rs_ = rsqrtf(sq * (1.0f / 256.0f) + 1e-5f);
        float a = (d0 * rs_ * g[lane] + be[lane]) * pw[lane]
                + (d1 * rs_ * g[lane + 64] + be[lane + 64]) * pw[lane + 64]
                + (d2 * rs_ * g[lane + 128] + be[lane + 128]) * pw[lane + 128]
                + (d3 * rs_ * g[lane + 192] + be[lane + 192]) * pw[lane + 192];
#pragma unroll
        for (int off = 1; off < 64; off <<= 1) a += __shfl_xor(a, off);
        if (lane == 0) { lg[r] = a + pb[0]; muA[r] = mean; rsA[r] = rs_; }
    }
    __syncthreads();
    float m = -1e30f;
    for (int i = tid; i < SEQL; i += 256) m = fmaxf(m, lg[i]);
    red[tid] = m; __syncthreads();
    for (int s = 128; s > 0; s >>= 1) {
        if (tid < s) red[tid] = fmaxf(red[tid], red[tid + s]);
        __syncthreads();
    }
    float M = red[0]; __syncthreads();
    float sum = 0.f;
    for (int i = tid; i < SEQL; i += 256) sum += expf(lg[i] - M);
    red[tid] = sum; __syncthreads();
    for (int s = 128; s > 0; s >>= 1) {
        if (tid < s) red[tid] += red[tid + s];
        __syncthreads();
    }
    float inv = 1.0f / red[0];
    __syncthreads();
    // probabilities, then t[n]=p*rs and scalarB = sum p*mu*rs
    float pB = 0.f;
    for (int i = tid; i < SEQL; i += 256) {
        float p = expf(lg[i] - M) * inv;
        pB += p * muA[i] * rsA[i];
        rsA[i] = p * rsA[i];
    }
    red[tid] = pB; __syncthreads();
    for (int s = 128; s > 0; s >>= 1) {
        if (tid < s) red[tid] += red[tid + s];
        __syncthreads();
    }
    if (tid == 0) sBsh = red[0];
    __syncthreads();
    float sB = sBsh;
    float acc = 0.f;
    for (int n = 0; n < SEQL; n++) acc = fmaf(rsA[n], Zb[(long)n * 256 + tid], acc);
    pooled[tid] = g[tid] * (acc - sB) + be[tid];
    __syncthreads();
    if (tid < 101) {
        float a = hb[tid];
        for (int d = 0; d < 256; d++) a = fmaf(pooled[d], hw[tid * 256 + d], a);
        out[b * 101 + tid] = a;
    }
}

// ---------------------------------------------------------------------------
extern "C" void kernel_launch(void* const* d_in, const int* in_sizes, int n_in,
                              void* d_out, int out_size, void* d_ws, size_t ws_size,
                              hipStream_t stream) {
    (void)in_sizes; (void)n_in; (void)out_size; (void)ws_size;
    const float* x     = (const float*)d_in[0];
    const float* w1    = (const float*)d_in[1];
    const float* w2    = (const float*)d_in[2];
    const float* w3    = (const float*)d_in[3];
    const float* tokw  = (const float*)d_in[4];
    const float* pos   = (const float*)d_in[5];
    const float* ln1s  = (const float*)d_in[6];
    const float* ln1b  = (const float*)d_in[7];
    const float* qkvw  = (const float*)d_in[8];
    const float* qkvb  = (const float*)d_in[9];
    const float* projw = (const float*)d_in[10];
    const float* projb = (const float*)d_in[11];
    const float* ln2s  = (const float*)d_in[12];
    const float* ln2b  = (const float*)d_in[13];
    const float* fc1w  = (const float*)d_in[14];
    const float* fc1b  = (const float*)d_in[15];
    const float* fc2w  = (const float*)d_in[16];
    const float* fc2b  = (const float*)d_in[17];
    const float* lnfs  = (const float*)d_in[18];
    const float* lnfb  = (const float*)d_in[19];
    const float* poolw = (const float*)d_in[20];
    const float* poolb = (const float*)d_in[21];
    const float* headw = (const float*)d_in[22];
    const float* headb = (const float*)d_in[23];
    float* out = (float*)d_out;
    char* ws = (char*)d_ws;

    uint64_t* B1P = (uint64_t*)(ws + 0);                  // 14,450,688
    uint32_t* B2P = (uint32_t*)(ws + 14450688);           //  2,408,448
    float*    H3  = (float*)(ws + 16859136);              //  2,408,448
    uint16_t* W1B = (uint16_t*)(ws + 19267584);           //     57,344
    uint64_t* WP2 = (uint64_t*)(ws + 19324928);           //     37,632
    uint64_t* WN2 = (uint64_t*)(ws + 19362560);           //     37,632
    uint32_t* WP3 = (uint32_t*)(ws + 19400192);           //      2,048
    uint32_t* WN3 = (uint32_t*)(ws + 19402240);           //      2,048
    uint16_t* WQb = (uint16_t*)(ws + 19404288);           //  2,752,512
    uint16_t* WPb = (uint16_t*)(ws + 22156800);           //    917,504
    uint16_t* W1b = (uint16_t*)(ws + 23074304);           //  1,835,008
    uint16_t* W2b = (uint16_t*)(ws + 24909312);           //  1,835,008
    float*    TOK = (float*)(ws + 26744320);              // 51,380,224 [b][h][w][c]
    float*    Z   = (float*)(ws + 78124544);              // 12,845,056
    uint16_t* Gbf = (uint16_t*)(ws + 90969600);           // 19,267,584
    uint16_t* Obf = (uint16_t*)(ws + 110237184);          //  6,422,528
    uint16_t* MLPb= (uint16_t*)(ws + 116659712);          // 12,845,056
    uint16_t* VT  = (uint16_t*)(ws + 129504768);          //  6,422,528

    k_prep<<<14469, 256, 0, stream>>>(qkvw, projw, fc1w, fc2w, w1, w2, w3,
                                      WQb, WPb, W1b, W2b, W1B, WP2, WN2, WP3, WN3);

    k_conv1m<<<dim3(224, 9, 4), 256, 0, stream>>>(x, W1B, B1P);
    k_conv2<<<dim3(112, 3, 4), 256, 0, stream>>>(B1P, WP2, WN2, B2P);
    k_conv3<<<2352, 256, 0, stream>>>(B2P, WP3, WN3, H3);
    k_tok<<<dim3(112, 4), 256, 0, stream>>>(H3, tokw, TOK);
    k_pool_z<<<12544, 256, 0, stream>>>(TOK, pos, Z);

    for (int l = 0; l < 7; l++) {
        k_gemm_ln<<<dim3(6, 98), 256, 0, stream>>>(Z, WQb + (long)l * 196608,
                                                   ln1s + l * 256, ln1b + l * 256,
                                                   qkvb + l * 768, Gbf, VT,
                                                   768, 0, 1);
        k_flash<<<dim3(49, 4, 4), 256, 0, stream>>>(Gbf, VT, Obf);
        k_gemm<<<dim3(2, 98), 256, 0, stream>>>(Obf, WPb + (long)l * 65536,
                                                projb + l * 256, Z,
                                                12544, 256, 256);
        k_gemm_ln<<<dim3(4, 98), 256, 0, stream>>>(Z, W1b + (long)l * 131072,
                                                   ln2s + l * 256, ln2b + l * 256,
                                                   fc1b + l * 512, MLPb, nullptr,
                                                   512, 1, 0);
        k_gemm<<<dim3(2, 98), 256, 0, stream>>>(MLPb, W2b + (long)l * 131072,
                                                fc2b + l * 256, Z,
                                                12544, 256, 512);
    }

    k_tail<<<4, 256, 0, stream>>>(Z, lnfs, lnfb, poolw, poolb, headw, headb, out);
}

// Round 7
// 4756.802 us; speedup vs baseline: 6.5129x; 1.1161x over previous
//
#include <hip/hip_runtime.h>
#include <hip/hip_bf16.h>
#include <cstdint>

#define SEQL 3136

typedef __attribute__((ext_vector_type(8))) short v8s;
typedef __attribute__((ext_vector_type(4))) float f32x4;

__device__ __forceinline__ uint16_t bf16u(float f) {
    uint32_t u = __float_as_uint(f);
    uint32_t r = u + 0x7fff + ((u >> 16) & 1);   // RNE
    return (uint16_t)(r >> 16);
}
__device__ __forceinline__ float bf2f(uint16_t b) {
    uint32_t u = ((uint32_t)b) << 16;
    return __uint_as_float(u);
}

// ---------------- merged prep: bf16 weight cvt + conv1 bf16 sign-W + conv2/3 masks ----
__global__ __launch_bounds__(256) void k_prep(const float* __restrict__ qw,
                                              const float* __restrict__ pw,
                                              const float* __restrict__ f1,
                                              const float* __restrict__ f2,
                                              const float* __restrict__ w1,
                                              const float* __restrict__ w2,
                                              const float* __restrict__ w3,
                                              uint16_t* __restrict__ dq,
                                              uint16_t* __restrict__ dp,
                                              uint16_t* __restrict__ d1,
                                              uint16_t* __restrict__ d2,
                                              uint16_t* __restrict__ w1b,
                                              uint64_t* __restrict__ wp2,
                                              uint64_t* __restrict__ wn2,
                                              uint32_t* __restrict__ wp3,
                                              uint32_t* __restrict__ wn3) {
    int gid = blockIdx.x * 256 + threadIdx.x;
    if (gid < 1376256) { dq[gid] = bf16u(qw[gid]); return; }
    if (gid < 1835008) { int i = gid - 1376256; dp[i] = bf16u(pw[i]); return; }
    if (gid < 2752512) { int i = gid - 1835008; d1[i] = bf16u(f1[i]); return; }
    if (gid < 3670016) { int i = gid - 2752512; d2[i] = bf16u(f2[i]); return; }
    if (gid < 3698688) {
        // conv1 sign weights as bf16: W1B[kw][oc][c=(ic*3+kd)*7+kh], c=63 -> 0
        int i = gid - 3670016;
        int c = i & 63, oc = (i >> 6) & 63, kw = i >> 12;
        uint16_t v = 0;
        if (c < 63) {
            int ic = c / 21, rem = c % 21, kd = rem / 7, kh = rem % 7;
            float w = w1[((((oc * 3 + ic) * 3 + kd) * 7 + kh) * 7) + kw];
            v = (w > 0.f) ? 0x3F80 : ((w < 0.f) ? 0xBF80 : 0);
        }
        w1b[i] = v;
        return;
    }
    if (gid < 3703392) {
        int i = gid - 3698688;
        int oc = i / 147, r = i % 147;
        uint64_t p = 0, n = 0;
        for (int ic = 0; ic < 64; ic++) {
            float v = w2[(long)oc * 9408 + (long)ic * 147 + r];
            if (v > 0.f) p |= (1ull << ic);
            else if (v < 0.f) n |= (1ull << ic);
        }
        wp2[i] = p; wn2[i] = n;
        return;
    }
    if (gid < 3703833) {
        int i = gid - 3703392;
        int oc = i / 147, r = i % 147;
        uint32_t p = 0, n = 0;
        for (int ic = 0; ic < 32; ic++) {
            float v = w3[(long)oc * 4704 + (long)ic * 147 + r];
            if (v > 0.f) p |= (1u << ic);
            else if (v < 0.f) n |= (1u << ic);
        }
        wp3[i] = p; wn3[i] = n;
    }
}

// ---------------- prepx: 3-way bf16 split of x into padded planes -------------------
// X3[s][b][ic][dslot 27][ih' 232][iw' 232] u16; dslot = d+1 (slot0 = zero plane);
// ih' = ih+3, iw' = iw+3; borders zero. Written as u32 (iw'-pairs).
__global__ __launch_bounds__(256) void k_prepx(const float* __restrict__ x,
                                               uint32_t* __restrict__ X3) {
    int gid = blockIdx.x * 256 + threadIdx.x;
    if (gid >= 26158464) return;
    int iwp = gid % 116;
    int t = gid / 116;
    int ihp = t % 232; t /= 232;
    int dslot = t % 27; t /= 27;
    int ic = t % 3; t /= 3;
    int b = t & 3; int s = t >> 2;
    int d = dslot - 1;
    int ih = ihp - 3;
    uint32_t out = 0;
    if (d >= 0 && (unsigned)ih < 224u) {
        const float* xp = x + ((long)(b * 3 + ic) * 27 + d) * 50176 + ih * 224;
#pragma unroll
        for (int half = 0; half < 2; half++) {
            int iw = 2 * iwp + half - 3;
            float v = ((unsigned)iw < 224u) ? xp[iw] : 0.f;
            uint16_t hi = bf16u(v);
            uint16_t o = hi;
            if (s > 0) {
                float r1 = v - bf2f(hi);
                uint16_t lo = bf16u(r1);
                o = (s == 2) ? bf16u(r1 - bf2f(lo)) : lo;
            }
            out |= ((uint32_t)o) << (16 * half);
        }
    }
    X3[gid] = out;
}

// ---------------- conv1: MFMA implicit GEMM from pre-split X3, packed u64 out --------
// block = (oh, od, b). M=224 ow (14 tiles), N=64 oc (4 tiles), K = 7kw x 64c x 3splits.
__device__ __forceinline__ v8s ldA76(const uint16_t* Xt, int colb, int c0) {
    union { v8s v; uint2 u[2]; } t;
    const uint16_t* p = Xt + colb * 76 + c0;
    t.u[0] = *(const uint2*)p;
    t.u[1] = *(const uint2*)(p + 4);
    return t.v;
}

__global__ __launch_bounds__(256) void k_conv1m(const uint16_t* __restrict__ X3,
                                                const uint16_t* __restrict__ w1b,
                                                uint64_t* __restrict__ b1p) {
    __shared__ __align__(16) uint16_t Xt[232 * 76];   // [col][c] stride 76 (38dw, gcd2)
    __shared__ __align__(16) uint16_t Wb[64 * 72];    // [oc][c] for current kw
    __shared__ uint16_t obits16[224 * 4];
    int tid = threadIdx.x;
    int oh = blockIdx.x, od = blockIdx.y, b = blockIdx.z;
    int lane = tid & 63, wv = tid >> 6;
    int wm = wv >> 1, wn = wv & 1;
    int tl = lane & 15, g = lane >> 4;

    f32x4 acc[7][2];
#pragma unroll
    for (int mt = 0; mt < 7; mt++) {
        acc[mt][0] = (f32x4){0.f, 0.f, 0.f, 0.f};
        acc[mt][1] = (f32x4){0.f, 0.f, 0.f, 0.f};
    }

    for (int s = 0; s < 3; s++) {
        __syncthreads();   // prior Xt reads done
        if (tid < 232) {
            // base: (s,b) block + od plane group + oh row + col
            const uint16_t* Xb = X3 + ((long)(s * 4 + b) * 81 + (long)od * 3) * 53824
                               + oh * 232 + tid;
#pragma unroll
            for (int cp = 0; cp < 32; cp++) {
                const int c0 = 2 * cp, c1 = c0 + 1;
                uint32_t v0 = 0, v1 = 0;
                if (c0 < 63) {
                    const int ickd = c0 / 7, kh = c0 % 7;
                    const int ic = ickd / 3, kd = ickd % 3;
                    v0 = Xb[(long)(ic * 27 + kd) * 53824 + kh * 232];
                }
                if (c1 < 63) {
                    const int ickd = c1 / 7, kh = c1 % 7;
                    const int ic = ickd / 3, kd = ickd % 3;
                    v1 = Xb[(long)(ic * 27 + kd) * 53824 + kh * 232];
                }
                *(uint32_t*)&Xt[tid * 76 + c0] = v0 | (v1 << 16);
            }
        }
        for (int kw = 0; kw < 7; kw++) {
            __syncthreads();   // prev Wb reads done; Xt visible (kw==0)
#pragma unroll
            for (int it = 0; it < 8; it++) {
                int idx = it * 256 + tid;
                int c2 = idx & 31, oc = idx >> 5;
                *(uint32_t*)&Wb[oc * 72 + c2 * 2] =
                    ((const uint32_t*)w1b)[kw * 2048 + oc * 32 + c2];
            }
            __syncthreads();
#pragma unroll
            for (int ks = 0; ks < 2; ks++) {
                v8s b0 = *(const v8s*)&Wb[(wn * 32 + tl) * 72 + ks * 32 + g * 8];
                v8s b1 = *(const v8s*)&Wb[(wn * 32 + 16 + tl) * 72 + ks * 32 + g * 8];
#pragma unroll
                for (int mt = 0; mt < 7; mt++) {
                    int colb = (wm * 7 + mt) * 16 + tl + kw;   // Xt index = xcol+3
                    v8s a = ldA76(Xt, colb, ks * 32 + g * 8);
                    acc[mt][0] = __builtin_amdgcn_mfma_f32_16x16x32_bf16(a, b0, acc[mt][0], 0, 0, 0);
                    acc[mt][1] = __builtin_amdgcn_mfma_f32_16x16x32_bf16(a, b1, acc[mt][1], 0, 0, 0);
                }
            }
        }
    }
    // epilogue: ballot -> 16-bit oc pieces
#pragma unroll
    for (int mt = 0; mt < 7; mt++)
#pragma unroll
        for (int nt = 0; nt < 2; nt++)
#pragma unroll
            for (int r = 0; r < 4; r++) {
                unsigned long long mask = __ballot(acc[mt][nt][r] > 0.f);
                if (tl == 0) {
                    int ow = (wm * 7 + mt) * 16 + g * 4 + r;
                    obits16[ow * 4 + wn * 2 + nt] = (uint16_t)(mask >> (g * 16));
                }
            }
    __syncthreads();
    if (tid < 224) {
        uint64_t w = (uint64_t)obits16[tid * 4]
                   | ((uint64_t)obits16[tid * 4 + 1] << 16)
                   | ((uint64_t)obits16[tid * 4 + 2] << 32)
                   | ((uint64_t)obits16[tid * 4 + 3] << 48);
        b1p[(((long)b * 9 + od) * 224 + oh) * 224 + tid] = w;
    }
}

// ---------------- conv2: 2-oh blocking, LDS patch + popcount, packed u32 out ---------
__global__ __launch_bounds__(256) void k_conv2(const uint64_t* __restrict__ bp1,
                                               const uint64_t* __restrict__ wp,
                                               const uint64_t* __restrict__ wn,
                                               uint32_t* __restrict__ b2p) {
    __shared__ uint64_t xs[24 * 232];
    __shared__ uint32_t obits[2][224];
    int tid = threadIdx.x;
    int oh0 = blockIdx.x * 2, od = blockIdx.y, b = blockIdx.z;
    for (int i = tid; i < 24 * 232; i += 256) {
        int col = i % 232; int t = i / 232;
        int kh = t & 7; int kd = t >> 3;
        int d = od * 3 - 1 + kd;
        int h = oh0 - 3 + kh;
        int w = col - 3;
        uint64_t v = 0;
        if ((unsigned)d < 9u && (unsigned)h < 224u && (unsigned)w < 224u)
            v = bp1[(((long)b * 9 + d) * 224 + h) * 224 + w];
        xs[i] = v;
    }
    if (tid < 224) { obits[0][tid] = 0; obits[1][tid] = 0; }
    __syncthreads();
    int tx = tid & 15, ty = tid >> 4;
    int ow0 = tx * 14, oc0 = ty * 2;
#pragma unroll
    for (int oi = 0; oi < 2; oi++) {
        int acc0[14], acc1[14];
#pragma unroll
        for (int o2 = 0; o2 < 14; o2++) { acc0[o2] = 0; acc1[o2] = 0; }
        for (int kd = 0; kd < 3; kd++) {
#pragma unroll
            for (int kh = 0; kh < 7; kh++) {
                const uint64_t* row = &xs[(kd * 8 + kh + oi) * 232 + ow0];
                uint64_t xv[20];
#pragma unroll
                for (int t = 0; t < 20; t++) xv[t] = row[t];
                int rbase = kd * 49 + kh * 7;
#pragma unroll
                for (int kw = 0; kw < 7; kw++) {
                    uint64_t p0 = wp[oc0 * 147 + rbase + kw];
                    uint64_t n0 = wn[oc0 * 147 + rbase + kw];
                    uint64_t p1 = wp[(oc0 + 1) * 147 + rbase + kw];
                    uint64_t n1 = wn[(oc0 + 1) * 147 + rbase + kw];
#pragma unroll
                    for (int o2 = 0; o2 < 14; o2++) {
                        uint64_t bits = xv[o2 + kw];
                        acc0[o2] += __popcll(bits & p0) - __popcll(bits & n0);
                        acc1[o2] += __popcll(bits & p1) - __popcll(bits & n1);
                    }
                }
            }
        }
#pragma unroll
        for (int o2 = 0; o2 < 14; o2++) {
            uint32_t v = (uint32_t)((acc0[o2] > 0) | ((acc1[o2] > 0) << 1));
            if (v) atomicOr(&obits[oi][ow0 + o2], v << oc0);
        }
    }
    __syncthreads();
    if (tid < 224) {
        long base = (((long)b * 3 + od) * 224 + oh0) * 224 + tid;
        b2p[base] = obits[0][tid];
        b2p[base + 224] = obits[1][tid];
    }
}

// conv3 via popcount -> fp32 relu count
__global__ __launch_bounds__(256) void k_conv3(const uint32_t* __restrict__ bp2,
                                               const uint32_t* __restrict__ wp,
                                               const uint32_t* __restrict__ wn,
                                               float* __restrict__ h3) {
    int gid = blockIdx.x * 256 + threadIdx.x;  // 602,112
    int q = gid;
    int ow = q % 224; q /= 224;
    int oh = q % 224; q /= 224;
    int oc = q % 3;   int b = q / 3;
    int acc = 0;
    for (int kd = 0; kd < 3; kd++) {
        int d = kd - 1;
        if ((unsigned)d >= 3u) continue;
        for (int kh = 0; kh < 7; kh++) {
            int h = oh - 3 + kh;
            if ((unsigned)h >= 224u) continue;
            const uint32_t* bp = bp2 + ((long)(b * 3 + d) * 224 + h) * 224;
            const uint32_t* mp = wp + ((oc * 3 + kd) * 7 + kh) * 7;
            const uint32_t* mn = wn + ((oc * 3 + kd) * 7 + kh) * 7;
#pragma unroll
            for (int kw = 0; kw < 7; kw++) {
                int w = ow - 3 + kw;
                if ((unsigned)w < 224u) {
                    uint32_t bits = bp[w];
                    acc += __popc(bits & mp[kw]) - __popc(bits & mn[kw]);
                }
            }
        }
    }
    h3[gid] = fmaxf((float)acc, 0.f);
}

// ---------------- tokenizer conv; tok layout [b][h][w][c] ----------------
__global__ __launch_bounds__(256) void k_tok(const float* __restrict__ h3,
                                             const float* __restrict__ wt,
                                             float* __restrict__ tok) {
    __shared__ float xs[3 * 7 * 232];
    int tid = threadIdx.x;
    int oh = blockIdx.x, b = blockIdx.y;
    for (int i = tid; i < 3 * 7 * 232; i += 256) {
        int col = i % 232; int t = i / 232;
        int kh = t % 7; int ic = t / 7;
        int ih = oh * 2 - 3 + kh;
        int iw = col - 3;
        float v = 0.f;
        if ((unsigned)ih < 224u && (unsigned)iw < 224u)
            v = h3[((long)(b * 3 + ic) * 50176) + ih * 224 + iw];
        xs[i] = v;
    }
    __syncthreads();
    int oc = tid;
    float* obase = tok + ((long)(b * 112 + oh) * 112) * 256 + oc;
    for (int chunk = 0; chunk < 4; chunk++) {
        int ow0 = chunk * 28;
        float acc[28];
#pragma unroll
        for (int o2 = 0; o2 < 28; o2++) acc[o2] = 0.f;
        for (int ic = 0; ic < 3; ic++) {
#pragma unroll
            for (int kh = 0; kh < 7; kh++) {
                const float* row = &xs[(ic * 7 + kh) * 232 + ow0 * 2];
                float xv[61];
#pragma unroll
                for (int t = 0; t < 61; t++) xv[t] = row[t];
                const float* wr = wt + (oc * 3 + ic) * 49 + kh * 7;
                float w[7];
#pragma unroll
                for (int kw = 0; kw < 7; kw++) w[kw] = wr[kw];
#pragma unroll
                for (int kw = 0; kw < 7; kw++)
#pragma unroll
                    for (int o2 = 0; o2 < 28; o2++)
                        acc[o2] = fmaf(w[kw], xv[2 * o2 + kw], acc[o2]);
            }
        }
#pragma unroll
        for (int o2 = 0; o2 < 28; o2++)
            obase[(long)(ow0 + o2) * 256] = fmaxf(acc[o2], 0.f);
    }
}

// maxpool 3x3 s2 p1 + pos_emb
__global__ __launch_bounds__(256) void k_pool_z(const float* __restrict__ tok,
                                                const float* __restrict__ pos,
                                                float* __restrict__ z) {
    int gid = blockIdx.x * 256 + threadIdx.x;
    int c = gid & 255;
    int n = (gid >> 8) % SEQL;
    int b = gid / (256 * SEQL);
    int oh = n / 56, ow = n % 56;
    const float* tp = tok + ((long)b * 112 * 112) * 256 + c;
    float m = -1e30f;
#pragma unroll
    for (int kh = 0; kh < 3; kh++) {
        int h = oh * 2 - 1 + kh;
        if ((unsigned)h >= 112u) continue;
#pragma unroll
        for (int kw = 0; kw < 3; kw++) {
            int w = ow * 2 - 1 + kw;
            if ((unsigned)w < 112u) m = fmaxf(m, tp[(long)(h * 112 + w) * 256]);
        }
    }
    z[gid] = m + pos[n * 256 + c];
}

// ---------------- GEMM with fused layernorm on A (A = LN(Z) rows) ----------------
__global__ __launch_bounds__(256) void k_gemm_ln(const float* __restrict__ Z,
                                                 const uint16_t* __restrict__ W,
                                                 const float* __restrict__ lns,
                                                 const float* __restrict__ lnb,
                                                 const float* __restrict__ bias,
                                                 uint16_t* __restrict__ C,
                                                 uint16_t* __restrict__ VT,
                                                 int N, int dogelu, int dovt) {
    __shared__ uint16_t As[128 * 40], Bs[128 * 40];
    __shared__ float mu[128], rsd[128];
    int tid = threadIdx.x;
    int lane = tid & 63, wave = tid >> 6;
    int wm = wave >> 1, wn = wave & 1;
    int m0 = blockIdx.y * 128, n0 = blockIdx.x * 128;
    {
        int row = tid >> 1, hf = tid & 1;
        const float* zr = Z + (long)(m0 + row) * 256 + hf * 128;
        float s = 0.f, sq = 0.f;
        for (int i = 0; i < 128; i++) { float v = zr[i]; s += v; sq += v * v; }
        s += __shfl_xor(s, 1); sq += __shfl_xor(sq, 1);
        if (hf == 0) {
            float m = s * (1.0f / 256.0f);
            mu[row] = m;
            rsd[row] = rsqrtf(sq * (1.0f / 256.0f) - m * m + 1e-5f);
        }
    }
    f32x4 acc[4][4];
#pragma unroll
    for (int i = 0; i < 4; i++)
#pragma unroll
        for (int j = 0; j < 4; j++) acc[i][j] = (f32x4){0.f, 0.f, 0.f, 0.f};
    int rl = lane & 15, kq = (lane >> 4) * 8;
    for (int k0 = 0; k0 < 256; k0 += 32) {
        __syncthreads();
#pragma unroll
        for (int c2 = 0; c2 < 16; c2++) {
            int idx = c2 * 256 + tid;
            int col = idx & 31, row = idx >> 5;
            float v = Z[(long)(m0 + row) * 256 + k0 + col];
            v = (v - mu[row]) * rsd[row] * lns[k0 + col] + lnb[k0 + col];
            As[row * 40 + col] = bf16u(v);
        }
#pragma unroll
        for (int c = 0; c < 2; c++) {
            int idx = c * 256 + tid;
            int row = idx >> 2, k8 = (idx & 3) * 8;
            *(uint4*)&Bs[row * 40 + k8] = *(const uint4*)&W[(long)(n0 + row) * 256 + k0 + k8];
        }
        __syncthreads();
        v8s a[4], bb[4];
#pragma unroll
        for (int i = 0; i < 4; i++) a[i] = *(const v8s*)&As[(wm * 64 + i * 16 + rl) * 40 + kq];
#pragma unroll
        for (int j = 0; j < 4; j++) bb[j] = *(const v8s*)&Bs[(wn * 64 + j * 16 + rl) * 40 + kq];
#pragma unroll
        for (int i = 0; i < 4; i++)
#pragma unroll
            for (int j = 0; j < 4; j++)
                acc[i][j] = __builtin_amdgcn_mfma_f32_16x16x32_bf16(a[i], bb[j], acc[i][j], 0, 0, 0);
    }
    int rq = (lane >> 4) * 4;
    bool vt = (dovt != 0) && (n0 >= 512);
#pragma unroll
    for (int i = 0; i < 4; i++) {
#pragma unroll
        for (int j = 0; j < 4; j++) {
            int col = n0 + wn * 64 + j * 16 + rl;
            float bval = bias[col];
#pragma unroll
            for (int r = 0; r < 4; r++) {
                int row = m0 + wm * 64 + i * 16 + rq + r;
                float v = acc[i][j][r] + bval;
                if (dogelu) v = 0.5f * v * (1.0f + erff(v * 0.70710678118654752f));
                if (vt) {
                    int hv = col - 512;
                    int h = hv >> 6, d = hv & 63;
                    int bb2 = row / SEQL, nn = row - bb2 * SEQL;
                    VT[((long)(bb2 * 4 + h) * 64 + d) * SEQL + nn] = bf16u(v);
                } else {
                    C[(long)row * N + col] = bf16u(v);
                }
            }
        }
    }
}

// ---------------- plain bf16 GEMM (A bf16), resid fp32 += ----------------
__global__ __launch_bounds__(256) void k_gemm(const uint16_t* __restrict__ A,
                                              const uint16_t* __restrict__ W,
                                              const float* __restrict__ bias,
                                              float* __restrict__ C,
                                              int M, int N, int K) {
    __shared__ uint16_t As[128 * 40], Bs[128 * 40];
    int tid = threadIdx.x;
    int lane = tid & 63, wave = tid >> 6;
    int wm = wave >> 1, wn = wave & 1;
    int m0 = blockIdx.y * 128, n0 = blockIdx.x * 128;
    f32x4 acc[4][4];
#pragma unroll
    for (int i = 0; i < 4; i++)
#pragma unroll
        for (int j = 0; j < 4; j++) acc[i][j] = (f32x4){0.f, 0.f, 0.f, 0.f};
    int rl = lane & 15, kq = (lane >> 4) * 8;
    for (int k0 = 0; k0 < K; k0 += 32) {
        __syncthreads();
#pragma unroll
        for (int c = 0; c < 2; c++) {
            int idx = c * 256 + tid;
            int row = idx >> 2, k8 = (idx & 3) * 8;
            *(uint4*)&As[row * 40 + k8] = *(const uint4*)&A[(long)(m0 + row) * K + k0 + k8];
            *(uint4*)&Bs[row * 40 + k8] = *(const uint4*)&W[(long)(n0 + row) * K + k0 + k8];
        }
        __syncthreads();
        v8s a[4], bb[4];
#pragma unroll
        for (int i = 0; i < 4; i++) a[i] = *(const v8s*)&As[(wm * 64 + i * 16 + rl) * 40 + kq];
#pragma unroll
        for (int j = 0; j < 4; j++) bb[j] = *(const v8s*)&Bs[(wn * 64 + j * 16 + rl) * 40 + kq];
#pragma unroll
        for (int i = 0; i < 4; i++)
#pragma unroll
            for (int j = 0; j < 4; j++)
                acc[i][j] = __builtin_amdgcn_mfma_f32_16x16x32_bf16(a[i], bb[j], acc[i][j], 0, 0, 0);
    }
    int rq = (lane >> 4) * 4;
#pragma unroll
    for (int i = 0; i < 4; i++) {
#pragma unroll
        for (int j = 0; j < 4; j++) {
            int col = n0 + wn * 64 + j * 16 + rl;
            float bval = bias[col];
#pragma unroll
            for (int r = 0; r < 4; r++) {
                int row = m0 + wm * 64 + i * 16 + rq + r;
                C[(long)row * N + col] += acc[i][j][r] + bval;
            }
        }
    }
}

// ---------------- flash attention, bf16 MFMA, pre-transposed V, b128 staging -------
__global__ __launch_bounds__(256) void k_flash(const uint16_t* __restrict__ G,
                                               const uint16_t* __restrict__ VT,
                                               uint16_t* __restrict__ o) {
    __shared__ __align__(16) uint32_t Qs[64 * 36], Ks[64 * 36], Vt[64 * 36];
    __shared__ __align__(16) uint16_t Ps[64 * 72];
    int tid = threadIdx.x;
    int lane = tid & 63, wv = tid >> 6;
    int qt = blockIdx.x, h = blockIdx.y, b = blockIdx.z;
    long base = (long)b * SEQL * 768 + h * 64;
    long vtbase = ((long)(b * 4 + h) * 64) * SEQL;
#pragma unroll
    for (int it = 0; it < 2; it++) {
        int idx = it * 256 + tid;
        int q8 = idx & 7, r = idx >> 3;
        *(uint4*)&Qs[r * 36 + q8 * 4] = *(const uint4*)&G[base + (long)(qt * 64 + r) * 768 + q8 * 8];
    }
    int g = lane >> 4, tl = lane & 15;
    int qr0 = wv * 16;
    __syncthreads();
    v8s aq[2];
#pragma unroll
    for (int ks = 0; ks < 2; ks++)
        aq[ks] = *(const v8s*)&Qs[(qr0 + tl) * 36 + ks * 16 + g * 4];

    float m_[4], l_[4];
    f32x4 ov[4];
#pragma unroll
    for (int r = 0; r < 4; r++) { m_[r] = -1e30f; l_[r] = 0.f; }
#pragma unroll
    for (int j = 0; j < 4; j++) ov[j] = (f32x4){0.f, 0.f, 0.f, 0.f};

    for (int kt = 0; kt < 49; kt++) {
        __syncthreads();
#pragma unroll
        for (int it = 0; it < 2; it++) {
            int idx = it * 256 + tid;
            int q8 = idx & 7, r = idx >> 3;
            *(uint4*)&Ks[r * 36 + q8 * 4] =
                *(const uint4*)&G[base + (long)(kt * 64 + r) * 768 + 256 + q8 * 8];
        }
#pragma unroll
        for (int it = 0; it < 2; it++) {
            int idx = it * 256 + tid;
            int r8 = idx & 7, d = idx >> 3;
            *(uint4*)&Vt[d * 36 + r8 * 4] =
                *(const uint4*)&VT[vtbase + (long)d * SEQL + kt * 64 + r8 * 8];
        }
        __syncthreads();
        f32x4 s[4];
#pragma unroll
        for (int j = 0; j < 4; j++) s[j] = (f32x4){0.f, 0.f, 0.f, 0.f};
#pragma unroll
        for (int ks = 0; ks < 2; ks++) {
#pragma unroll
            for (int j = 0; j < 4; j++) {
                v8s bk = *(const v8s*)&Ks[(j * 16 + tl) * 36 + ks * 16 + g * 4];
                s[j] = __builtin_amdgcn_mfma_f32_16x16x32_bf16(aq[ks], bk, s[j], 0, 0, 0);
            }
        }
        float alpha[4];
#pragma unroll
        for (int r = 0; r < 4; r++) {
            float s0 = s[0][r] * 0.125f, s1 = s[1][r] * 0.125f;
            float s2 = s[2][r] * 0.125f, s3 = s[3][r] * 0.125f;
            s[0][r] = s0; s[1][r] = s1; s[2][r] = s2; s[3][r] = s3;
            float mx = fmaxf(fmaxf(s0, s1), fmaxf(s2, s3));
#pragma unroll
            for (int off = 1; off < 16; off <<= 1) mx = fmaxf(mx, __shfl_xor(mx, off));
            float nm = fmaxf(m_[r], mx);
            alpha[r] = __expf(m_[r] - nm);
            float rs = 0.f;
#pragma unroll
            for (int j = 0; j < 4; j++) {
                float p = __expf(s[j][r] - nm);
                s[j][r] = p; rs += p;
            }
#pragma unroll
            for (int off = 1; off < 16; off <<= 1) rs += __shfl_xor(rs, off);
            l_[r] = l_[r] * alpha[r] + rs;
            m_[r] = nm;
        }
#pragma unroll
        for (int j = 0; j < 4; j++)
#pragma unroll
            for (int r = 0; r < 4; r++) ov[j][r] *= alpha[r];
#pragma unroll
        for (int j = 0; j < 4; j++)
#pragma unroll
            for (int r = 0; r < 4; r++)
                Ps[(qr0 + g * 4 + r) * 72 + j * 16 + tl] = bf16u(s[j][r]);
#pragma unroll
        for (int ks = 0; ks < 2; ks++) {
            v8s ap = *(const v8s*)&Ps[(qr0 + tl) * 72 + ks * 32 + g * 8];
#pragma unroll
            for (int jd = 0; jd < 4; jd++) {
                v8s bv = *(const v8s*)&Vt[(jd * 16 + tl) * 36 + ks * 16 + g * 4];
                ov[jd] = __builtin_amdgcn_mfma_f32_16x16x32_bf16(ap, bv, ov[jd], 0, 0, 0);
            }
        }
    }
    long ob = ((long)b * SEQL + qt * 64) * 256 + h * 64;
#pragma unroll
    for (int r = 0; r < 4; r++) {
        float inv = 1.0f / l_[r];
        int row = qr0 + g * 4 + r;
#pragma unroll
        for (int jd = 0; jd < 4; jd++)
            o[ob + (long)row * 256 + jd * 16 + tl] = bf16u(ov[jd][r] * inv);
    }
}

// ---------------- fused tail: final LN + pool logits + softmax + pooled + head -----
__global__ __launch_bounds__(256) void k_tail(const float* __restrict__ Z,
                                              const float* __restrict__ g,
                                              const float* __restrict__ be,
                                              const float* __restrict__ pw,
                                              const float* __restrict__ pb,
                                              const float* __restrict__ hw,
                                              const float* __restrict__ hb,
                                              float* __restrict__ out) {
    __shared__ float lg[SEQL];
    __shared__ float muA[SEQL];
    __shared__ float rsA[SEQL];
    __shared__ float red[256];
    __shared__ float pooled[256];
    __shared__ float sBsh;
    int b = blockIdx.x, tid = threadIdx.x;
    int wv = tid >> 6, lane = tid & 63;
    const float* Zb = Z + (long)b * SEQL * 256;
    for (int r = wv; r < SEQL; r += 4) {
        const float* xr = Zb + (long)r * 256;
        float v0 = xr[lane], v1 = xr[lane + 64], v2 = xr[lane + 128], v3 = xr[lane + 192];
        float s = v0 + v1 + v2 + v3;
#pragma unroll
        for (int off = 1; off < 64; off <<= 1) s += __shfl_xor(s, off);
        float mean = s * (1.0f / 256.0f);
        float d0 = v0 - mean, d1 = v1 - mean, d2 = v2 - mean, d3 = v3 - mean;
        float sq = d0 * d0 + d1 * d1 + d2 * d2 + d3 * d3;
#pragma unroll
        for (int off = 1; off < 64; off <<= 1) sq += __shfl_xor(sq, off);
        float rs_ = rsqrtf(sq * (1.0f / 256.0f) + 1e-5f);
        float a = (d0 * rs_ * g[lane] + be[lane]) * pw[lane]
                + (d1 * rs_ * g[lane + 64] + be[lane + 64]) * pw[lane + 64]
                + (d2 * rs_ * g[lane + 128] + be[lane + 128]) * pw[lane + 128]
                + (d3 * rs_ * g[lane + 192] + be[lane + 192]) * pw[lane + 192];
#pragma unroll
        for (int off = 1; off < 64; off <<= 1) a += __shfl_xor(a, off);
        if (lane == 0) { lg[r] = a + pb[0]; muA[r] = mean; rsA[r] = rs_; }
    }
    __syncthreads();
    float m = -1e30f;
    for (int i = tid; i < SEQL; i += 256) m = fmaxf(m, lg[i]);
    red[tid] = m; __syncthreads();
    for (int s = 128; s > 0; s >>= 1) {
        if (tid < s) red[tid] = fmaxf(red[tid], red[tid + s]);
        __syncthreads();
    }
    float M = red[0]; __syncthreads();
    float sum = 0.f;
    for (int i = tid; i < SEQL; i += 256) sum += expf(lg[i] - M);
    red[tid] = sum; __syncthreads();
    for (int s = 128; s > 0; s >>= 1) {
        if (tid < s) red[tid] += red[tid + s];
        __syncthreads();
    }
    float inv = 1.0f / red[0];
    __syncthreads();
    float pB = 0.f;
    for (int i = tid; i < SEQL; i += 256) {
        float p = expf(lg[i] - M) * inv;
        pB += p * muA[i] * rsA[i];
        rsA[i] = p * rsA[i];
    }
    red[tid] = pB; __syncthreads();
    for (int s = 128; s > 0; s >>= 1) {
        if (tid < s) red[tid] += red[tid + s];
        __syncthreads();
    }
    if (tid == 0) sBsh = red[0];
    __syncthreads();
    float sB = sBsh;
    float acc = 0.f;
    for (int n = 0; n < SEQL; n++) acc = fmaf(rsA[n], Zb[(long)n * 256 + tid], acc);
    pooled[tid] = g[tid] * (acc - sB) + be[tid];
    __syncthreads();
    if (tid < 101) {
        float a = hb[tid];
        for (int d = 0; d < 256; d++) a = fmaf(pooled[d], hw[tid * 256 + d], a);
        out[b * 101 + tid] = a;
    }
}

// ---------------------------------------------------------------------------
extern "C" void kernel_launch(void* const* d_in, const int* in_sizes, int n_in,
                              void* d_out, int out_size, void* d_ws, size_t ws_size,
                              hipStream_t stream) {
    (void)in_sizes; (void)n_in; (void)out_size; (void)ws_size;
    const float* x     = (const float*)d_in[0];
    const float* w1    = (const float*)d_in[1];
    const float* w2    = (const float*)d_in[2];
    const float* w3    = (const float*)d_in[3];
    const float* tokw  = (const float*)d_in[4];
    const float* pos   = (const float*)d_in[5];
    const float* ln1s  = (const float*)d_in[6];
    const float* ln1b  = (const float*)d_in[7];
    const float* qkvw  = (const float*)d_in[8];
    const float* qkvb  = (const float*)d_in[9];
    const float* projw = (const float*)d_in[10];
    const float* projb = (const float*)d_in[11];
    const float* ln2s  = (const float*)d_in[12];
    const float* ln2b  = (const float*)d_in[13];
    const float* fc1w  = (const float*)d_in[14];
    const float* fc1b  = (const float*)d_in[15];
    const float* fc2w  = (const float*)d_in[16];
    const float* fc2b  = (const float*)d_in[17];
    const float* lnfs  = (const float*)d_in[18];
    const float* lnfb  = (const float*)d_in[19];
    const float* poolw = (const float*)d_in[20];
    const float* poolb = (const float*)d_in[21];
    const float* headw = (const float*)d_in[22];
    const float* headb = (const float*)d_in[23];
    float* out = (float*)d_out;
    char* ws = (char*)d_ws;

    uint64_t* B1P = (uint64_t*)(ws + 0);                  // 14,450,688
    uint32_t* B2P = (uint32_t*)(ws + 14450688);           //  2,408,448
    float*    H3  = (float*)(ws + 16859136);              //  2,408,448
    uint16_t* W1B = (uint16_t*)(ws + 19267584);           //     57,344
    uint64_t* WP2 = (uint64_t*)(ws + 19324928);           //     37,632
    uint64_t* WN2 = (uint64_t*)(ws + 19362560);           //     37,632
    uint32_t* WP3 = (uint32_t*)(ws + 19400192);           //      2,048
    uint32_t* WN3 = (uint32_t*)(ws + 19402240);           //      2,048
    uint16_t* WQb = (uint16_t*)(ws + 19404288);           //  2,752,512
    uint16_t* WPb = (uint16_t*)(ws + 22156800);           //    917,504
    uint16_t* W1b = (uint16_t*)(ws + 23074304);           //  1,835,008
    uint16_t* W2b = (uint16_t*)(ws + 24909312);           //  1,835,008
    // X3 (104,633,856 B) aliases TOK..VT region — dead until after conv1m
    uint16_t* X3  = (uint16_t*)(ws + 26744320);
    float*    TOK = (float*)(ws + 26744320);              // 51,380,224 [b][h][w][c]
    float*    Z   = (float*)(ws + 78124544);              // 12,845,056
    uint16_t* Gbf = (uint16_t*)(ws + 90969600);           // 19,267,584
    uint16_t* Obf = (uint16_t*)(ws + 110237184);          //  6,422,528
    uint16_t* MLPb= (uint16_t*)(ws + 116659712);          // 12,845,056
    uint16_t* VT  = (uint16_t*)(ws + 129504768);          //  6,422,528

    k_prep<<<14469, 256, 0, stream>>>(qkvw, projw, fc1w, fc2w, w1, w2, w3,
                                      WQb, WPb, W1b, W2b, W1B, WP2, WN2, WP3, WN3);
    k_prepx<<<102182, 256, 0, stream>>>(x, (uint32_t*)X3);

    k_conv1m<<<dim3(224, 9, 4), 256, 0, stream>>>(X3, W1B, B1P);
    k_conv2<<<dim3(112, 3, 4), 256, 0, stream>>>(B1P, WP2, WN2, B2P);
    k_conv3<<<2352, 256, 0, stream>>>(B2P, WP3, WN3, H3);
    k_tok<<<dim3(112, 4), 256, 0, stream>>>(H3, tokw, TOK);
    k_pool_z<<<12544, 256, 0, stream>>>(TOK, pos, Z);

    for (int l = 0; l < 7; l++) {
        k_gemm_ln<<<dim3(6, 98), 256, 0, stream>>>(Z, WQb + (long)l * 196608,
                                                   ln1s + l * 256, ln1b + l * 256,
                                                   qkvb + l * 768, Gbf, VT,
                                                   768, 0, 1);
        k_flash<<<dim3(49, 4, 4), 256, 0, stream>>>(Gbf, VT, Obf);
        k_gemm<<<dim3(2, 98), 256, 0, stream>>>(Obf, WPb + (long)l * 65536,
                                                projb + l * 256, Z,
                                                12544, 256, 256);
        k_gemm_ln<<<dim3(4, 98), 256, 0, stream>>>(Z, W1b + (long)l * 131072,
                                                   ln2s + l * 256, ln2b + l * 256,
                                                   fc1b + l * 512, MLPb, nullptr,
                                                   512, 1, 0);
        k_gemm<<<dim3(2, 98), 256, 0, stream>>>(MLPb, W2b + (long)l * 131072,
                                                fc2b + l * 256, Z,
                                                12544, 256, 512);
    }

    k_tail<<<4, 256, 0, stream>>>(Z, lnfs, lnfb, poolw, poolb, headw, headb, out);
}